// Round 1
// baseline (972.666 us; speedup 1.0000x reference)
//
#include <hip/hip_runtime.h>
#include <hip/hip_bf16.h>

// Problem constants (reference: B=8, L=1024, C=4, D=64, H=8, NB=2, K=16)
#define BB   8
#define LL   1024
#define DD   64
#define D2   128
#define D4   256
#define HH   8
#define DH   16

__device__ __forceinline__ float gelu_tanh(float u) {
  // jax.nn.gelu(approximate=True): 0.5*x*(1+tanh(sqrt(2/pi)*(x+0.044715*x^3)))
  float t = tanhf(0.7978845608028654f * (u + 0.044715f * u * u * u));
  return 0.5f * u * (1.0f + t);
}

__device__ __forceinline__ float wave_reduce_sum(float v) {
#pragma unroll
  for (int m = 32; m >= 1; m >>= 1) v += __shfl_xor(v, m, 64);
  return v;
}

// ---------------------------------------------------------------------------
// K1: feats = [embed | z | cond] (128) -> gelu(feats@Win1+bin1) @ Win2 + bin2
// 8 tokens per block, 256 threads.
// ---------------------------------------------------------------------------
__global__ __launch_bounds__(256) void k_input_mlp(
    const float* __restrict__ embed, const float* __restrict__ z,
    const float* __restrict__ cond, const float* __restrict__ Win1,
    const float* __restrict__ bin1, const float* __restrict__ Win2,
    const float* __restrict__ bin2, float* __restrict__ x) {
  __shared__ float feats[8][128];
  __shared__ float hid[8][256];
  int t = threadIdx.x;
  int base = blockIdx.x * 8;
  for (int idx = t; idx < 8 * 128; idx += 256) {
    int tok = idx >> 7, dim = idx & 127;
    int bl = base + tok;
    int l = bl & (LL - 1);
    float v;
    if (dim < 123) v = embed[l * 123 + dim];
    else if (dim == 123) v = z[bl];
    else v = cond[dim - 124];
    feats[tok][dim] = v;
  }
  __syncthreads();
  float acc[8];
  float bj = bin1[t];
#pragma unroll
  for (int tok = 0; tok < 8; ++tok) acc[tok] = bj;
  for (int i = 0; i < 128; ++i) {
    float w = Win1[i * 256 + t];
#pragma unroll
    for (int tok = 0; tok < 8; ++tok) acc[tok] = fmaf(feats[tok][i], w, acc[tok]);
  }
#pragma unroll
  for (int tok = 0; tok < 8; ++tok) hid[tok][t] = gelu_tanh(acc[tok]);
  __syncthreads();
  int d = t & 63, g = t >> 6;  // g handles tokens g and g+4
  float a0 = bin2[d], a1 = a0;
  for (int i = 0; i < 256; ++i) {
    float w = Win2[i * 64 + d];
    a0 = fmaf(hid[g][i], w, a0);
    a1 = fmaf(hid[g + 4][i], w, a1);
  }
  x[(base + g) * 64 + d] = a0;
  x[(base + g + 4) * 64 + d] = a1;
}

// ---------------------------------------------------------------------------
// K2: RBF bias, batch-independent. biasT[h][k][q] (transposed for coalesced
// q-lane reads in attention). rbf_b folded in.
// ---------------------------------------------------------------------------
__global__ __launch_bounds__(256) void k_bias(
    const float* __restrict__ s, const float* __restrict__ rbf_c,
    const float* __restrict__ rbf_logw, const float* __restrict__ rbf_w,
    const float* __restrict__ rbf_b, float* __restrict__ biasT, int lay) {
  int id = blockIdx.x * 256 + threadIdx.x;  // 0 .. L*L-1
  int k = id >> 10, q = id & 1023;
  float dd = s[q] - s[k];  // dist[q,k] = s[q]-s[k]
  float acc[8];
#pragma unroll
  for (int h = 0; h < 8; ++h) acc[h] = rbf_b[lay * 8 + h];
#pragma unroll 1
  for (int f = 0; f < 16; ++f) {
    float c = rbf_c[lay * 16 + f];
    // 1/(2 w^2) = 0.5*exp(-2*logw)
    float inv2w2 = 0.5f * __expf(-2.0f * rbf_logw[lay * 16 + f]);
    float e = dd - c;
    float ph = __expf(-e * e * inv2w2);
#pragma unroll
    for (int h = 0; h < 8; ++h)
      acc[h] = fmaf(ph, rbf_w[lay * 128 + f * 8 + h], acc[h]);
  }
#pragma unroll
  for (int h = 0; h < 8; ++h)
    biasT[(size_t)(h * 1024 + k) * 1024 + q] = acc[h];
}

// ---------------------------------------------------------------------------
// K3: h = LN(x; ln1) ; q,k,v = h@W + b stored as (B,H,L,dh).
// 4 tokens per block; one wave per token for LN.
// ---------------------------------------------------------------------------
__global__ __launch_bounds__(256) void k_ln_qkv(
    const float* __restrict__ x, const float* __restrict__ ln_s,
    const float* __restrict__ ln_b, const float* __restrict__ Wq,
    const float* __restrict__ bq, const float* __restrict__ Wk,
    const float* __restrict__ bk, const float* __restrict__ Wv,
    const float* __restrict__ bv, float* __restrict__ qo,
    float* __restrict__ ko, float* __restrict__ vo, int lay) {
  __shared__ float hl[4][64];
  int t = threadIdx.x, w = t >> 6, lane = t & 63;
  int bl = blockIdx.x * 4 + w;
  float xv = x[bl * 64 + lane];
  float mean = wave_reduce_sum(xv) * (1.0f / 64.0f);
  float diff = xv - mean;
  float var = wave_reduce_sum(diff * diff) * (1.0f / 64.0f);
  hl[w][lane] = diff * rsqrtf(var + 1e-6f) * ln_s[lay * 64 + lane] + ln_b[lay * 64 + lane];
  __syncthreads();
  int j = t & 127, half = t >> 7;
#pragma unroll
  for (int mat = 0; mat < 3; ++mat) {
    const float* W = (mat == 0 ? Wq : mat == 1 ? Wk : Wv) + lay * 64 * 128;
    const float* bp = (mat == 0 ? bq : mat == 1 ? bk : bv) + lay * 128;
    float* outp = (mat == 0 ? qo : mat == 1 ? ko : vo);
    float bb = bp[j];
#pragma unroll
    for (int tp = 0; tp < 2; ++tp) {
      int tok = tp * 2 + half;
      float acc = bb;
      for (int i = 0; i < 64; ++i) acc = fmaf(hl[tok][i], W[i * 128 + j], acc);
      int bl2 = blockIdx.x * 4 + tok;
      int b = bl2 >> 10, l = bl2 & 1023;
      outp[(size_t)(((b * 8 + (j >> 4)) << 10) + l) * 16 + (j & 15)] = acc;
    }
  }
}

// ---------------------------------------------------------------------------
// K4: flash attention per (b, h, 64 q-rows). 4 waves split the 1024-key range
// into quarters; each lane owns one q row (online softmax); log-sum-exp merge.
// ---------------------------------------------------------------------------
__global__ __launch_bounds__(256) void k_attn(
    const float* __restrict__ qg, const float* __restrict__ kg,
    const float* __restrict__ vg, const float* __restrict__ biasT,
    float* __restrict__ og) {
  __shared__ float smem[8192];  // 32 KB: k staging [4][64][16] + v staging
  int t = threadIdx.x, p = t >> 6, r = t & 63;
  int bid = blockIdx.x;
  int b = bid >> 7;
  int h = (bid >> 4) & 7;
  int qt = bid & 15;
  int qrow = qt * 64 + r;
  const float* qp = qg + (size_t)((b * 8 + h) * 1024 + qrow) * 16;
  float qv[16];
#pragma unroll
  for (int d = 0; d < 16; d += 4) {
    float4 f = *(const float4*)(qp + d);
    qv[d] = f.x; qv[d + 1] = f.y; qv[d + 2] = f.z; qv[d + 3] = f.w;
  }
  float m = -1e30f, l = 0.0f;
  float o[16];
#pragma unroll
  for (int d = 0; d < 16; ++d) o[d] = 0.0f;
  float* k_lds = smem + p * 1024;
  float* v_lds = smem + 4096 + p * 1024;
#pragma unroll 1
  for (int tile = 0; tile < 4; ++tile) {
    int k0 = p * 256 + tile * 64;
    const float* kp = kg + (size_t)((b * 8 + h) * 1024 + k0 + r) * 16;
    const float* vp = vg + (size_t)((b * 8 + h) * 1024 + k0 + r) * 16;
    __syncthreads();
#pragma unroll
    for (int d = 0; d < 16; d += 4) {
      *(float4*)(k_lds + r * 16 + d) = *(const float4*)(kp + d);
      *(float4*)(v_lds + r * 16 + d) = *(const float4*)(vp + d);
    }
    __syncthreads();
    const float* bp = biasT + (size_t)(h * 1024 + k0) * 1024 + qrow;
#pragma unroll 1
    for (int c = 0; c < 4; ++c) {
      float sc[16];
      float cm = -1e30f;
#pragma unroll
      for (int jj = 0; jj < 16; ++jj) {
        const float* kk = k_lds + (c * 16 + jj) * 16;
        float acc = 0.0f;
#pragma unroll
        for (int d = 0; d < 16; ++d) acc = fmaf(qv[d], kk[d], acc);
        float sv = fmaf(acc, 0.25f, bp[(c * 16 + jj) * 1024]);  // scale=1/sqrt(16)
        sc[jj] = sv;
        cm = fmaxf(cm, sv);
      }
      float mnew = fmaxf(m, cm);
      float alpha = __expf(m - mnew);
      l *= alpha;
#pragma unroll
      for (int d = 0; d < 16; ++d) o[d] *= alpha;
#pragma unroll
      for (int jj = 0; jj < 16; ++jj) {
        float pe = __expf(sc[jj] - mnew);
        l += pe;
        const float* vv = v_lds + (c * 16 + jj) * 16;
#pragma unroll
        for (int d = 0; d < 16; ++d) o[d] = fmaf(pe, vv[d], o[d]);
      }
      m = mnew;
    }
  }
  // merge the 4 k-range partials (log-sum-exp)
  __syncthreads();
  float* pm = smem;        // [4][64]
  float* pl = smem + 256;  // [4][64]
  float* po = smem + 512;  // [4][64][16]
  pm[p * 64 + r] = m;
  pl[p * 64 + r] = l;
#pragma unroll
  for (int d = 0; d < 16; ++d) po[(p * 64 + r) * 16 + d] = o[d];
  __syncthreads();
  if (t < 64) {
    float M = pm[t];
#pragma unroll
    for (int pp = 1; pp < 4; ++pp) M = fmaxf(M, pm[pp * 64 + t]);
    float Ls = 0.0f;
    float O[16];
#pragma unroll
    for (int d = 0; d < 16; ++d) O[d] = 0.0f;
#pragma unroll
    for (int pp = 0; pp < 4; ++pp) {
      float al = __expf(pm[pp * 64 + t] - M);
      Ls = fmaf(pl[pp * 64 + t], al, Ls);
#pragma unroll
      for (int d = 0; d < 16; ++d) O[d] = fmaf(po[(pp * 64 + t) * 16 + d], al, O[d]);
    }
    float inv = 1.0f / Ls;
    float* op = og + (size_t)(b * 1024 + qt * 64 + t) * 128 + h * 16;
#pragma unroll
    for (int d = 0; d < 16; d += 4) {
      float4 f;
      f.x = O[d] * inv; f.y = O[d + 1] * inv; f.z = O[d + 2] * inv; f.w = O[d + 3] * inv;
      *(float4*)(op + d) = f;
    }
  }
}

// ---------------------------------------------------------------------------
// K5: x += o @ Wo + bo.  8 tokens per block.
// ---------------------------------------------------------------------------
__global__ __launch_bounds__(256) void k_proj(
    const float* __restrict__ og, const float* __restrict__ Wo,
    const float* __restrict__ bo, float* __restrict__ x, int lay) {
  __shared__ float o_lds[8][128];
  int t = threadIdx.x;
  int base = blockIdx.x * 8;
  for (int idx = t; idx < 1024; idx += 256) {
    int tok = idx >> 7, i = idx & 127;
    o_lds[tok][i] = og[(size_t)(base + tok) * 128 + i];
  }
  __syncthreads();
  int d = t & 63, g = t >> 6;
  const float* W = Wo + lay * 128 * 64;
  float bb = bo[lay * 64 + d];
  float a0 = bb, a1 = bb;
  for (int i = 0; i < 128; ++i) {
    float w = W[i * 64 + d];
    a0 = fmaf(o_lds[g][i], w, a0);
    a1 = fmaf(o_lds[g + 4][i], w, a1);
  }
  x[(base + g) * 64 + d] += a0;
  x[(base + g + 4) * 64 + d] += a1;
}

// ---------------------------------------------------------------------------
// K6: x += gelu(LN(x;ln2) @ W1 + b1) @ W2 + b2.  4 tokens per block.
// ---------------------------------------------------------------------------
__global__ __launch_bounds__(256) void k_ffn(
    float* __restrict__ x, const float* __restrict__ ln_s,
    const float* __restrict__ ln_b, const float* __restrict__ W1,
    const float* __restrict__ b1, const float* __restrict__ W2,
    const float* __restrict__ b2, int lay) {
  __shared__ float h2[4][64];
  __shared__ float hid[4][256];
  int t = threadIdx.x, w = t >> 6, lane = t & 63;
  int bl = blockIdx.x * 4 + w;
  float xv = x[bl * 64 + lane];
  float mean = wave_reduce_sum(xv) * (1.0f / 64.0f);
  float diff = xv - mean;
  float var = wave_reduce_sum(diff * diff) * (1.0f / 64.0f);
  h2[w][lane] = diff * rsqrtf(var + 1e-6f) * ln_s[lay * 64 + lane] + ln_b[lay * 64 + lane];
  __syncthreads();
  const float* Wa = W1 + lay * 64 * 256;
  float bb = b1[lay * 256 + t];
  float hacc[4];
#pragma unroll
  for (int tok = 0; tok < 4; ++tok) hacc[tok] = bb;
  for (int i = 0; i < 64; ++i) {
    float wv = Wa[i * 256 + t];
#pragma unroll
    for (int tok = 0; tok < 4; ++tok) hacc[tok] = fmaf(h2[tok][i], wv, hacc[tok]);
  }
#pragma unroll
  for (int tok = 0; tok < 4; ++tok) hid[tok][t] = gelu_tanh(hacc[tok]);
  __syncthreads();
  const float* Wb = W2 + lay * 256 * 64;
  float acc = b2[lay * 64 + lane];
  for (int i = 0; i < 256; ++i) acc = fmaf(hid[w][i], Wb[i * 64 + lane], acc);
  x[bl * 64 + lane] = xv + acc;  // residual: tok==w, d==lane is this thread's own
}

// ---------------------------------------------------------------------------
// K7: head MLP: gelu(x@Wh1+bh1) -> gelu(@Wh2+bh2) -> @Wh3+bh3. 4 tokens/block.
// ---------------------------------------------------------------------------
__global__ __launch_bounds__(256) void k_head(
    const float* __restrict__ x, const float* __restrict__ Wh1,
    const float* __restrict__ bh1, const float* __restrict__ Wh2,
    const float* __restrict__ bh2, const float* __restrict__ Wh3,
    const float* __restrict__ bh3, float* __restrict__ out) {
  __shared__ float xr[4][64];
  __shared__ float h1[4][256];
  __shared__ float h2s[4][64];
  int t = threadIdx.x, w = t >> 6, lane = t & 63;
  int base = blockIdx.x * 4;
  xr[w][lane] = x[(base + w) * 64 + lane];
  __syncthreads();
  float bb = bh1[t];
  float acc1[4];
#pragma unroll
  for (int tok = 0; tok < 4; ++tok) acc1[tok] = bb;
  for (int i = 0; i < 64; ++i) {
    float wv = Wh1[i * 256 + t];
#pragma unroll
    for (int tok = 0; tok < 4; ++tok) acc1[tok] = fmaf(xr[tok][i], wv, acc1[tok]);
  }
#pragma unroll
  for (int tok = 0; tok < 4; ++tok) h1[tok][t] = gelu_tanh(acc1[tok]);
  __syncthreads();
  {
    float acc = bh2[lane];
    for (int i = 0; i < 256; ++i) acc = fmaf(h1[w][i], Wh2[i * 64 + lane], acc);
    h2s[w][lane] = gelu_tanh(acc);
  }
  __syncthreads();
  {
    float v = h2s[w][lane] * Wh3[lane];
    float sum = wave_reduce_sum(v);
    if (lane == 0) out[base + w] = sum + bh3[0];
  }
}

// ---------------------------------------------------------------------------
extern "C" void kernel_launch(void* const* d_in, const int* in_sizes, int n_in,
                              void* d_out, int out_size, void* d_ws, size_t ws_size,
                              hipStream_t stream) {
  const float* z      = (const float*)d_in[0];
  const float* cond   = (const float*)d_in[1];
  const float* s      = (const float*)d_in[2];
  const float* embed  = (const float*)d_in[3];
  const float* Win1   = (const float*)d_in[4];
  const float* bin1   = (const float*)d_in[5];
  const float* Win2   = (const float*)d_in[6];
  const float* bin2   = (const float*)d_in[7];
  const float* ln1_s  = (const float*)d_in[8];
  const float* ln1_b  = (const float*)d_in[9];
  const float* ln2_s  = (const float*)d_in[10];
  const float* ln2_b  = (const float*)d_in[11];
  const float* Wq     = (const float*)d_in[12];
  const float* bq     = (const float*)d_in[13];
  const float* Wk     = (const float*)d_in[14];
  const float* bk     = (const float*)d_in[15];
  const float* Wv     = (const float*)d_in[16];
  const float* bv     = (const float*)d_in[17];
  const float* Wo     = (const float*)d_in[18];
  const float* bo     = (const float*)d_in[19];
  const float* rbf_c  = (const float*)d_in[20];
  const float* rbf_lw = (const float*)d_in[21];
  const float* rbf_w  = (const float*)d_in[22];
  const float* rbf_b  = (const float*)d_in[23];
  const float* W1     = (const float*)d_in[24];
  const float* b1     = (const float*)d_in[25];
  const float* W2     = (const float*)d_in[26];
  const float* b2     = (const float*)d_in[27];
  const float* Wh1    = (const float*)d_in[28];
  const float* bh1    = (const float*)d_in[29];
  const float* Wh2    = (const float*)d_in[30];
  const float* bh2    = (const float*)d_in[31];
  const float* Wh3    = (const float*)d_in[32];
  const float* bh3    = (const float*)d_in[33];

  float* ws = (float*)d_ws;
  float* x     = ws;                                    // 524288
  float* qb    = x  + (size_t)BB * LL * DD;             // 1048576
  float* kb    = qb + (size_t)BB * HH * LL * DH;        // 1048576
  float* vb    = kb + (size_t)BB * HH * LL * DH;        // 1048576
  float* ob    = vb + (size_t)BB * HH * LL * DH;        // 1048576
  float* biasT = ob + (size_t)BB * LL * D2;             // 8388608 (33.5 MB)

  k_input_mlp<<<1024, 256, 0, stream>>>(embed, z, cond, Win1, bin1, Win2, bin2, x);
  for (int lay = 0; lay < 2; ++lay) {
    k_bias<<<4096, 256, 0, stream>>>(s, rbf_c, rbf_lw, rbf_w, rbf_b, biasT, lay);
    k_ln_qkv<<<2048, 256, 0, stream>>>(x, ln1_s, ln1_b, Wq, bq, Wk, bk, Wv, bv,
                                       qb, kb, vb, lay);
    k_attn<<<1024, 256, 0, stream>>>(qb, kb, vb, biasT, ob);
    k_proj<<<1024, 256, 0, stream>>>(ob, Wo, bo, x, lay);
    k_ffn<<<2048, 256, 0, stream>>>(x, ln2_s, ln2_b, W1, b1, W2, b2, lay);
  }
  k_head<<<2048, 256, 0, stream>>>(x, Wh1, bh1, Wh2, bh2, Wh3, bh3, (float*)d_out);
}

// Round 2
// 486.588 us; speedup vs baseline: 1.9990x; 1.9990x over previous
//
#include <hip/hip_runtime.h>
#include <hip/hip_bf16.h>

// Problem constants (reference: B=8, L=1024, C=4, D=64, H=8, NB=2, K=16)
#define BB   8
#define LL   1024
#define DD   64
#define D2   128
#define D4   256
#define HH   8
#define DH   16

__device__ __forceinline__ float gelu_tanh(float u) {
  float t = tanhf(0.7978845608028654f * (u + 0.044715f * u * u * u));
  return 0.5f * u * (1.0f + t);
}

__device__ __forceinline__ float wave_reduce_sum(float v) {
#pragma unroll
  for (int m = 32; m >= 1; m >>= 1) v += __shfl_xor(v, m, 64);
  return v;
}

// ---------------------------------------------------------------------------
// K1: input MLP. 16 tokens/block, weights staged in LDS, 2tok x 8out tiles.
// ---------------------------------------------------------------------------
__global__ __launch_bounds__(256) void k_input_mlp(
    const float* __restrict__ embed, const float* __restrict__ z,
    const float* __restrict__ cond, const float* __restrict__ Win1,
    const float* __restrict__ bin1, const float* __restrict__ Win2,
    const float* __restrict__ bin2, float* __restrict__ x) {
  __shared__ float feats[16 * 128];  // 8 KB
  __shared__ float hid[16 * 256];    // 16 KB
  __shared__ float Wl[32 * 256];     // 32 KB
  int t = threadIdx.x;
  int tok0 = blockIdx.x * 16;
  for (int idx = t; idx < 16 * 128; idx += 256) {
    int tok = idx >> 7, dim = idx & 127;
    int bl = tok0 + tok, l = bl & (LL - 1);
    float v;
    if (dim < 123) v = embed[l * 123 + dim];
    else if (dim == 123) v = z[bl];
    else v = cond[dim - 124];
    feats[idx] = v;
  }
  // GEMM1: 128 -> 256, gelu
  {
    int tg = t >> 5, og8 = (t & 31) * 8;
    float acc[2][8];
    float4 b0 = *(const float4*)(bin1 + og8);
    float4 b1 = *(const float4*)(bin1 + og8 + 4);
#pragma unroll
    for (int c = 0; c < 2; ++c) {
      acc[c][0] = b0.x; acc[c][1] = b0.y; acc[c][2] = b0.z; acc[c][3] = b0.w;
      acc[c][4] = b1.x; acc[c][5] = b1.y; acc[c][6] = b1.z; acc[c][7] = b1.w;
    }
#pragma unroll 1
    for (int ch = 0; ch < 4; ++ch) {
      __syncthreads();
      for (int idx = t * 4; idx < 32 * 256; idx += 1024)
        *(float4*)(Wl + idx) = *(const float4*)(Win1 + ch * 32 * 256 + idx);
      __syncthreads();
#pragma unroll 4
      for (int ii = 0; ii < 32; ++ii) {
        int i = ch * 32 + ii;
        float4 w0 = *(float4*)(Wl + ii * 256 + og8);
        float4 w1 = *(float4*)(Wl + ii * 256 + og8 + 4);
#pragma unroll
        for (int c = 0; c < 2; ++c) {
          float hv = feats[(tg * 2 + c) * 128 + i];
          acc[c][0] = fmaf(hv, w0.x, acc[c][0]);
          acc[c][1] = fmaf(hv, w0.y, acc[c][1]);
          acc[c][2] = fmaf(hv, w0.z, acc[c][2]);
          acc[c][3] = fmaf(hv, w0.w, acc[c][3]);
          acc[c][4] = fmaf(hv, w1.x, acc[c][4]);
          acc[c][5] = fmaf(hv, w1.y, acc[c][5]);
          acc[c][6] = fmaf(hv, w1.z, acc[c][6]);
          acc[c][7] = fmaf(hv, w1.w, acc[c][7]);
        }
      }
    }
#pragma unroll
    for (int c = 0; c < 2; ++c)
#pragma unroll
      for (int jj = 0; jj < 8; ++jj)
        hid[(tg * 2 + c) * 256 + og8 + jj] = gelu_tanh(acc[c][jj]);
  }
  // GEMM2: 256 -> 64
  {
    int tg = t >> 4, og4 = (t & 15) * 4;
    float4 acc = *(const float4*)(bin2 + og4);
#pragma unroll 1
    for (int ch = 0; ch < 2; ++ch) {
      __syncthreads();
      for (int idx = t * 4; idx < 128 * 64; idx += 1024)
        *(float4*)(Wl + idx) = *(const float4*)(Win2 + ch * 128 * 64 + idx);
      __syncthreads();
#pragma unroll 4
      for (int ii = 0; ii < 128; ++ii) {
        int i = ch * 128 + ii;
        float4 wv = *(float4*)(Wl + ii * 64 + og4);
        float hv = hid[tg * 256 + i];
        acc.x = fmaf(hv, wv.x, acc.x);
        acc.y = fmaf(hv, wv.y, acc.y);
        acc.z = fmaf(hv, wv.z, acc.z);
        acc.w = fmaf(hv, wv.w, acc.w);
      }
    }
    *(float4*)(x + (size_t)(tok0 + tg) * 64 + og4) = acc;
  }
}

// ---------------------------------------------------------------------------
// K2: RBF bias (batch-independent), biasT[h][k][q].
// ---------------------------------------------------------------------------
__global__ __launch_bounds__(256) void k_bias(
    const float* __restrict__ s, const float* __restrict__ rbf_c,
    const float* __restrict__ rbf_logw, const float* __restrict__ rbf_w,
    const float* __restrict__ rbf_b, float* __restrict__ biasT, int lay) {
  int id = blockIdx.x * 256 + threadIdx.x;
  int k = id >> 10, q = id & 1023;
  float dd = s[q] - s[k];
  float acc[8];
#pragma unroll
  for (int h = 0; h < 8; ++h) acc[h] = rbf_b[lay * 8 + h];
#pragma unroll 1
  for (int f = 0; f < 16; ++f) {
    float c = rbf_c[lay * 16 + f];
    float inv2w2 = 0.5f * __expf(-2.0f * rbf_logw[lay * 16 + f]);
    float e = dd - c;
    float ph = __expf(-e * e * inv2w2);
#pragma unroll
    for (int h = 0; h < 8; ++h)
      acc[h] = fmaf(ph, rbf_w[lay * 128 + f * 8 + h], acc[h]);
  }
#pragma unroll
  for (int h = 0; h < 8; ++h)
    biasT[(size_t)(h * 1024 + k) * 1024 + q] = acc[h];
}

// ---------------------------------------------------------------------------
// K3: LN + QKV. 16 tokens/block; W staged whole (64x128) per mat in LDS.
// ---------------------------------------------------------------------------
__global__ __launch_bounds__(256) void k_ln_qkv(
    const float* __restrict__ x, const float* __restrict__ ln_s,
    const float* __restrict__ ln_b, const float* __restrict__ Wq,
    const float* __restrict__ bq, const float* __restrict__ Wk,
    const float* __restrict__ bk, const float* __restrict__ Wv,
    const float* __restrict__ bv, float* __restrict__ qo,
    float* __restrict__ ko, float* __restrict__ vo, int lay) {
  __shared__ float hs[16 * 64];  // 4 KB
  __shared__ float Wl[64 * 128]; // 32 KB
  int t = threadIdx.x, w = t >> 6, lane = t & 63;
  int tok0 = blockIdx.x * 16;
  float ss = ln_s[lay * 64 + lane], sb = ln_b[lay * 64 + lane];
#pragma unroll
  for (int tk = 0; tk < 4; ++tk) {
    int tok = w * 4 + tk;
    float v = x[(size_t)(tok0 + tok) * 64 + lane];
    float mean = wave_reduce_sum(v) * 0.015625f;
    float d = v - mean;
    float var = wave_reduce_sum(d * d) * 0.015625f;
    hs[tok * 64 + lane] = d * rsqrtf(var + 1e-6f) * ss + sb;
  }
  int tg = t >> 5, og = t & 31;  // 2 toks, 4 outs
  int b = tok0 >> 10, l0 = tok0 & 1023;
  int j = og * 4, h = j >> 4, jo = j & 15;
#pragma unroll 1
  for (int mat = 0; mat < 3; ++mat) {
    const float* W = (mat == 0 ? Wq : mat == 1 ? Wk : Wv) + lay * 64 * 128;
    const float* bias = (mat == 0 ? bq : mat == 1 ? bk : bv) + lay * 128;
    float* outp = (mat == 0 ? qo : mat == 1 ? ko : vo);
    __syncthreads();
    for (int idx = t * 4; idx < 64 * 128; idx += 1024)
      *(float4*)(Wl + idx) = *(const float4*)(W + idx);
    __syncthreads();
    float4 bb = *(const float4*)(bias + j);
    float acc[2][4];
#pragma unroll
    for (int c = 0; c < 2; ++c) {
      acc[c][0] = bb.x; acc[c][1] = bb.y; acc[c][2] = bb.z; acc[c][3] = bb.w;
    }
#pragma unroll 4
    for (int i = 0; i < 64; ++i) {
      float4 wv = *(float4*)(Wl + i * 128 + j);
#pragma unroll
      for (int c = 0; c < 2; ++c) {
        float hv = hs[(tg * 2 + c) * 64 + i];
        acc[c][0] = fmaf(hv, wv.x, acc[c][0]);
        acc[c][1] = fmaf(hv, wv.y, acc[c][1]);
        acc[c][2] = fmaf(hv, wv.z, acc[c][2]);
        acc[c][3] = fmaf(hv, wv.w, acc[c][3]);
      }
    }
#pragma unroll
    for (int c = 0; c < 2; ++c) {
      int l = l0 + tg * 2 + c;
      float4 o4;
      o4.x = acc[c][0]; o4.y = acc[c][1]; o4.z = acc[c][2]; o4.w = acc[c][3];
      *(float4*)(outp + (size_t)((b * 8 + h) * 1024 + l) * 16 + jo) = o4;
    }
  }
}

// ---------------------------------------------------------------------------
// K4: flash attention per (b, h, 64 q-rows); 4 waves split key range.
// ---------------------------------------------------------------------------
__global__ __launch_bounds__(256) void k_attn(
    const float* __restrict__ qg, const float* __restrict__ kg,
    const float* __restrict__ vg, const float* __restrict__ biasT,
    float* __restrict__ og) {
  __shared__ float smem[8192];
  int t = threadIdx.x, p = t >> 6, r = t & 63;
  int bid = blockIdx.x;
  int b = bid >> 7;
  int h = (bid >> 4) & 7;
  int qt = bid & 15;
  int qrow = qt * 64 + r;
  const float* qp = qg + (size_t)((b * 8 + h) * 1024 + qrow) * 16;
  float qv[16];
#pragma unroll
  for (int d = 0; d < 16; d += 4) {
    float4 f = *(const float4*)(qp + d);
    qv[d] = f.x; qv[d + 1] = f.y; qv[d + 2] = f.z; qv[d + 3] = f.w;
  }
  float m = -1e30f, l = 0.0f;
  float o[16];
#pragma unroll
  for (int d = 0; d < 16; ++d) o[d] = 0.0f;
  float* k_lds = smem + p * 1024;
  float* v_lds = smem + 4096 + p * 1024;
#pragma unroll 1
  for (int tile = 0; tile < 4; ++tile) {
    int k0 = p * 256 + tile * 64;
    const float* kp = kg + (size_t)((b * 8 + h) * 1024 + k0 + r) * 16;
    const float* vp = vg + (size_t)((b * 8 + h) * 1024 + k0 + r) * 16;
    __syncthreads();
#pragma unroll
    for (int d = 0; d < 16; d += 4) {
      *(float4*)(k_lds + r * 16 + d) = *(const float4*)(kp + d);
      *(float4*)(v_lds + r * 16 + d) = *(const float4*)(vp + d);
    }
    __syncthreads();
    const float* bp = biasT + (size_t)(h * 1024 + k0) * 1024 + qrow;
#pragma unroll 1
    for (int c = 0; c < 4; ++c) {
      float sc[16];
      float cm = -1e30f;
#pragma unroll
      for (int jj = 0; jj < 16; ++jj) {
        const float* kk = k_lds + (c * 16 + jj) * 16;
        float acc = 0.0f;
#pragma unroll
        for (int d = 0; d < 16; ++d) acc = fmaf(qv[d], kk[d], acc);
        float sv = fmaf(acc, 0.25f, bp[(c * 16 + jj) * 1024]);
        sc[jj] = sv;
        cm = fmaxf(cm, sv);
      }
      float mnew = fmaxf(m, cm);
      float alpha = __expf(m - mnew);
      l *= alpha;
#pragma unroll
      for (int d = 0; d < 16; ++d) o[d] *= alpha;
#pragma unroll
      for (int jj = 0; jj < 16; ++jj) {
        float pe = __expf(sc[jj] - mnew);
        l += pe;
        const float* vv = v_lds + (c * 16 + jj) * 16;
#pragma unroll
        for (int d = 0; d < 16; ++d) o[d] = fmaf(pe, vv[d], o[d]);
      }
      m = mnew;
    }
  }
  __syncthreads();
  float* pm = smem;
  float* pl = smem + 256;
  float* po = smem + 512;
  pm[p * 64 + r] = m;
  pl[p * 64 + r] = l;
#pragma unroll
  for (int d = 0; d < 16; ++d) po[(p * 64 + r) * 16 + d] = o[d];
  __syncthreads();
  if (t < 64) {
    float M = pm[t];
#pragma unroll
    for (int pp = 1; pp < 4; ++pp) M = fmaxf(M, pm[pp * 64 + t]);
    float Ls = 0.0f;
    float O[16];
#pragma unroll
    for (int d = 0; d < 16; ++d) O[d] = 0.0f;
#pragma unroll
    for (int pp = 0; pp < 4; ++pp) {
      float al = __expf(pm[pp * 64 + t] - M);
      Ls = fmaf(pl[pp * 64 + t], al, Ls);
#pragma unroll
      for (int d = 0; d < 16; ++d) O[d] = fmaf(po[(pp * 64 + t) * 16 + d], al, O[d]);
    }
    float inv = 1.0f / Ls;
    float* op = og + (size_t)(b * 1024 + qt * 64 + t) * 128 + h * 16;
#pragma unroll
    for (int d = 0; d < 16; d += 4) {
      float4 f;
      f.x = O[d] * inv; f.y = O[d + 1] * inv; f.z = O[d + 2] * inv; f.w = O[d + 3] * inv;
      *(float4*)(op + d) = f;
    }
  }
}

// ---------------------------------------------------------------------------
// K5: x += o @ Wo + bo. 16 tokens/block, Wo staged whole.
// ---------------------------------------------------------------------------
__global__ __launch_bounds__(256) void k_proj(
    const float* __restrict__ og_, const float* __restrict__ Wo,
    const float* __restrict__ bo, float* __restrict__ x, int lay) {
  __shared__ float ol[16 * 128];  // 8 KB
  __shared__ float Wl[128 * 64];  // 32 KB
  int t = threadIdx.x;
  int tok0 = blockIdx.x * 16;
  for (int idx = t * 4; idx < 16 * 128; idx += 1024)
    *(float4*)(ol + idx) = *(const float4*)(og_ + (size_t)tok0 * 128 + idx);
  for (int idx = t * 4; idx < 128 * 64; idx += 1024)
    *(float4*)(Wl + idx) = *(const float4*)(Wo + lay * 128 * 64 + idx);
  __syncthreads();
  int tg = t >> 4, og4 = (t & 15) * 4;
  float4 acc = *(const float4*)(bo + lay * 64 + og4);
#pragma unroll 4
  for (int i = 0; i < 128; ++i) {
    float4 wv = *(float4*)(Wl + i * 64 + og4);
    float hv = ol[tg * 128 + i];
    acc.x = fmaf(hv, wv.x, acc.x);
    acc.y = fmaf(hv, wv.y, acc.y);
    acc.z = fmaf(hv, wv.z, acc.z);
    acc.w = fmaf(hv, wv.w, acc.w);
  }
  float* xp = x + (size_t)(tok0 + tg) * 64 + og4;
  float4 xv = *(float4*)xp;
  xv.x += acc.x; xv.y += acc.y; xv.z += acc.z; xv.w += acc.w;
  *(float4*)xp = xv;
}

// ---------------------------------------------------------------------------
// K6: FFN. 16 tokens/block, LDS-staged weights.
// ---------------------------------------------------------------------------
__global__ __launch_bounds__(256) void k_ffn(
    float* __restrict__ x, const float* __restrict__ ln_s,
    const float* __restrict__ ln_b, const float* __restrict__ W1,
    const float* __restrict__ b1, const float* __restrict__ W2,
    const float* __restrict__ b2, int lay) {
  __shared__ float hs[16 * 64];    // 4 KB
  __shared__ float hid[16 * 256];  // 16 KB
  __shared__ float Wl[32 * 256];   // 32 KB
  int t = threadIdx.x, w = t >> 6, lane = t & 63;
  int tok0 = blockIdx.x * 16;
  float ss = ln_s[lay * 64 + lane], sb = ln_b[lay * 64 + lane];
#pragma unroll
  for (int tk = 0; tk < 4; ++tk) {
    int tok = w * 4 + tk;
    float v = x[(size_t)(tok0 + tok) * 64 + lane];
    float mean = wave_reduce_sum(v) * 0.015625f;
    float d = v - mean;
    float var = wave_reduce_sum(d * d) * 0.015625f;
    hs[tok * 64 + lane] = d * rsqrtf(var + 1e-6f) * ss + sb;
  }
  // GEMM1: 64 -> 256 gelu (2 chunks of 32 rows)
  {
    int tg = t >> 5, og8 = (t & 31) * 8;
    float acc[2][8];
    float4 b0 = *(const float4*)(b1 + lay * 256 + og8);
    float4 b1v = *(const float4*)(b1 + lay * 256 + og8 + 4);
#pragma unroll
    for (int c = 0; c < 2; ++c) {
      acc[c][0] = b0.x; acc[c][1] = b0.y; acc[c][2] = b0.z; acc[c][3] = b0.w;
      acc[c][4] = b1v.x; acc[c][5] = b1v.y; acc[c][6] = b1v.z; acc[c][7] = b1v.w;
    }
#pragma unroll 1
    for (int ch = 0; ch < 2; ++ch) {
      __syncthreads();
      for (int idx = t * 4; idx < 32 * 256; idx += 1024)
        *(float4*)(Wl + idx) = *(const float4*)(W1 + lay * 64 * 256 + ch * 32 * 256 + idx);
      __syncthreads();
#pragma unroll 4
      for (int ii = 0; ii < 32; ++ii) {
        int i = ch * 32 + ii;
        float4 w0 = *(float4*)(Wl + ii * 256 + og8);
        float4 w1 = *(float4*)(Wl + ii * 256 + og8 + 4);
#pragma unroll
        for (int c = 0; c < 2; ++c) {
          float hv = hs[(tg * 2 + c) * 64 + i];
          acc[c][0] = fmaf(hv, w0.x, acc[c][0]);
          acc[c][1] = fmaf(hv, w0.y, acc[c][1]);
          acc[c][2] = fmaf(hv, w0.z, acc[c][2]);
          acc[c][3] = fmaf(hv, w0.w, acc[c][3]);
          acc[c][4] = fmaf(hv, w1.x, acc[c][4]);
          acc[c][5] = fmaf(hv, w1.y, acc[c][5]);
          acc[c][6] = fmaf(hv, w1.z, acc[c][6]);
          acc[c][7] = fmaf(hv, w1.w, acc[c][7]);
        }
      }
    }
#pragma unroll
    for (int c = 0; c < 2; ++c)
#pragma unroll
      for (int jj = 0; jj < 8; ++jj)
        hid[(tg * 2 + c) * 256 + og8 + jj] = gelu_tanh(acc[c][jj]);
  }
  // GEMM2: 256 -> 64 + residual
  {
    int tg = t >> 4, og4 = (t & 15) * 4;
    float4 acc = *(const float4*)(b2 + lay * 64 + og4);
#pragma unroll 1
    for (int ch = 0; ch < 2; ++ch) {
      __syncthreads();
      for (int idx = t * 4; idx < 128 * 64; idx += 1024)
        *(float4*)(Wl + idx) = *(const float4*)(W2 + lay * 256 * 64 + ch * 128 * 64 + idx);
      __syncthreads();
#pragma unroll 4
      for (int ii = 0; ii < 128; ++ii) {
        int i = ch * 128 + ii;
        float4 wv = *(float4*)(Wl + ii * 64 + og4);
        float hv = hid[tg * 256 + i];
        acc.x = fmaf(hv, wv.x, acc.x);
        acc.y = fmaf(hv, wv.y, acc.y);
        acc.z = fmaf(hv, wv.z, acc.z);
        acc.w = fmaf(hv, wv.w, acc.w);
      }
    }
    float* xp = x + (size_t)(tok0 + tg) * 64 + og4;
    float4 xv = *(float4*)xp;
    xv.x += acc.x; xv.y += acc.y; xv.z += acc.z; xv.w += acc.w;
    *(float4*)xp = xv;
  }
}

// ---------------------------------------------------------------------------
// K7: head MLP. 16 tokens/block.
// ---------------------------------------------------------------------------
__global__ __launch_bounds__(256) void k_head(
    const float* __restrict__ x, const float* __restrict__ Wh1,
    const float* __restrict__ bh1, const float* __restrict__ Wh2,
    const float* __restrict__ bh2, const float* __restrict__ Wh3,
    const float* __restrict__ bh3, float* __restrict__ out) {
  __shared__ float xl[16 * 64];    // 4 KB
  __shared__ float hid[16 * 256];  // 16 KB
  __shared__ float h2s[16 * 64];   // 4 KB
  __shared__ float Wl[32 * 256];   // 32 KB
  int t = threadIdx.x;
  int tok0 = blockIdx.x * 16;
  {
    int idx = t * 4;
    *(float4*)(xl + idx) = *(const float4*)(x + (size_t)tok0 * 64 + idx);
  }
  // GEMM1: 64 -> 256 gelu
  {
    int tg = t >> 5, og8 = (t & 31) * 8;
    float acc[2][8];
    float4 b0 = *(const float4*)(bh1 + og8);
    float4 b1v = *(const float4*)(bh1 + og8 + 4);
#pragma unroll
    for (int c = 0; c < 2; ++c) {
      acc[c][0] = b0.x; acc[c][1] = b0.y; acc[c][2] = b0.z; acc[c][3] = b0.w;
      acc[c][4] = b1v.x; acc[c][5] = b1v.y; acc[c][6] = b1v.z; acc[c][7] = b1v.w;
    }
#pragma unroll 1
    for (int ch = 0; ch < 2; ++ch) {
      __syncthreads();
      for (int idx = t * 4; idx < 32 * 256; idx += 1024)
        *(float4*)(Wl + idx) = *(const float4*)(Wh1 + ch * 32 * 256 + idx);
      __syncthreads();
#pragma unroll 4
      for (int ii = 0; ii < 32; ++ii) {
        int i = ch * 32 + ii;
        float4 w0 = *(float4*)(Wl + ii * 256 + og8);
        float4 w1 = *(float4*)(Wl + ii * 256 + og8 + 4);
#pragma unroll
        for (int c = 0; c < 2; ++c) {
          float hv = xl[(tg * 2 + c) * 64 + i];
          acc[c][0] = fmaf(hv, w0.x, acc[c][0]);
          acc[c][1] = fmaf(hv, w0.y, acc[c][1]);
          acc[c][2] = fmaf(hv, w0.z, acc[c][2]);
          acc[c][3] = fmaf(hv, w0.w, acc[c][3]);
          acc[c][4] = fmaf(hv, w1.x, acc[c][4]);
          acc[c][5] = fmaf(hv, w1.y, acc[c][5]);
          acc[c][6] = fmaf(hv, w1.z, acc[c][6]);
          acc[c][7] = fmaf(hv, w1.w, acc[c][7]);
        }
      }
    }
#pragma unroll
    for (int c = 0; c < 2; ++c)
#pragma unroll
      for (int jj = 0; jj < 8; ++jj)
        hid[(tg * 2 + c) * 256 + og8 + jj] = gelu_tanh(acc[c][jj]);
  }
  // GEMM2: 256 -> 64 gelu
  {
    int tg = t >> 4, og4 = (t & 15) * 4;
    float4 acc = *(const float4*)(bh2 + og4);
#pragma unroll 1
    for (int ch = 0; ch < 2; ++ch) {
      __syncthreads();
      for (int idx = t * 4; idx < 128 * 64; idx += 1024)
        *(float4*)(Wl + idx) = *(const float4*)(Wh2 + ch * 128 * 64 + idx);
      __syncthreads();
#pragma unroll 4
      for (int ii = 0; ii < 128; ++ii) {
        int i = ch * 128 + ii;
        float4 wv = *(float4*)(Wl + ii * 64 + og4);
        float hv = hid[tg * 256 + i];
        acc.x = fmaf(hv, wv.x, acc.x);
        acc.y = fmaf(hv, wv.y, acc.y);
        acc.z = fmaf(hv, wv.z, acc.z);
        acc.w = fmaf(hv, wv.w, acc.w);
      }
    }
    float4 g;
    g.x = gelu_tanh(acc.x); g.y = gelu_tanh(acc.y);
    g.z = gelu_tanh(acc.z); g.w = gelu_tanh(acc.w);
    *(float4*)(h2s + tg * 64 + og4) = g;
  }
  __syncthreads();
  // GEMM3: dot with Wh3
  int w = t >> 6, lane = t & 63;
  float wv3 = Wh3[lane];
#pragma unroll
  for (int tk = 0; tk < 4; ++tk) {
    int tok = w * 4 + tk;
    float v = h2s[tok * 64 + lane] * wv3;
    float sum = wave_reduce_sum(v);
    if (lane == 0) out[tok0 + tok] = sum + bh3[0];
  }
}

// ---------------------------------------------------------------------------
extern "C" void kernel_launch(void* const* d_in, const int* in_sizes, int n_in,
                              void* d_out, int out_size, void* d_ws, size_t ws_size,
                              hipStream_t stream) {
  const float* z      = (const float*)d_in[0];
  const float* cond   = (const float*)d_in[1];
  const float* s      = (const float*)d_in[2];
  const float* embed  = (const float*)d_in[3];
  const float* Win1   = (const float*)d_in[4];
  const float* bin1   = (const float*)d_in[5];
  const float* Win2   = (const float*)d_in[6];
  const float* bin2   = (const float*)d_in[7];
  const float* ln1_s  = (const float*)d_in[8];
  const float* ln1_b  = (const float*)d_in[9];
  const float* ln2_s  = (const float*)d_in[10];
  const float* ln2_b  = (const float*)d_in[11];
  const float* Wq     = (const float*)d_in[12];
  const float* bq     = (const float*)d_in[13];
  const float* Wk     = (const float*)d_in[14];
  const float* bk     = (const float*)d_in[15];
  const float* Wv     = (const float*)d_in[16];
  const float* bv     = (const float*)d_in[17];
  const float* Wo     = (const float*)d_in[18];
  const float* bo     = (const float*)d_in[19];
  const float* rbf_c  = (const float*)d_in[20];
  const float* rbf_lw = (const float*)d_in[21];
  const float* rbf_w  = (const float*)d_in[22];
  const float* rbf_b  = (const float*)d_in[23];
  const float* W1     = (const float*)d_in[24];
  const float* b1     = (const float*)d_in[25];
  const float* W2     = (const float*)d_in[26];
  const float* b2     = (const float*)d_in[27];
  const float* Wh1    = (const float*)d_in[28];
  const float* bh1    = (const float*)d_in[29];
  const float* Wh2    = (const float*)d_in[30];
  const float* bh2    = (const float*)d_in[31];
  const float* Wh3    = (const float*)d_in[32];
  const float* bh3    = (const float*)d_in[33];

  float* ws = (float*)d_ws;
  float* x     = ws;
  float* qb    = x  + (size_t)BB * LL * DD;
  float* kb    = qb + (size_t)BB * HH * LL * DH;
  float* vb    = kb + (size_t)BB * HH * LL * DH;
  float* ob    = vb + (size_t)BB * HH * LL * DH;
  float* biasT = ob + (size_t)BB * LL * D2;

  k_input_mlp<<<512, 256, 0, stream>>>(embed, z, cond, Win1, bin1, Win2, bin2, x);
  for (int lay = 0; lay < 2; ++lay) {
    k_bias<<<4096, 256, 0, stream>>>(s, rbf_c, rbf_lw, rbf_w, rbf_b, biasT, lay);
    k_ln_qkv<<<512, 256, 0, stream>>>(x, ln1_s, ln1_b, Wq, bq, Wk, bk, Wv, bv,
                                      qb, kb, vb, lay);
    k_attn<<<1024, 256, 0, stream>>>(qb, kb, vb, biasT, ob);
    k_proj<<<512, 256, 0, stream>>>(ob, Wo, bo, x, lay);
    k_ffn<<<512, 256, 0, stream>>>(x, ln2_s, ln2_b, W1, b1, W2, b2, lay);
  }
  k_head<<<512, 256, 0, stream>>>(x, Wh1, bh1, Wh2, bh2, Wh3, bh3, (float*)d_out);
}

// Round 3
// 341.033 us; speedup vs baseline: 2.8521x; 1.4268x over previous
//
#include <hip/hip_runtime.h>
#include <hip/hip_bf16.h>

// Problem constants (reference: B=8, L=1024, C=4, D=64, H=8, NB=2, K=16)
#define BB   8
#define LL   1024
#define DD   64
#define D2   128
#define D4   256
#define HH   8
#define DH   16

typedef __attribute__((ext_vector_type(8))) short short8;   // 8 bf16 (4 VGPRs)
typedef __attribute__((ext_vector_type(4))) float floatx4;  // MFMA C/D

__device__ __forceinline__ float gelu_tanh(float u) {
  float t = tanhf(0.7978845608028654f * (u + 0.044715f * u * u * u));
  return 0.5f * u * (1.0f + t);
}

__device__ __forceinline__ float wave_reduce_sum(float v) {
#pragma unroll
  for (int m = 32; m >= 1; m >>= 1) v += __shfl_xor(v, m, 64);
  return v;
}

__device__ __forceinline__ unsigned short f2bf(float x) {  // RNE
  unsigned u = __float_as_uint(x);
  u += 0x7fffu + ((u >> 16) & 1u);
  return (unsigned short)(u >> 16);
}

// ---------------------------------------------------------------------------
// K1: input MLP. 16 tokens/block, weights staged in LDS, 2tok x 8out tiles.
// ---------------------------------------------------------------------------
__global__ __launch_bounds__(256) void k_input_mlp(
    const float* __restrict__ embed, const float* __restrict__ z,
    const float* __restrict__ cond, const float* __restrict__ Win1,
    const float* __restrict__ bin1, const float* __restrict__ Win2,
    const float* __restrict__ bin2, float* __restrict__ x) {
  __shared__ float feats[16 * 128];  // 8 KB
  __shared__ float hid[16 * 256];    // 16 KB
  __shared__ float Wl[32 * 256];     // 32 KB
  int t = threadIdx.x;
  int tok0 = blockIdx.x * 16;
  for (int idx = t; idx < 16 * 128; idx += 256) {
    int tok = idx >> 7, dim = idx & 127;
    int bl = tok0 + tok, l = bl & (LL - 1);
    float v;
    if (dim < 123) v = embed[l * 123 + dim];
    else if (dim == 123) v = z[bl];
    else v = cond[dim - 124];
    feats[idx] = v;
  }
  // GEMM1: 128 -> 256, gelu
  {
    int tg = t >> 5, og8 = (t & 31) * 8;
    float acc[2][8];
    float4 b0 = *(const float4*)(bin1 + og8);
    float4 b1 = *(const float4*)(bin1 + og8 + 4);
#pragma unroll
    for (int c = 0; c < 2; ++c) {
      acc[c][0] = b0.x; acc[c][1] = b0.y; acc[c][2] = b0.z; acc[c][3] = b0.w;
      acc[c][4] = b1.x; acc[c][5] = b1.y; acc[c][6] = b1.z; acc[c][7] = b1.w;
    }
#pragma unroll 1
    for (int ch = 0; ch < 4; ++ch) {
      __syncthreads();
      for (int idx = t * 4; idx < 32 * 256; idx += 1024)
        *(float4*)(Wl + idx) = *(const float4*)(Win1 + ch * 32 * 256 + idx);
      __syncthreads();
#pragma unroll 4
      for (int ii = 0; ii < 32; ++ii) {
        int i = ch * 32 + ii;
        float4 w0 = *(float4*)(Wl + ii * 256 + og8);
        float4 w1 = *(float4*)(Wl + ii * 256 + og8 + 4);
#pragma unroll
        for (int c = 0; c < 2; ++c) {
          float hv = feats[(tg * 2 + c) * 128 + i];
          acc[c][0] = fmaf(hv, w0.x, acc[c][0]);
          acc[c][1] = fmaf(hv, w0.y, acc[c][1]);
          acc[c][2] = fmaf(hv, w0.z, acc[c][2]);
          acc[c][3] = fmaf(hv, w0.w, acc[c][3]);
          acc[c][4] = fmaf(hv, w1.x, acc[c][4]);
          acc[c][5] = fmaf(hv, w1.y, acc[c][5]);
          acc[c][6] = fmaf(hv, w1.z, acc[c][6]);
          acc[c][7] = fmaf(hv, w1.w, acc[c][7]);
        }
      }
    }
#pragma unroll
    for (int c = 0; c < 2; ++c)
#pragma unroll
      for (int jj = 0; jj < 8; ++jj)
        hid[(tg * 2 + c) * 256 + og8 + jj] = gelu_tanh(acc[c][jj]);
  }
  // GEMM2: 256 -> 64
  {
    int tg = t >> 4, og4 = (t & 15) * 4;
    float4 acc = *(const float4*)(bin2 + og4);
#pragma unroll 1
    for (int ch = 0; ch < 2; ++ch) {
      __syncthreads();
      for (int idx = t * 4; idx < 128 * 64; idx += 1024)
        *(float4*)(Wl + idx) = *(const float4*)(Win2 + ch * 128 * 64 + idx);
      __syncthreads();
#pragma unroll 4
      for (int ii = 0; ii < 128; ++ii) {
        int i = ch * 128 + ii;
        float4 wv = *(float4*)(Wl + ii * 64 + og4);
        float hv = hid[tg * 256 + i];
        acc.x = fmaf(hv, wv.x, acc.x);
        acc.y = fmaf(hv, wv.y, acc.y);
        acc.z = fmaf(hv, wv.z, acc.z);
        acc.w = fmaf(hv, wv.w, acc.w);
      }
    }
    *(float4*)(x + (size_t)(tok0 + tg) * 64 + og4) = acc;
  }
}

// ---------------------------------------------------------------------------
// K2: RBF bias (batch-independent), biasT[h][k][q] fp32.
// ---------------------------------------------------------------------------
__global__ __launch_bounds__(256) void k_bias(
    const float* __restrict__ s, const float* __restrict__ rbf_c,
    const float* __restrict__ rbf_logw, const float* __restrict__ rbf_w,
    const float* __restrict__ rbf_b, float* __restrict__ biasT, int lay) {
  int id = blockIdx.x * 256 + threadIdx.x;
  int k = id >> 10, q = id & 1023;
  float dd = s[q] - s[k];
  float acc[8];
#pragma unroll
  for (int h = 0; h < 8; ++h) acc[h] = rbf_b[lay * 8 + h];
#pragma unroll 1
  for (int f = 0; f < 16; ++f) {
    float c = rbf_c[lay * 16 + f];
    float inv2w2 = 0.5f * __expf(-2.0f * rbf_logw[lay * 16 + f]);
    float e = dd - c;
    float ph = __expf(-e * e * inv2w2);
#pragma unroll
    for (int h = 0; h < 8; ++h)
      acc[h] = fmaf(ph, rbf_w[lay * 128 + f * 8 + h], acc[h]);
  }
#pragma unroll
  for (int h = 0; h < 8; ++h)
    biasT[(size_t)(h * 1024 + k) * 1024 + q] = acc[h];
}

// ---------------------------------------------------------------------------
// K3: LN + QKV -> bf16 outputs (b*8+h, l, 16) for MFMA attention.
// ---------------------------------------------------------------------------
__global__ __launch_bounds__(256) void k_ln_qkv(
    const float* __restrict__ x, const float* __restrict__ ln_s,
    const float* __restrict__ ln_b, const float* __restrict__ Wq,
    const float* __restrict__ bq, const float* __restrict__ Wk,
    const float* __restrict__ bk, const float* __restrict__ Wv,
    const float* __restrict__ bv, unsigned short* __restrict__ qo,
    unsigned short* __restrict__ ko, unsigned short* __restrict__ vo, int lay) {
  __shared__ float hs[16 * 64];  // 4 KB
  __shared__ float Wl[64 * 128]; // 32 KB
  int t = threadIdx.x, w = t >> 6, lane = t & 63;
  int tok0 = blockIdx.x * 16;
  float ss = ln_s[lay * 64 + lane], sb = ln_b[lay * 64 + lane];
#pragma unroll
  for (int tk = 0; tk < 4; ++tk) {
    int tok = w * 4 + tk;
    float v = x[(size_t)(tok0 + tok) * 64 + lane];
    float mean = wave_reduce_sum(v) * 0.015625f;
    float d = v - mean;
    float var = wave_reduce_sum(d * d) * 0.015625f;
    hs[tok * 64 + lane] = d * rsqrtf(var + 1e-6f) * ss + sb;
  }
  int tg = t >> 5, og = t & 31;  // 2 toks, 4 outs
  int b = tok0 >> 10, l0 = tok0 & 1023;
  int j = og * 4, h = j >> 4, jo = j & 15;
#pragma unroll 1
  for (int mat = 0; mat < 3; ++mat) {
    const float* W = (mat == 0 ? Wq : mat == 1 ? Wk : Wv) + lay * 64 * 128;
    const float* bias = (mat == 0 ? bq : mat == 1 ? bk : bv) + lay * 128;
    unsigned short* outp = (mat == 0 ? qo : mat == 1 ? ko : vo);
    __syncthreads();
    for (int idx = t * 4; idx < 64 * 128; idx += 1024)
      *(float4*)(Wl + idx) = *(const float4*)(W + idx);
    __syncthreads();
    float4 bb = *(const float4*)(bias + j);
    float acc[2][4];
#pragma unroll
    for (int c = 0; c < 2; ++c) {
      acc[c][0] = bb.x; acc[c][1] = bb.y; acc[c][2] = bb.z; acc[c][3] = bb.w;
    }
#pragma unroll 4
    for (int i = 0; i < 64; ++i) {
      float4 wv = *(float4*)(Wl + i * 128 + j);
#pragma unroll
      for (int c = 0; c < 2; ++c) {
        float hv = hs[(tg * 2 + c) * 64 + i];
        acc[c][0] = fmaf(hv, wv.x, acc[c][0]);
        acc[c][1] = fmaf(hv, wv.y, acc[c][1]);
        acc[c][2] = fmaf(hv, wv.z, acc[c][2]);
        acc[c][3] = fmaf(hv, wv.w, acc[c][3]);
      }
    }
#pragma unroll
    for (int c = 0; c < 2; ++c) {
      int l = l0 + tg * 2 + c;
      uint2 pk;
      pk.x = (unsigned)f2bf(acc[c][0]) | ((unsigned)f2bf(acc[c][1]) << 16);
      pk.y = (unsigned)f2bf(acc[c][2]) | ((unsigned)f2bf(acc[c][3]) << 16);
      *(uint2*)(outp + ((size_t)((b * 8 + h) * 1024 + l)) * 16 + jo) = pk;
    }
  }
}

// ---------------------------------------------------------------------------
// K4: MFMA flash attention. Block = (b, h, 64 q rows); 4 waves x 16 q each.
// Computes S^T = K.Q^T per 64-key chunk so softmaxed P lands in A-layout
// after a per-wave LDS bounce. dh=16 zero-padded to K=32 for QK^T.
// ---------------------------------------------------------------------------
__global__ __launch_bounds__(256) void k_attn(
    const unsigned short* __restrict__ qg, const unsigned short* __restrict__ kg,
    const unsigned short* __restrict__ vg, const float* __restrict__ biasT,
    float* __restrict__ og) {
  __shared__ __align__(16) unsigned short Kl[64 * 32];      // [key][d0..31], d16+ zero
  __shared__ __align__(16) unsigned short VT[16 * 72];      // [d][key], padded row 72
  __shared__ __align__(16) unsigned short Pl[4][16 * 72];   // per-wave [q][key], padded
  int t = threadIdx.x, w = t >> 6, lane = t & 63;
  int lq = lane & 15, quad = lane >> 4;
  int bid = blockIdx.x;
  int b = bid >> 7, h = (bid >> 4) & 7, qblk = bid & 15;
  int q0w = qblk * 64 + w * 16;
  size_t bh = (size_t)(b * 8 + h) * 1024;

  // zero Kl (covers the d16..31 pad; d0..15 rewritten per chunk)
  ((uint4*)Kl)[t] = uint4{0, 0, 0, 0};

  // B-frag of Q: quads 0,1 hold d=quad*8..+7; quads 2,3 zero (pad)
  short8 Qb = {};
  if (quad < 2)
    Qb = *(const short8*)(qg + (bh + q0w + lq) * 16 + quad * 8);

  float m = -1e30f, l = 0.0f;
  floatx4 O = {0.0f, 0.0f, 0.0f, 0.0f};

#pragma unroll 1
  for (int kc = 0; kc < 1024; kc += 64) {
    __syncthreads();
    // stage K chunk [64][16] and V^T chunk [16][64]
    {
      int key = t >> 2, dp = (t & 3) * 4;
      uint2 kv = *(const uint2*)(kg + (bh + kc + key) * 16 + dp);
      *(uint2*)(Kl + key * 32 + dp) = kv;
      uint2 vv = *(const uint2*)(vg + (bh + kc + key) * 16 + dp);
      VT[(dp + 0) * 72 + key] = (unsigned short)(vv.x & 0xffff);
      VT[(dp + 1) * 72 + key] = (unsigned short)(vv.x >> 16);
      VT[(dp + 2) * 72 + key] = (unsigned short)(vv.y & 0xffff);
      VT[(dp + 3) * 72 + key] = (unsigned short)(vv.y >> 16);
    }
    __syncthreads();
    // QK^T (transposed): 4 tiles of 16 keys
    float s[16];
#pragma unroll
    for (int tile = 0; tile < 4; ++tile) {
      short8 A = *(const short8*)(Kl + (tile * 16 + lq) * 32 + quad * 8);
      floatx4 c = {0.0f, 0.0f, 0.0f, 0.0f};
      c = __builtin_amdgcn_mfma_f32_16x16x32_bf16(A, Qb, c, 0, 0, 0);
      const float* bp = biasT +
          ((size_t)(h * 1024 + kc + tile * 16 + quad * 4)) * 1024 + q0w + lq;
#pragma unroll
      for (int r = 0; r < 4; ++r)
        s[tile * 4 + r] = fmaf(c[r], 0.25f, bp[r * 1024]);
    }
    // online softmax (state keyed by column q = lane&15)
    float cm = s[0];
#pragma unroll
    for (int i = 1; i < 16; ++i) cm = fmaxf(cm, s[i]);
    cm = fmaxf(cm, __shfl_xor(cm, 16, 64));
    cm = fmaxf(cm, __shfl_xor(cm, 32, 64));
    float mnew = fmaxf(m, cm);
    float alpha = __expf(m - mnew);
    float p[16], psum = 0.0f;
#pragma unroll
    for (int i = 0; i < 16; ++i) {
      p[i] = __expf(s[i] - mnew);
      psum += p[i];
    }
    psum += __shfl_xor(psum, 16, 64);
    psum += __shfl_xor(psum, 32, 64);
    l = l * alpha + psum;
    m = mnew;
    // P -> bf16 -> per-wave LDS (A-layout bounce)
    unsigned short* pw = &Pl[w][lq * 72];
#pragma unroll
    for (int tile = 0; tile < 4; ++tile) {
      uint2 pk;
      pk.x = (unsigned)f2bf(p[tile * 4 + 0]) | ((unsigned)f2bf(p[tile * 4 + 1]) << 16);
      pk.y = (unsigned)f2bf(p[tile * 4 + 2]) | ((unsigned)f2bf(p[tile * 4 + 3]) << 16);
      *(uint2*)(pw + tile * 16 + quad * 4) = pk;
    }
    asm volatile("s_waitcnt lgkmcnt(0)" ::: "memory");
    // rescale O (rows keyed q = quad*4+r): fetch alpha via bpermute
#pragma unroll
    for (int r = 0; r < 4; ++r) {
      int idx = (quad * 4 + r) * 4;
      float ar = __uint_as_float(
          __builtin_amdgcn_ds_bpermute(idx, __float_as_uint(alpha)));
      O[r] *= ar;
    }
    // PV: 2 MFMAs (K=32 keys each)
#pragma unroll
    for (int i = 0; i < 2; ++i) {
      short8 Pa = *(const short8*)(pw + i * 32 + quad * 8);
      short8 Vb = *(const short8*)(&VT[lq * 72 + i * 32 + quad * 8]);
      O = __builtin_amdgcn_mfma_f32_16x16x32_bf16(Pa, Vb, O, 0, 0, 0);
    }
  }
  // normalize and write out (O: row=q=quad*4+r, col=d=lane&15)
  float linv = 1.0f / l;
#pragma unroll
  for (int r = 0; r < 4; ++r) {
    int idx = (quad * 4 + r) * 4;
    float lr = __uint_as_float(
        __builtin_amdgcn_ds_bpermute(idx, __float_as_uint(linv)));
    og[((size_t)(b * 1024 + q0w + quad * 4 + r)) * 128 + h * 16 + lq] = O[r] * lr;
  }
}

// ---------------------------------------------------------------------------
// K5: x += o @ Wo + bo. 16 tokens/block, Wo staged whole.
// ---------------------------------------------------------------------------
__global__ __launch_bounds__(256) void k_proj(
    const float* __restrict__ og_, const float* __restrict__ Wo,
    const float* __restrict__ bo, float* __restrict__ x, int lay) {
  __shared__ float ol[16 * 128];  // 8 KB
  __shared__ float Wl[128 * 64];  // 32 KB
  int t = threadIdx.x;
  int tok0 = blockIdx.x * 16;
  for (int idx = t * 4; idx < 16 * 128; idx += 1024)
    *(float4*)(ol + idx) = *(const float4*)(og_ + (size_t)tok0 * 128 + idx);
  for (int idx = t * 4; idx < 128 * 64; idx += 1024)
    *(float4*)(Wl + idx) = *(const float4*)(Wo + lay * 128 * 64 + idx);
  __syncthreads();
  int tg = t >> 4, og4 = (t & 15) * 4;
  float4 acc = *(const float4*)(bo + lay * 64 + og4);
#pragma unroll 4
  for (int i = 0; i < 128; ++i) {
    float4 wv = *(float4*)(Wl + i * 64 + og4);
    float hv = ol[tg * 128 + i];
    acc.x = fmaf(hv, wv.x, acc.x);
    acc.y = fmaf(hv, wv.y, acc.y);
    acc.z = fmaf(hv, wv.z, acc.z);
    acc.w = fmaf(hv, wv.w, acc.w);
  }
  float* xp = x + (size_t)(tok0 + tg) * 64 + og4;
  float4 xv = *(float4*)xp;
  xv.x += acc.x; xv.y += acc.y; xv.z += acc.z; xv.w += acc.w;
  *(float4*)xp = xv;
}

// ---------------------------------------------------------------------------
// K6: FFN. 16 tokens/block, LDS-staged weights.
// ---------------------------------------------------------------------------
__global__ __launch_bounds__(256) void k_ffn(
    float* __restrict__ x, const float* __restrict__ ln_s,
    const float* __restrict__ ln_b, const float* __restrict__ W1,
    const float* __restrict__ b1, const float* __restrict__ W2,
    const float* __restrict__ b2, int lay) {
  __shared__ float hs[16 * 64];    // 4 KB
  __shared__ float hid[16 * 256];  // 16 KB
  __shared__ float Wl[32 * 256];   // 32 KB
  int t = threadIdx.x, w = t >> 6, lane = t & 63;
  int tok0 = blockIdx.x * 16;
  float ss = ln_s[lay * 64 + lane], sb = ln_b[lay * 64 + lane];
#pragma unroll
  for (int tk = 0; tk < 4; ++tk) {
    int tok = w * 4 + tk;
    float v = x[(size_t)(tok0 + tok) * 64 + lane];
    float mean = wave_reduce_sum(v) * 0.015625f;
    float d = v - mean;
    float var = wave_reduce_sum(d * d) * 0.015625f;
    hs[tok * 64 + lane] = d * rsqrtf(var + 1e-6f) * ss + sb;
  }
  // GEMM1: 64 -> 256 gelu
  {
    int tg = t >> 5, og8 = (t & 31) * 8;
    float acc[2][8];
    float4 b0 = *(const float4*)(b1 + lay * 256 + og8);
    float4 b1v = *(const float4*)(b1 + lay * 256 + og8 + 4);
#pragma unroll
    for (int c = 0; c < 2; ++c) {
      acc[c][0] = b0.x; acc[c][1] = b0.y; acc[c][2] = b0.z; acc[c][3] = b0.w;
      acc[c][4] = b1v.x; acc[c][5] = b1v.y; acc[c][6] = b1v.z; acc[c][7] = b1v.w;
    }
#pragma unroll 1
    for (int ch = 0; ch < 2; ++ch) {
      __syncthreads();
      for (int idx = t * 4; idx < 32 * 256; idx += 1024)
        *(float4*)(Wl + idx) = *(const float4*)(W1 + lay * 64 * 256 + ch * 32 * 256 + idx);
      __syncthreads();
#pragma unroll 4
      for (int ii = 0; ii < 32; ++ii) {
        int i = ch * 32 + ii;
        float4 w0 = *(float4*)(Wl + ii * 256 + og8);
        float4 w1 = *(float4*)(Wl + ii * 256 + og8 + 4);
#pragma unroll
        for (int c = 0; c < 2; ++c) {
          float hv = hs[(tg * 2 + c) * 64 + i];
          acc[c][0] = fmaf(hv, w0.x, acc[c][0]);
          acc[c][1] = fmaf(hv, w0.y, acc[c][1]);
          acc[c][2] = fmaf(hv, w0.z, acc[c][2]);
          acc[c][3] = fmaf(hv, w0.w, acc[c][3]);
          acc[c][4] = fmaf(hv, w1.x, acc[c][4]);
          acc[c][5] = fmaf(hv, w1.y, acc[c][5]);
          acc[c][6] = fmaf(hv, w1.z, acc[c][6]);
          acc[c][7] = fmaf(hv, w1.w, acc[c][7]);
        }
      }
    }
#pragma unroll
    for (int c = 0; c < 2; ++c)
#pragma unroll
      for (int jj = 0; jj < 8; ++jj)
        hid[(tg * 2 + c) * 256 + og8 + jj] = gelu_tanh(acc[c][jj]);
  }
  // GEMM2: 256 -> 64 + residual
  {
    int tg = t >> 4, og4 = (t & 15) * 4;
    float4 acc = *(const float4*)(b2 + lay * 64 + og4);
#pragma unroll 1
    for (int ch = 0; ch < 2; ++ch) {
      __syncthreads();
      for (int idx = t * 4; idx < 128 * 64; idx += 1024)
        *(float4*)(Wl + idx) = *(const float4*)(W2 + lay * 256 * 64 + ch * 128 * 64 + idx);
      __syncthreads();
#pragma unroll 4
      for (int ii = 0; ii < 128; ++ii) {
        int i = ch * 128 + ii;
        float4 wv = *(float4*)(Wl + ii * 64 + og4);
        float hv = hid[tg * 256 + i];
        acc.x = fmaf(hv, wv.x, acc.x);
        acc.y = fmaf(hv, wv.y, acc.y);
        acc.z = fmaf(hv, wv.z, acc.z);
        acc.w = fmaf(hv, wv.w, acc.w);
      }
    }
    float* xp = x + (size_t)(tok0 + tg) * 64 + og4;
    float4 xv = *(float4*)xp;
    xv.x += acc.x; xv.y += acc.y; xv.z += acc.z; xv.w += acc.w;
    *(float4*)xp = xv;
  }
}

// ---------------------------------------------------------------------------
// K7: head MLP. 16 tokens/block.
// ---------------------------------------------------------------------------
__global__ __launch_bounds__(256) void k_head(
    const float* __restrict__ x, const float* __restrict__ Wh1,
    const float* __restrict__ bh1, const float* __restrict__ Wh2,
    const float* __restrict__ bh2, const float* __restrict__ Wh3,
    const float* __restrict__ bh3, float* __restrict__ out) {
  __shared__ float xl[16 * 64];    // 4 KB
  __shared__ float hid[16 * 256];  // 16 KB
  __shared__ float h2s[16 * 64];   // 4 KB
  __shared__ float Wl[32 * 256];   // 32 KB
  int t = threadIdx.x;
  int tok0 = blockIdx.x * 16;
  {
    int idx = t * 4;
    *(float4*)(xl + idx) = *(const float4*)(x + (size_t)tok0 * 64 + idx);
  }
  // GEMM1: 64 -> 256 gelu
  {
    int tg = t >> 5, og8 = (t & 31) * 8;
    float acc[2][8];
    float4 b0 = *(const float4*)(bh1 + og8);
    float4 b1v = *(const float4*)(bh1 + og8 + 4);
#pragma unroll
    for (int c = 0; c < 2; ++c) {
      acc[c][0] = b0.x; acc[c][1] = b0.y; acc[c][2] = b0.z; acc[c][3] = b0.w;
      acc[c][4] = b1v.x; acc[c][5] = b1v.y; acc[c][6] = b1v.z; acc[c][7] = b1v.w;
    }
#pragma unroll 1
    for (int ch = 0; ch < 2; ++ch) {
      __syncthreads();
      for (int idx = t * 4; idx < 32 * 256; idx += 1024)
        *(float4*)(Wl + idx) = *(const float4*)(Wh1 + ch * 32 * 256 + idx);
      __syncthreads();
#pragma unroll 4
      for (int ii = 0; ii < 32; ++ii) {
        int i = ch * 32 + ii;
        float4 w0 = *(float4*)(Wl + ii * 256 + og8);
        float4 w1 = *(float4*)(Wl + ii * 256 + og8 + 4);
#pragma unroll
        for (int c = 0; c < 2; ++c) {
          float hv = xl[(tg * 2 + c) * 64 + i];
          acc[c][0] = fmaf(hv, w0.x, acc[c][0]);
          acc[c][1] = fmaf(hv, w0.y, acc[c][1]);
          acc[c][2] = fmaf(hv, w0.z, acc[c][2]);
          acc[c][3] = fmaf(hv, w0.w, acc[c][3]);
          acc[c][4] = fmaf(hv, w1.x, acc[c][4]);
          acc[c][5] = fmaf(hv, w1.y, acc[c][5]);
          acc[c][6] = fmaf(hv, w1.z, acc[c][6]);
          acc[c][7] = fmaf(hv, w1.w, acc[c][7]);
        }
      }
    }
#pragma unroll
    for (int c = 0; c < 2; ++c)
#pragma unroll
      for (int jj = 0; jj < 8; ++jj)
        hid[(tg * 2 + c) * 256 + og8 + jj] = gelu_tanh(acc[c][jj]);
  }
  // GEMM2: 256 -> 64 gelu
  {
    int tg = t >> 4, og4 = (t & 15) * 4;
    float4 acc = *(const float4*)(bh2 + og4);
#pragma unroll 1
    for (int ch = 0; ch < 2; ++ch) {
      __syncthreads();
      for (int idx = t * 4; idx < 128 * 64; idx += 1024)
        *(float4*)(Wl + idx) = *(const float4*)(Wh2 + ch * 128 * 64 + idx);
      __syncthreads();
#pragma unroll 4
      for (int ii = 0; ii < 128; ++ii) {
        int i = ch * 128 + ii;
        float4 wv = *(float4*)(Wl + ii * 64 + og4);
        float hv = hid[tg * 256 + i];
        acc.x = fmaf(hv, wv.x, acc.x);
        acc.y = fmaf(hv, wv.y, acc.y);
        acc.z = fmaf(hv, wv.z, acc.z);
        acc.w = fmaf(hv, wv.w, acc.w);
      }
    }
    float4 g;
    g.x = gelu_tanh(acc.x); g.y = gelu_tanh(acc.y);
    g.z = gelu_tanh(acc.z); g.w = gelu_tanh(acc.w);
    *(float4*)(h2s + tg * 64 + og4) = g;
  }
  __syncthreads();
  // GEMM3: dot with Wh3
  int w = t >> 6, lane = t & 63;
  float wv3 = Wh3[lane];
#pragma unroll
  for (int tk = 0; tk < 4; ++tk) {
    int tok = w * 4 + tk;
    float v = h2s[tok * 64 + lane] * wv3;
    float sum = wave_reduce_sum(v);
    if (lane == 0) out[tok0 + tok] = sum + bh3[0];
  }
}

// ---------------------------------------------------------------------------
extern "C" void kernel_launch(void* const* d_in, const int* in_sizes, int n_in,
                              void* d_out, int out_size, void* d_ws, size_t ws_size,
                              hipStream_t stream) {
  const float* z      = (const float*)d_in[0];
  const float* cond   = (const float*)d_in[1];
  const float* s      = (const float*)d_in[2];
  const float* embed  = (const float*)d_in[3];
  const float* Win1   = (const float*)d_in[4];
  const float* bin1   = (const float*)d_in[5];
  const float* Win2   = (const float*)d_in[6];
  const float* bin2   = (const float*)d_in[7];
  const float* ln1_s  = (const float*)d_in[8];
  const float* ln1_b  = (const float*)d_in[9];
  const float* ln2_s  = (const float*)d_in[10];
  const float* ln2_b  = (const float*)d_in[11];
  const float* Wq     = (const float*)d_in[12];
  const float* bq     = (const float*)d_in[13];
  const float* Wk     = (const float*)d_in[14];
  const float* bk     = (const float*)d_in[15];
  const float* Wv     = (const float*)d_in[16];
  const float* bv     = (const float*)d_in[17];
  const float* Wo     = (const float*)d_in[18];
  const float* bo     = (const float*)d_in[19];
  const float* rbf_c  = (const float*)d_in[20];
  const float* rbf_lw = (const float*)d_in[21];
  const float* rbf_w  = (const float*)d_in[22];
  const float* rbf_b  = (const float*)d_in[23];
  const float* W1     = (const float*)d_in[24];
  const float* b1     = (const float*)d_in[25];
  const float* W2     = (const float*)d_in[26];
  const float* b2     = (const float*)d_in[27];
  const float* Wh1    = (const float*)d_in[28];
  const float* bh1    = (const float*)d_in[29];
  const float* Wh2    = (const float*)d_in[30];
  const float* bh2    = (const float*)d_in[31];
  const float* Wh3    = (const float*)d_in[32];
  const float* bh3    = (const float*)d_in[33];

  char* base = (char*)d_ws;
  float*          x     = (float*)(base);                          // 2 MB
  unsigned short* qb    = (unsigned short*)(base + (2u << 20));    // 2 MB
  unsigned short* kb    = (unsigned short*)(base + (4u << 20));    // 2 MB
  unsigned short* vb    = (unsigned short*)(base + (6u << 20));    // 2 MB
  float*          ob    = (float*)(base + (8u << 20));             // 4 MB
  float*          biasT = (float*)(base + (12u << 20));            // 33.5 MB

  k_input_mlp<<<512, 256, 0, stream>>>(embed, z, cond, Win1, bin1, Win2, bin2, x);
  for (int lay = 0; lay < 2; ++lay) {
    k_bias<<<4096, 256, 0, stream>>>(s, rbf_c, rbf_lw, rbf_w, rbf_b, biasT, lay);
    k_ln_qkv<<<512, 256, 0, stream>>>(x, ln1_s, ln1_b, Wq, bq, Wk, bk, Wv, bv,
                                      qb, kb, vb, lay);
    k_attn<<<1024, 256, 0, stream>>>(qb, kb, vb, biasT, ob);
    k_proj<<<512, 256, 0, stream>>>(ob, Wo, bo, x, lay);
    k_ffn<<<512, 256, 0, stream>>>(x, ln2_s, ln2_b, W1, b1, W2, b2, lay);
  }
  k_head<<<512, 256, 0, stream>>>(x, Wh1, bh1, Wh2, bh2, Wh3, bh3, (float*)d_out);
}

// Round 4
// 327.319 us; speedup vs baseline: 2.9716x; 1.0419x over previous
//
#include <hip/hip_runtime.h>
#include <hip/hip_bf16.h>

// Problem constants (reference: B=8, L=1024, C=4, D=64, H=8, NB=2, K=16)
#define BB   8
#define LL   1024
#define DD   64
#define D2   128
#define D4   256
#define HH   8
#define DH   16

typedef __attribute__((ext_vector_type(8))) short short8;   // 8 bf16 (4 VGPRs)
typedef __attribute__((ext_vector_type(4))) float floatx4;  // MFMA C/D

__device__ __forceinline__ float gelu_tanh(float u) {
  float t = tanhf(0.7978845608028654f * (u + 0.044715f * u * u * u));
  return 0.5f * u * (1.0f + t);
}

__device__ __forceinline__ float wave_reduce_sum(float v) {
#pragma unroll
  for (int m = 32; m >= 1; m >>= 1) v += __shfl_xor(v, m, 64);
  return v;
}

__device__ __forceinline__ unsigned short f2bf(float x) {  // RNE
  unsigned u = __float_as_uint(x);
  u += 0x7fffu + ((u >> 16) & 1u);
  return (unsigned short)(u >> 16);
}

__device__ __forceinline__ float bf2f(unsigned short x) {
  return __uint_as_float(((unsigned)x) << 16);
}

// ---------------------------------------------------------------------------
// K1: input MLP. 16 tokens/block, weights staged in LDS, 2tok x 8out tiles.
// ---------------------------------------------------------------------------
__global__ __launch_bounds__(256) void k_input_mlp(
    const float* __restrict__ embed, const float* __restrict__ z,
    const float* __restrict__ cond, const float* __restrict__ Win1,
    const float* __restrict__ bin1, const float* __restrict__ Win2,
    const float* __restrict__ bin2, float* __restrict__ x) {
  __shared__ float feats[16 * 128];  // 8 KB
  __shared__ float hid[16 * 256];    // 16 KB
  __shared__ float Wl[32 * 256];     // 32 KB
  int t = threadIdx.x;
  int tok0 = blockIdx.x * 16;
  for (int idx = t; idx < 16 * 128; idx += 256) {
    int tok = idx >> 7, dim = idx & 127;
    int bl = tok0 + tok, l = bl & (LL - 1);
    float v;
    if (dim < 123) v = embed[l * 123 + dim];
    else if (dim == 123) v = z[bl];
    else v = cond[dim - 124];
    feats[idx] = v;
  }
  // GEMM1: 128 -> 256, gelu
  {
    int tg = t >> 5, og8 = (t & 31) * 8;
    float acc[2][8];
    float4 b0 = *(const float4*)(bin1 + og8);
    float4 b1 = *(const float4*)(bin1 + og8 + 4);
#pragma unroll
    for (int c = 0; c < 2; ++c) {
      acc[c][0] = b0.x; acc[c][1] = b0.y; acc[c][2] = b0.z; acc[c][3] = b0.w;
      acc[c][4] = b1.x; acc[c][5] = b1.y; acc[c][6] = b1.z; acc[c][7] = b1.w;
    }
#pragma unroll 1
    for (int ch = 0; ch < 4; ++ch) {
      __syncthreads();
      for (int idx = t * 4; idx < 32 * 256; idx += 1024)
        *(float4*)(Wl + idx) = *(const float4*)(Win1 + ch * 32 * 256 + idx);
      __syncthreads();
#pragma unroll 4
      for (int ii = 0; ii < 32; ++ii) {
        int i = ch * 32 + ii;
        float4 w0 = *(float4*)(Wl + ii * 256 + og8);
        float4 w1 = *(float4*)(Wl + ii * 256 + og8 + 4);
#pragma unroll
        for (int c = 0; c < 2; ++c) {
          float hv = feats[(tg * 2 + c) * 128 + i];
          acc[c][0] = fmaf(hv, w0.x, acc[c][0]);
          acc[c][1] = fmaf(hv, w0.y, acc[c][1]);
          acc[c][2] = fmaf(hv, w0.z, acc[c][2]);
          acc[c][3] = fmaf(hv, w0.w, acc[c][3]);
          acc[c][4] = fmaf(hv, w1.x, acc[c][4]);
          acc[c][5] = fmaf(hv, w1.y, acc[c][5]);
          acc[c][6] = fmaf(hv, w1.z, acc[c][6]);
          acc[c][7] = fmaf(hv, w1.w, acc[c][7]);
        }
      }
    }
#pragma unroll
    for (int c = 0; c < 2; ++c)
#pragma unroll
      for (int jj = 0; jj < 8; ++jj)
        hid[(tg * 2 + c) * 256 + og8 + jj] = gelu_tanh(acc[c][jj]);
  }
  // GEMM2: 256 -> 64
  {
    int tg = t >> 4, og4 = (t & 15) * 4;
    float4 acc = *(const float4*)(bin2 + og4);
#pragma unroll 1
    for (int ch = 0; ch < 2; ++ch) {
      __syncthreads();
      for (int idx = t * 4; idx < 128 * 64; idx += 1024)
        *(float4*)(Wl + idx) = *(const float4*)(Win2 + ch * 128 * 64 + idx);
      __syncthreads();
#pragma unroll 4
      for (int ii = 0; ii < 128; ++ii) {
        int i = ch * 128 + ii;
        float4 wv = *(float4*)(Wl + ii * 64 + og4);
        float hv = hid[tg * 256 + i];
        acc.x = fmaf(hv, wv.x, acc.x);
        acc.y = fmaf(hv, wv.y, acc.y);
        acc.z = fmaf(hv, wv.z, acc.z);
        acc.w = fmaf(hv, wv.w, acc.w);
      }
    }
    *(float4*)(x + (size_t)(tok0 + tg) * 64 + og4) = acc;
  }
}

// ---------------------------------------------------------------------------
// K2: RBF bias, both layers (blockIdx.y = lay), bf16 out biasT[lay][h][k][q].
// ---------------------------------------------------------------------------
__global__ __launch_bounds__(256) void k_bias(
    const float* __restrict__ s, const float* __restrict__ rbf_c,
    const float* __restrict__ rbf_logw, const float* __restrict__ rbf_w,
    const float* __restrict__ rbf_b, unsigned short* __restrict__ biasT) {
  int lay = blockIdx.y;
  int id = blockIdx.x * 256 + threadIdx.x;
  int k = id >> 10, q = id & 1023;
  float dd = s[q] - s[k];
  float acc[8];
#pragma unroll
  for (int h = 0; h < 8; ++h) acc[h] = rbf_b[lay * 8 + h];
#pragma unroll 1
  for (int f = 0; f < 16; ++f) {
    float c = rbf_c[lay * 16 + f];
    float inv2w2 = 0.5f * __expf(-2.0f * rbf_logw[lay * 16 + f]);
    float e = dd - c;
    float ph = __expf(-e * e * inv2w2);
#pragma unroll
    for (int h = 0; h < 8; ++h)
      acc[h] = fmaf(ph, rbf_w[lay * 128 + f * 8 + h], acc[h]);
  }
  unsigned short* bT = biasT + (size_t)lay * 8 * 1024 * 1024;
#pragma unroll
  for (int h = 0; h < 8; ++h)
    bT[(size_t)(h * 1024 + k) * 1024 + q] = f2bf(acc[h]);
}

// ---------------------------------------------------------------------------
// K3: LN + QKV -> bf16 outputs (b*8+h, l, 16) for MFMA attention.
// ---------------------------------------------------------------------------
__global__ __launch_bounds__(256) void k_ln_qkv(
    const float* __restrict__ x, const float* __restrict__ ln_s,
    const float* __restrict__ ln_b, const float* __restrict__ Wq,
    const float* __restrict__ bq, const float* __restrict__ Wk,
    const float* __restrict__ bk, const float* __restrict__ Wv,
    const float* __restrict__ bv, unsigned short* __restrict__ qo,
    unsigned short* __restrict__ ko, unsigned short* __restrict__ vo, int lay) {
  __shared__ float hs[16 * 64];  // 4 KB
  __shared__ float Wl[64 * 128]; // 32 KB
  int t = threadIdx.x, w = t >> 6, lane = t & 63;
  int tok0 = blockIdx.x * 16;
  float ss = ln_s[lay * 64 + lane], sb = ln_b[lay * 64 + lane];
#pragma unroll
  for (int tk = 0; tk < 4; ++tk) {
    int tok = w * 4 + tk;
    float v = x[(size_t)(tok0 + tok) * 64 + lane];
    float mean = wave_reduce_sum(v) * 0.015625f;
    float d = v - mean;
    float var = wave_reduce_sum(d * d) * 0.015625f;
    hs[tok * 64 + lane] = d * rsqrtf(var + 1e-6f) * ss + sb;
  }
  int tg = t >> 5, og = t & 31;  // 2 toks, 4 outs
  int b = tok0 >> 10, l0 = tok0 & 1023;
  int j = og * 4, h = j >> 4, jo = j & 15;
#pragma unroll 1
  for (int mat = 0; mat < 3; ++mat) {
    const float* W = (mat == 0 ? Wq : mat == 1 ? Wk : Wv) + lay * 64 * 128;
    const float* bias = (mat == 0 ? bq : mat == 1 ? bk : bv) + lay * 128;
    unsigned short* outp = (mat == 0 ? qo : mat == 1 ? ko : vo);
    __syncthreads();
    for (int idx = t * 4; idx < 64 * 128; idx += 1024)
      *(float4*)(Wl + idx) = *(const float4*)(W + idx);
    __syncthreads();
    float4 bb = *(const float4*)(bias + j);
    float acc[2][4];
#pragma unroll
    for (int c = 0; c < 2; ++c) {
      acc[c][0] = bb.x; acc[c][1] = bb.y; acc[c][2] = bb.z; acc[c][3] = bb.w;
    }
#pragma unroll 4
    for (int i = 0; i < 64; ++i) {
      float4 wv = *(float4*)(Wl + i * 128 + j);
#pragma unroll
      for (int c = 0; c < 2; ++c) {
        float hv = hs[(tg * 2 + c) * 64 + i];
        acc[c][0] = fmaf(hv, wv.x, acc[c][0]);
        acc[c][1] = fmaf(hv, wv.y, acc[c][1]);
        acc[c][2] = fmaf(hv, wv.z, acc[c][2]);
        acc[c][3] = fmaf(hv, wv.w, acc[c][3]);
      }
    }
#pragma unroll
    for (int c = 0; c < 2; ++c) {
      int l = l0 + tg * 2 + c;
      uint2 pk;
      pk.x = (unsigned)f2bf(acc[c][0]) | ((unsigned)f2bf(acc[c][1]) << 16);
      pk.y = (unsigned)f2bf(acc[c][2]) | ((unsigned)f2bf(acc[c][3]) << 16);
      *(uint2*)(outp + ((size_t)((b * 8 + h) * 1024 + l)) * 16 + jo) = pk;
    }
  }
}

// ---------------------------------------------------------------------------
// K4: MFMA flash attention. Block = (b, h, 64 q rows); 4 waves x 16 q each.
// S^T = K.Q^T per 64-key chunk; P bounced via per-wave LDS to A-layout.
// Bias read as bf16.
// ---------------------------------------------------------------------------
__global__ __launch_bounds__(256) void k_attn(
    const unsigned short* __restrict__ qg, const unsigned short* __restrict__ kg,
    const unsigned short* __restrict__ vg, const unsigned short* __restrict__ biasT,
    float* __restrict__ og) {
  __shared__ __align__(16) unsigned short Kl[64 * 32];      // [key][d0..31], d16+ zero
  __shared__ __align__(16) unsigned short VT[16 * 72];      // [d][key], padded row 72
  __shared__ __align__(16) unsigned short Pl[4][16 * 72];   // per-wave [q][key], padded
  int t = threadIdx.x, w = t >> 6, lane = t & 63;
  int lq = lane & 15, quad = lane >> 4;
  int bid = blockIdx.x;
  int b = bid >> 7, h = (bid >> 4) & 7, qblk = bid & 15;
  int q0w = qblk * 64 + w * 16;
  size_t bh = (size_t)(b * 8 + h) * 1024;

  ((uint4*)Kl)[t] = uint4{0, 0, 0, 0};

  short8 Qb = {};
  if (quad < 2)
    Qb = *(const short8*)(qg + (bh + q0w + lq) * 16 + quad * 8);

  float m = -1e30f, l = 0.0f;
  floatx4 O = {0.0f, 0.0f, 0.0f, 0.0f};

#pragma unroll 1
  for (int kc = 0; kc < 1024; kc += 64) {
    __syncthreads();
    {
      int key = t >> 2, dp = (t & 3) * 4;
      uint2 kv = *(const uint2*)(kg + (bh + kc + key) * 16 + dp);
      *(uint2*)(Kl + key * 32 + dp) = kv;
      uint2 vv = *(const uint2*)(vg + (bh + kc + key) * 16 + dp);
      VT[(dp + 0) * 72 + key] = (unsigned short)(vv.x & 0xffff);
      VT[(dp + 1) * 72 + key] = (unsigned short)(vv.x >> 16);
      VT[(dp + 2) * 72 + key] = (unsigned short)(vv.y & 0xffff);
      VT[(dp + 3) * 72 + key] = (unsigned short)(vv.y >> 16);
    }
    __syncthreads();
    float s[16];
#pragma unroll
    for (int tile = 0; tile < 4; ++tile) {
      short8 A = *(const short8*)(Kl + (tile * 16 + lq) * 32 + quad * 8);
      floatx4 c = {0.0f, 0.0f, 0.0f, 0.0f};
      c = __builtin_amdgcn_mfma_f32_16x16x32_bf16(A, Qb, c, 0, 0, 0);
      const unsigned short* bp = biasT +
          ((size_t)(h * 1024 + kc + tile * 16 + quad * 4)) * 1024 + q0w + lq;
#pragma unroll
      for (int r = 0; r < 4; ++r)
        s[tile * 4 + r] = fmaf(c[r], 0.25f, bf2f(bp[r * 1024]));
    }
    float cm = s[0];
#pragma unroll
    for (int i = 1; i < 16; ++i) cm = fmaxf(cm, s[i]);
    cm = fmaxf(cm, __shfl_xor(cm, 16, 64));
    cm = fmaxf(cm, __shfl_xor(cm, 32, 64));
    float mnew = fmaxf(m, cm);
    float alpha = __expf(m - mnew);
    float p[16], psum = 0.0f;
#pragma unroll
    for (int i = 0; i < 16; ++i) {
      p[i] = __expf(s[i] - mnew);
      psum += p[i];
    }
    psum += __shfl_xor(psum, 16, 64);
    psum += __shfl_xor(psum, 32, 64);
    l = l * alpha + psum;
    m = mnew;
    unsigned short* pw = &Pl[w][lq * 72];
#pragma unroll
    for (int tile = 0; tile < 4; ++tile) {
      uint2 pk;
      pk.x = (unsigned)f2bf(p[tile * 4 + 0]) | ((unsigned)f2bf(p[tile * 4 + 1]) << 16);
      pk.y = (unsigned)f2bf(p[tile * 4 + 2]) | ((unsigned)f2bf(p[tile * 4 + 3]) << 16);
      *(uint2*)(pw + tile * 16 + quad * 4) = pk;
    }
    asm volatile("s_waitcnt lgkmcnt(0)" ::: "memory");
#pragma unroll
    for (int r = 0; r < 4; ++r) {
      int idx = (quad * 4 + r) * 4;
      float ar = __uint_as_float(
          __builtin_amdgcn_ds_bpermute(idx, __float_as_uint(alpha)));
      O[r] *= ar;
    }
#pragma unroll
    for (int i = 0; i < 2; ++i) {
      short8 Pa = *(const short8*)(pw + i * 32 + quad * 8);
      short8 Vb = *(const short8*)(&VT[lq * 72 + i * 32 + quad * 8]);
      O = __builtin_amdgcn_mfma_f32_16x16x32_bf16(Pa, Vb, O, 0, 0, 0);
    }
  }
  float linv = 1.0f / l;
#pragma unroll
  for (int r = 0; r < 4; ++r) {
    int idx = (quad * 4 + r) * 4;
    float lr = __uint_as_float(
        __builtin_amdgcn_ds_bpermute(idx, __float_as_uint(linv)));
    og[((size_t)(b * 1024 + q0w + quad * 4 + r)) * 128 + h * 16 + lq] = O[r] * lr;
  }
}

// ---------------------------------------------------------------------------
// K5: fused (x += o@Wo + bo) -> LN2 -> FFN -> x += .  16 tokens/block.
// ---------------------------------------------------------------------------
__global__ __launch_bounds__(256) void k_proj_ffn(
    const float* __restrict__ og_, const float* __restrict__ Wo,
    const float* __restrict__ bo, float* __restrict__ x,
    const float* __restrict__ ln_s, const float* __restrict__ ln_b,
    const float* __restrict__ W1, const float* __restrict__ b1,
    const float* __restrict__ W2, const float* __restrict__ b2, int lay) {
  __shared__ float ol[16 * 128];   // 8 KB   (attn o staging)
  __shared__ float xl[16 * 64];    // 4 KB   (x after proj residual)
  __shared__ float hs[16 * 64];    // 4 KB   (LN2 output)
  __shared__ float hid[16 * 256];  // 16 KB  (FFN hidden)
  __shared__ float Wl[32 * 256];   // 32 KB  (weight staging, reused)
  int t = threadIdx.x, w = t >> 6, lane = t & 63;
  int tok0 = blockIdx.x * 16;
  // stage o and Wo
  for (int idx = t * 4; idx < 16 * 128; idx += 1024)
    *(float4*)(ol + idx) = *(const float4*)(og_ + (size_t)tok0 * 128 + idx);
  for (int idx = t * 4; idx < 128 * 64; idx += 1024)
    *(float4*)(Wl + idx) = *(const float4*)(Wo + lay * 128 * 64 + idx);
  __syncthreads();
  // proj + residual -> xl + global x
  {
    int tg = t >> 4, og4 = (t & 15) * 4;
    float4 acc = *(const float4*)(bo + lay * 64 + og4);
#pragma unroll 4
    for (int i = 0; i < 128; ++i) {
      float4 wv = *(float4*)(Wl + i * 64 + og4);
      float hv = ol[tg * 128 + i];
      acc.x = fmaf(hv, wv.x, acc.x);
      acc.y = fmaf(hv, wv.y, acc.y);
      acc.z = fmaf(hv, wv.z, acc.z);
      acc.w = fmaf(hv, wv.w, acc.w);
    }
    float* xp = x + (size_t)(tok0 + tg) * 64 + og4;
    float4 xv = *(float4*)xp;
    xv.x += acc.x; xv.y += acc.y; xv.z += acc.z; xv.w += acc.w;
    *(float4*)xp = xv;
    *(float4*)(xl + tg * 64 + og4) = xv;
  }
  __syncthreads();
  // LN2 (reads xl)
  {
    float ss = ln_s[lay * 64 + lane], sb = ln_b[lay * 64 + lane];
#pragma unroll
    for (int tk = 0; tk < 4; ++tk) {
      int tok = w * 4 + tk;
      float v = xl[tok * 64 + lane];
      float mean = wave_reduce_sum(v) * 0.015625f;
      float d = v - mean;
      float var = wave_reduce_sum(d * d) * 0.015625f;
      hs[tok * 64 + lane] = d * rsqrtf(var + 1e-6f) * ss + sb;
    }
  }
  // FFN GEMM1: 64 -> 256 gelu
  {
    int tg = t >> 5, og8 = (t & 31) * 8;
    float acc[2][8];
    float4 b0 = *(const float4*)(b1 + lay * 256 + og8);
    float4 b1v = *(const float4*)(b1 + lay * 256 + og8 + 4);
#pragma unroll
    for (int c = 0; c < 2; ++c) {
      acc[c][0] = b0.x; acc[c][1] = b0.y; acc[c][2] = b0.z; acc[c][3] = b0.w;
      acc[c][4] = b1v.x; acc[c][5] = b1v.y; acc[c][6] = b1v.z; acc[c][7] = b1v.w;
    }
#pragma unroll 1
    for (int ch = 0; ch < 2; ++ch) {
      __syncthreads();
      for (int idx = t * 4; idx < 32 * 256; idx += 1024)
        *(float4*)(Wl + idx) = *(const float4*)(W1 + lay * 64 * 256 + ch * 32 * 256 + idx);
      __syncthreads();
#pragma unroll 4
      for (int ii = 0; ii < 32; ++ii) {
        int i = ch * 32 + ii;
        float4 w0 = *(float4*)(Wl + ii * 256 + og8);
        float4 w1 = *(float4*)(Wl + ii * 256 + og8 + 4);
#pragma unroll
        for (int c = 0; c < 2; ++c) {
          float hv = hs[(tg * 2 + c) * 64 + i];
          acc[c][0] = fmaf(hv, w0.x, acc[c][0]);
          acc[c][1] = fmaf(hv, w0.y, acc[c][1]);
          acc[c][2] = fmaf(hv, w0.z, acc[c][2]);
          acc[c][3] = fmaf(hv, w0.w, acc[c][3]);
          acc[c][4] = fmaf(hv, w1.x, acc[c][4]);
          acc[c][5] = fmaf(hv, w1.y, acc[c][5]);
          acc[c][6] = fmaf(hv, w1.z, acc[c][6]);
          acc[c][7] = fmaf(hv, w1.w, acc[c][7]);
        }
      }
    }
#pragma unroll
    for (int c = 0; c < 2; ++c)
#pragma unroll
      for (int jj = 0; jj < 8; ++jj)
        hid[(tg * 2 + c) * 256 + og8 + jj] = gelu_tanh(acc[c][jj]);
  }
  // FFN GEMM2: 256 -> 64 + residual (xl)
  {
    int tg = t >> 4, og4 = (t & 15) * 4;
    float4 acc = *(const float4*)(b2 + lay * 64 + og4);
#pragma unroll 1
    for (int ch = 0; ch < 2; ++ch) {
      __syncthreads();
      for (int idx = t * 4; idx < 128 * 64; idx += 1024)
        *(float4*)(Wl + idx) = *(const float4*)(W2 + lay * 256 * 64 + ch * 128 * 64 + idx);
      __syncthreads();
#pragma unroll 4
      for (int ii = 0; ii < 128; ++ii) {
        int i = ch * 128 + ii;
        float4 wv = *(float4*)(Wl + ii * 64 + og4);
        float hv = hid[tg * 256 + i];
        acc.x = fmaf(hv, wv.x, acc.x);
        acc.y = fmaf(hv, wv.y, acc.y);
        acc.z = fmaf(hv, wv.z, acc.z);
        acc.w = fmaf(hv, wv.w, acc.w);
      }
    }
    float4 xv = *(float4*)(xl + tg * 64 + og4);
    xv.x += acc.x; xv.y += acc.y; xv.z += acc.z; xv.w += acc.w;
    *(float4*)(x + (size_t)(tok0 + tg) * 64 + og4) = xv;
  }
}

// ---------------------------------------------------------------------------
// K7: head MLP. 16 tokens/block.
// ---------------------------------------------------------------------------
__global__ __launch_bounds__(256) void k_head(
    const float* __restrict__ x, const float* __restrict__ Wh1,
    const float* __restrict__ bh1, const float* __restrict__ Wh2,
    const float* __restrict__ bh2, const float* __restrict__ Wh3,
    const float* __restrict__ bh3, float* __restrict__ out) {
  __shared__ float xl[16 * 64];    // 4 KB
  __shared__ float hid[16 * 256];  // 16 KB
  __shared__ float h2s[16 * 64];   // 4 KB
  __shared__ float Wl[32 * 256];   // 32 KB
  int t = threadIdx.x;
  int tok0 = blockIdx.x * 16;
  {
    int idx = t * 4;
    *(float4*)(xl + idx) = *(const float4*)(x + (size_t)tok0 * 64 + idx);
  }
  // GEMM1: 64 -> 256 gelu
  {
    int tg = t >> 5, og8 = (t & 31) * 8;
    float acc[2][8];
    float4 b0 = *(const float4*)(bh1 + og8);
    float4 b1v = *(const float4*)(bh1 + og8 + 4);
#pragma unroll
    for (int c = 0; c < 2; ++c) {
      acc[c][0] = b0.x; acc[c][1] = b0.y; acc[c][2] = b0.z; acc[c][3] = b0.w;
      acc[c][4] = b1v.x; acc[c][5] = b1v.y; acc[c][6] = b1v.z; acc[c][7] = b1v.w;
    }
#pragma unroll 1
    for (int ch = 0; ch < 2; ++ch) {
      __syncthreads();
      for (int idx = t * 4; idx < 32 * 256; idx += 1024)
        *(float4*)(Wl + idx) = *(const float4*)(Wh1 + ch * 32 * 256 + idx);
      __syncthreads();
#pragma unroll 4
      for (int ii = 0; ii < 32; ++ii) {
        int i = ch * 32 + ii;
        float4 w0 = *(float4*)(Wl + ii * 256 + og8);
        float4 w1 = *(float4*)(Wl + ii * 256 + og8 + 4);
#pragma unroll
        for (int c = 0; c < 2; ++c) {
          float hv = xl[(tg * 2 + c) * 64 + i];
          acc[c][0] = fmaf(hv, w0.x, acc[c][0]);
          acc[c][1] = fmaf(hv, w0.y, acc[c][1]);
          acc[c][2] = fmaf(hv, w0.z, acc[c][2]);
          acc[c][3] = fmaf(hv, w0.w, acc[c][3]);
          acc[c][4] = fmaf(hv, w1.x, acc[c][4]);
          acc[c][5] = fmaf(hv, w1.y, acc[c][5]);
          acc[c][6] = fmaf(hv, w1.z, acc[c][6]);
          acc[c][7] = fmaf(hv, w1.w, acc[c][7]);
        }
      }
    }
#pragma unroll
    for (int c = 0; c < 2; ++c)
#pragma unroll
      for (int jj = 0; jj < 8; ++jj)
        hid[(tg * 2 + c) * 256 + og8 + jj] = gelu_tanh(acc[c][jj]);
  }
  // GEMM2: 256 -> 64 gelu
  {
    int tg = t >> 4, og4 = (t & 15) * 4;
    float4 acc = *(const float4*)(bh2 + og4);
#pragma unroll 1
    for (int ch = 0; ch < 2; ++ch) {
      __syncthreads();
      for (int idx = t * 4; idx < 128 * 64; idx += 1024)
        *(float4*)(Wl + idx) = *(const float4*)(Wh2 + ch * 128 * 64 + idx);
      __syncthreads();
#pragma unroll 4
      for (int ii = 0; ii < 128; ++ii) {
        int i = ch * 128 + ii;
        float4 wv = *(float4*)(Wl + ii * 64 + og4);
        float hv = hid[tg * 256 + i];
        acc.x = fmaf(hv, wv.x, acc.x);
        acc.y = fmaf(hv, wv.y, acc.y);
        acc.z = fmaf(hv, wv.z, acc.z);
        acc.w = fmaf(hv, wv.w, acc.w);
      }
    }
    float4 g;
    g.x = gelu_tanh(acc.x); g.y = gelu_tanh(acc.y);
    g.z = gelu_tanh(acc.z); g.w = gelu_tanh(acc.w);
    *(float4*)(h2s + tg * 64 + og4) = g;
  }
  __syncthreads();
  int w = t >> 6, lane = t & 63;
  float wv3 = Wh3[lane];
#pragma unroll
  for (int tk = 0; tk < 4; ++tk) {
    int tok = w * 4 + tk;
    float v = h2s[tok * 64 + lane] * wv3;
    float sum = wave_reduce_sum(v);
    if (lane == 0) out[tok0 + tok] = sum + bh3[0];
  }
}

// ---------------------------------------------------------------------------
extern "C" void kernel_launch(void* const* d_in, const int* in_sizes, int n_in,
                              void* d_out, int out_size, void* d_ws, size_t ws_size,
                              hipStream_t stream) {
  const float* z      = (const float*)d_in[0];
  const float* cond   = (const float*)d_in[1];
  const float* s      = (const float*)d_in[2];
  const float* embed  = (const float*)d_in[3];
  const float* Win1   = (const float*)d_in[4];
  const float* bin1   = (const float*)d_in[5];
  const float* Win2   = (const float*)d_in[6];
  const float* bin2   = (const float*)d_in[7];
  const float* ln1_s  = (const float*)d_in[8];
  const float* ln1_b  = (const float*)d_in[9];
  const float* ln2_s  = (const float*)d_in[10];
  const float* ln2_b  = (const float*)d_in[11];
  const float* Wq     = (const float*)d_in[12];
  const float* bq     = (const float*)d_in[13];
  const float* Wk     = (const float*)d_in[14];
  const float* bk     = (const float*)d_in[15];
  const float* Wv     = (const float*)d_in[16];
  const float* bv     = (const float*)d_in[17];
  const float* Wo     = (const float*)d_in[18];
  const float* bo     = (const float*)d_in[19];
  const float* rbf_c  = (const float*)d_in[20];
  const float* rbf_lw = (const float*)d_in[21];
  const float* rbf_w  = (const float*)d_in[22];
  const float* rbf_b  = (const float*)d_in[23];
  const float* W1     = (const float*)d_in[24];
  const float* b1     = (const float*)d_in[25];
  const float* W2     = (const float*)d_in[26];
  const float* b2     = (const float*)d_in[27];
  const float* Wh1    = (const float*)d_in[28];
  const float* bh1    = (const float*)d_in[29];
  const float* Wh2    = (const float*)d_in[30];
  const float* bh2    = (const float*)d_in[31];
  const float* Wh3    = (const float*)d_in[32];
  const float* bh3    = (const float*)d_in[33];

  char* base = (char*)d_ws;
  float*          x     = (float*)(base);                          // 2 MB
  unsigned short* qb    = (unsigned short*)(base + (2u << 20));    // 2 MB
  unsigned short* kb    = (unsigned short*)(base + (4u << 20));    // 2 MB
  unsigned short* vb    = (unsigned short*)(base + (6u << 20));    // 2 MB
  float*          ob    = (float*)(base + (8u << 20));             // 4 MB
  unsigned short* biasT = (unsigned short*)(base + (12u << 20));   // 2 x 16.8 MB

  k_bias<<<dim3(4096, 2), 256, 0, stream>>>(s, rbf_c, rbf_lw, rbf_w, rbf_b, biasT);
  k_input_mlp<<<512, 256, 0, stream>>>(embed, z, cond, Win1, bin1, Win2, bin2, x);
  for (int lay = 0; lay < 2; ++lay) {
    k_ln_qkv<<<512, 256, 0, stream>>>(x, ln1_s, ln1_b, Wq, bq, Wk, bk, Wv, bv,
                                      qb, kb, vb, lay);
    k_attn<<<1024, 256, 0, stream>>>(qb, kb, vb,
                                     biasT + (size_t)lay * 8 * 1024 * 1024, ob);
    k_proj_ffn<<<512, 256, 0, stream>>>(ob, Wo, bo, x, ln2_s, ln2_b,
                                        W1, b1, W2, b2, lay);
  }
  k_head<<<512, 256, 0, stream>>>(x, Wh1, bh1, Wh2, bh2, Wh3, bh3, (float*)d_out);
}

// Round 5
// 286.433 us; speedup vs baseline: 3.3958x; 1.1427x over previous
//
#include <hip/hip_runtime.h>
#include <hip/hip_bf16.h>

// Problem constants (reference: B=8, L=1024, C=4, D=64, H=8, NB=2, K=16)
#define BB   8
#define LL   1024
#define DD   64
#define D2   128
#define D4   256
#define HH   8
#define DH   16

typedef __attribute__((ext_vector_type(8))) short short8;   // 8 bf16 (4 VGPRs)
typedef __attribute__((ext_vector_type(4))) float floatx4;  // MFMA C/D

// bf16 split-weight arena offsets (elements)
#define OFF_WIN1   0        // [256][128] hi, lo at +32768
#define OFF_WIN2   65536    // [64][256]  hi, lo at +16384
#define OFF_LAY0   98304
#define LAY_STRIDE 131072
#define OFF_WQ     0        // [128][64] hi, lo +8192
#define OFF_WK     16384
#define OFF_WV     32768
#define OFF_WO     49152    // [64][128] hi, lo +8192
#define OFF_W1     65536    // [256][64] hi, lo +16384
#define OFF_W2     98304    // [64][256] hi, lo +16384
#define OFF_WH1    360448   // [256][64] hi, lo +16384
#define OFF_WH2    393216   // [64][256] hi, lo +16384

__device__ __forceinline__ float gelu_tanh(float u) {
  float t = tanhf(0.7978845608028654f * (u + 0.044715f * u * u * u));
  return 0.5f * u * (1.0f + t);
}

__device__ __forceinline__ float wave_reduce_sum(float v) {
#pragma unroll
  for (int m = 32; m >= 1; m >>= 1) v += __shfl_xor(v, m, 64);
  return v;
}

__device__ __forceinline__ unsigned short f2bf(float x) {  // RNE
  unsigned u = __float_as_uint(x);
  u += 0x7fffu + ((u >> 16) & 1u);
  return (unsigned short)(u >> 16);
}

__device__ __forceinline__ float bf2f(unsigned short x) {
  return __uint_as_float(((unsigned)x) << 16);
}

__device__ __forceinline__ void split_bf(float v, unsigned short& hi,
                                         unsigned short& lo) {
  hi = f2bf(v);
  lo = f2bf(v - bf2f(hi));
}

// 16x16 output tile over K with 3-term bf16 split (ah*bh + al*bh + ah*bl).
// A in LDS rows [16][KP]; B in global rows [n][K] (hi and lo planes).
template <int K, int KP>
__device__ __forceinline__ floatx4 mfma_tile(
    const unsigned short* Ah, const unsigned short* Al,
    const unsigned short* __restrict__ Bh, const unsigned short* __restrict__ Bl,
    int lq, int quad, floatx4 C) {
#pragma unroll
  for (int kk = 0; kk < K; kk += 32) {
    short8 ah = *(const short8*)(Ah + lq * KP + kk + quad * 8);
    short8 al = *(const short8*)(Al + lq * KP + kk + quad * 8);
    short8 bh = *(const short8*)(Bh + lq * K + kk + quad * 8);
    short8 bl = *(const short8*)(Bl + lq * K + kk + quad * 8);
    C = __builtin_amdgcn_mfma_f32_16x16x32_bf16(ah, bh, C, 0, 0, 0);
    C = __builtin_amdgcn_mfma_f32_16x16x32_bf16(al, bh, C, 0, 0, 0);
    C = __builtin_amdgcn_mfma_f32_16x16x32_bf16(ah, bl, C, 0, 0, 0);
  }
  return C;
}

// ---------------------------------------------------------------------------
// K0: weight prep — transpose fp32 W[k][n] -> bf16 hi/lo planes T[n][k].
// ---------------------------------------------------------------------------
struct PrepArgs {
  const float* src[16];
  int Kd[16], Nd[16], dst[16], elems[16];
};

__global__ __launch_bounds__(256) void k_prep(PrepArgs a,
                                              unsigned short* __restrict__ arena) {
  int mid = blockIdx.y;
  int e = blockIdx.x * 256 + threadIdx.x;
  int KN = a.elems[mid];
  if (e >= KN) return;
  int K = a.Kd[mid], N = a.Nd[mid];
  int n = e / K, k = e - n * K;
  float wv = a.src[mid][k * N + n];
  unsigned short hi, lo;
  split_bf(wv, hi, lo);
  arena[a.dst[mid] + e] = hi;
  arena[a.dst[mid] + KN + e] = lo;
}

// ---------------------------------------------------------------------------
// K1: input MLP via MFMA. 16 tokens/block.
// ---------------------------------------------------------------------------
__global__ __launch_bounds__(256) void k_input_mlp(
    const float* __restrict__ embed, const float* __restrict__ z,
    const float* __restrict__ cond, const unsigned short* __restrict__ arena,
    const float* __restrict__ bin1, const float* __restrict__ bin2,
    float* __restrict__ x) {
  __shared__ __align__(16) unsigned short Ah[16 * 136], Al[16 * 136];
  __shared__ __align__(16) unsigned short Hh[16 * 264], Hl[16 * 264];
  int t = threadIdx.x, w = t >> 6, lane = t & 63;
  int lq = lane & 15, quad = lane >> 4;
  int tok0 = blockIdx.x * 16;
  for (int idx = t; idx < 2048; idx += 256) {
    int tok = idx >> 7, dim = idx & 127;
    int bl = tok0 + tok, l = bl & (LL - 1);
    float v;
    if (dim < 123) v = embed[l * 123 + dim];
    else if (dim == 123) v = z[bl];
    else v = cond[dim - 124];
    unsigned short hi, lo;
    split_bf(v, hi, lo);
    Ah[tok * 136 + dim] = hi;
    Al[tok * 136 + dim] = lo;
  }
  __syncthreads();
  // G1: 128 -> 256, gelu
  const unsigned short* B1h = arena + OFF_WIN1;
  const unsigned short* B1l = B1h + 32768;
#pragma unroll
  for (int j = 0; j < 4; ++j) {
    int tl = w * 4 + j, n = tl * 16 + lq;
    float bb = bin1[n];
    floatx4 C = {bb, bb, bb, bb};
    C = mfma_tile<128, 136>(Ah, Al, B1h + tl * 16 * 128, B1l + tl * 16 * 128,
                            lq, quad, C);
#pragma unroll
    for (int r = 0; r < 4; ++r) {
      float g = gelu_tanh(C[r]);
      unsigned short hi, lo;
      split_bf(g, hi, lo);
      Hh[(quad * 4 + r) * 264 + n] = hi;
      Hl[(quad * 4 + r) * 264 + n] = lo;
    }
  }
  __syncthreads();
  // G2: 256 -> 64
  const unsigned short* B2h = arena + OFF_WIN2;
  const unsigned short* B2l = B2h + 16384;
  {
    int n = w * 16 + lq;
    float bb = bin2[n];
    floatx4 C = {bb, bb, bb, bb};
    C = mfma_tile<256, 264>(Hh, Hl, B2h + w * 16 * 256, B2l + w * 16 * 256,
                            lq, quad, C);
#pragma unroll
    for (int r = 0; r < 4; ++r)
      x[(size_t)(tok0 + quad * 4 + r) * 64 + n] = C[r];
  }
}

// ---------------------------------------------------------------------------
// K2: RBF bias, both layers (blockIdx.y = lay), bf16 out biasT[lay][h][k][q].
// ---------------------------------------------------------------------------
__global__ __launch_bounds__(256) void k_bias(
    const float* __restrict__ s, const float* __restrict__ rbf_c,
    const float* __restrict__ rbf_logw, const float* __restrict__ rbf_w,
    const float* __restrict__ rbf_b, unsigned short* __restrict__ biasT) {
  int lay = blockIdx.y;
  int id = blockIdx.x * 256 + threadIdx.x;
  int k = id >> 10, q = id & 1023;
  float dd = s[q] - s[k];
  float acc[8];
#pragma unroll
  for (int h = 0; h < 8; ++h) acc[h] = rbf_b[lay * 8 + h];
#pragma unroll 1
  for (int f = 0; f < 16; ++f) {
    float c = rbf_c[lay * 16 + f];
    float inv2w2 = 0.5f * __expf(-2.0f * rbf_logw[lay * 16 + f]);
    float e = dd - c;
    float ph = __expf(-e * e * inv2w2);
#pragma unroll
    for (int h = 0; h < 8; ++h)
      acc[h] = fmaf(ph, rbf_w[lay * 128 + f * 8 + h], acc[h]);
  }
  unsigned short* bT = biasT + (size_t)lay * 8 * 1024 * 1024;
#pragma unroll
  for (int h = 0; h < 8; ++h)
    bT[(size_t)(h * 1024 + k) * 1024 + q] = f2bf(acc[h]);
}

// ---------------------------------------------------------------------------
// K3: LN + one of Q/K/V (blockIdx.y = mat) via MFMA -> bf16 (b*8+h, l, 16).
// ---------------------------------------------------------------------------
__global__ __launch_bounds__(256) void k_ln_qkv(
    const float* __restrict__ x, const float* __restrict__ ln_s,
    const float* __restrict__ ln_b, const unsigned short* __restrict__ arena,
    const float* __restrict__ bq, const float* __restrict__ bk,
    const float* __restrict__ bv, unsigned short* __restrict__ qo,
    unsigned short* __restrict__ ko, unsigned short* __restrict__ vo, int lay) {
  __shared__ __align__(16) unsigned short Ah[16 * 72], Al[16 * 72];
  int t = threadIdx.x, w = t >> 6, lane = t & 63;
  int tok0 = blockIdx.x * 16;
  int mat = blockIdx.y;
  float ss = ln_s[lay * 64 + lane], sb = ln_b[lay * 64 + lane];
#pragma unroll
  for (int tk = 0; tk < 4; ++tk) {
    int tok = w * 4 + tk;
    float v = x[(size_t)(tok0 + tok) * 64 + lane];
    float mean = wave_reduce_sum(v) * 0.015625f;
    float d = v - mean;
    float var = wave_reduce_sum(d * d) * 0.015625f;
    float hv = d * rsqrtf(var + 1e-6f) * ss + sb;
    unsigned short hi, lo;
    split_bf(hv, hi, lo);
    Ah[tok * 72 + lane] = hi;
    Al[tok * 72 + lane] = lo;
  }
  __syncthreads();
  int lq = lane & 15, quad = lane >> 4;
  const unsigned short* Bh =
      arena + OFF_LAY0 + lay * LAY_STRIDE + mat * 16384;
  const unsigned short* Bl = Bh + 8192;
  const float* bias = (mat == 0 ? bq : mat == 1 ? bk : bv) + lay * 128;
  unsigned short* outp = (mat == 0 ? qo : mat == 1 ? ko : vo);
  int b = tok0 >> 10, l0 = tok0 & 1023;
#pragma unroll
  for (int j = 0; j < 2; ++j) {
    int tl = w + j * 4;  // == head index
    int n = tl * 16 + lq;
    float bb = bias[n];
    floatx4 C = {bb, bb, bb, bb};
    C = mfma_tile<64, 72>(Ah, Al, Bh + tl * 16 * 64, Bl + tl * 16 * 64,
                          lq, quad, C);
    size_t basea = ((size_t)(b * 8 + tl) * 1024 + l0 + quad * 4) * 16 + lq;
#pragma unroll
    for (int r = 0; r < 4; ++r)
      outp[basea + (size_t)r * 16] = f2bf(C[r]);
  }
}

// ---------------------------------------------------------------------------
// K4: MFMA flash attention (unchanged from round 3/4).
// ---------------------------------------------------------------------------
__global__ __launch_bounds__(256) void k_attn(
    const unsigned short* __restrict__ qg, const unsigned short* __restrict__ kg,
    const unsigned short* __restrict__ vg, const unsigned short* __restrict__ biasT,
    float* __restrict__ og) {
  __shared__ __align__(16) unsigned short Kl[64 * 32];
  __shared__ __align__(16) unsigned short VT[16 * 72];
  __shared__ __align__(16) unsigned short Pl[4][16 * 72];
  int t = threadIdx.x, w = t >> 6, lane = t & 63;
  int lq = lane & 15, quad = lane >> 4;
  int bid = blockIdx.x;
  int b = bid >> 7, h = (bid >> 4) & 7, qblk = bid & 15;
  int q0w = qblk * 64 + w * 16;
  size_t bh = (size_t)(b * 8 + h) * 1024;

  ((uint4*)Kl)[t] = uint4{0, 0, 0, 0};

  short8 Qb = {};
  if (quad < 2)
    Qb = *(const short8*)(qg + (bh + q0w + lq) * 16 + quad * 8);

  float m = -1e30f, l = 0.0f;
  floatx4 O = {0.0f, 0.0f, 0.0f, 0.0f};

#pragma unroll 1
  for (int kc = 0; kc < 1024; kc += 64) {
    __syncthreads();
    {
      int key = t >> 2, dp = (t & 3) * 4;
      uint2 kv = *(const uint2*)(kg + (bh + kc + key) * 16 + dp);
      *(uint2*)(Kl + key * 32 + dp) = kv;
      uint2 vv = *(const uint2*)(vg + (bh + kc + key) * 16 + dp);
      VT[(dp + 0) * 72 + key] = (unsigned short)(vv.x & 0xffff);
      VT[(dp + 1) * 72 + key] = (unsigned short)(vv.x >> 16);
      VT[(dp + 2) * 72 + key] = (unsigned short)(vv.y & 0xffff);
      VT[(dp + 3) * 72 + key] = (unsigned short)(vv.y >> 16);
    }
    __syncthreads();
    float s[16];
#pragma unroll
    for (int tile = 0; tile < 4; ++tile) {
      short8 A = *(const short8*)(Kl + (tile * 16 + lq) * 32 + quad * 8);
      floatx4 c = {0.0f, 0.0f, 0.0f, 0.0f};
      c = __builtin_amdgcn_mfma_f32_16x16x32_bf16(A, Qb, c, 0, 0, 0);
      const unsigned short* bp = biasT +
          ((size_t)(h * 1024 + kc + tile * 16 + quad * 4)) * 1024 + q0w + lq;
#pragma unroll
      for (int r = 0; r < 4; ++r)
        s[tile * 4 + r] = fmaf(c[r], 0.25f, bf2f(bp[r * 1024]));
    }
    float cm = s[0];
#pragma unroll
    for (int i = 1; i < 16; ++i) cm = fmaxf(cm, s[i]);
    cm = fmaxf(cm, __shfl_xor(cm, 16, 64));
    cm = fmaxf(cm, __shfl_xor(cm, 32, 64));
    float mnew = fmaxf(m, cm);
    float alpha = __expf(m - mnew);
    float p[16], psum = 0.0f;
#pragma unroll
    for (int i = 0; i < 16; ++i) {
      p[i] = __expf(s[i] - mnew);
      psum += p[i];
    }
    psum += __shfl_xor(psum, 16, 64);
    psum += __shfl_xor(psum, 32, 64);
    l = l * alpha + psum;
    m = mnew;
    unsigned short* pw = &Pl[w][lq * 72];
#pragma unroll
    for (int tile = 0; tile < 4; ++tile) {
      uint2 pk;
      pk.x = (unsigned)f2bf(p[tile * 4 + 0]) | ((unsigned)f2bf(p[tile * 4 + 1]) << 16);
      pk.y = (unsigned)f2bf(p[tile * 4 + 2]) | ((unsigned)f2bf(p[tile * 4 + 3]) << 16);
      *(uint2*)(pw + tile * 16 + quad * 4) = pk;
    }
    asm volatile("s_waitcnt lgkmcnt(0)" ::: "memory");
#pragma unroll
    for (int r = 0; r < 4; ++r) {
      int idx = (quad * 4 + r) * 4;
      float ar = __uint_as_float(
          __builtin_amdgcn_ds_bpermute(idx, __float_as_uint(alpha)));
      O[r] *= ar;
    }
#pragma unroll
    for (int i = 0; i < 2; ++i) {
      short8 Pa = *(const short8*)(pw + i * 32 + quad * 8);
      short8 Vb = *(const short8*)(&VT[lq * 72 + i * 32 + quad * 8]);
      O = __builtin_amdgcn_mfma_f32_16x16x32_bf16(Pa, Vb, O, 0, 0, 0);
    }
  }
  float linv = 1.0f / l;
#pragma unroll
  for (int r = 0; r < 4; ++r) {
    int idx = (quad * 4 + r) * 4;
    float lr = __uint_as_float(
        __builtin_amdgcn_ds_bpermute(idx, __float_as_uint(linv)));
    og[((size_t)(b * 1024 + q0w + quad * 4 + r)) * 128 + h * 16 + lq] = O[r] * lr;
  }
}

// ---------------------------------------------------------------------------
// K5: fused proj + LN2 + FFN via MFMA. 16 tokens/block.
// ---------------------------------------------------------------------------
__global__ __launch_bounds__(256) void k_proj_ffn(
    const float* __restrict__ ob, const unsigned short* __restrict__ arena,
    const float* __restrict__ bo, float* __restrict__ x,
    const float* __restrict__ ln_s, const float* __restrict__ ln_b,
    const float* __restrict__ b1, const float* __restrict__ b2, int lay) {
  __shared__ __align__(16) unsigned short Ah[16 * 136], Al[16 * 136];  // o split
  __shared__ __align__(16) unsigned short Sh[16 * 72], Sl[16 * 72];    // LN2 split
  __shared__ __align__(16) unsigned short Hh[16 * 264], Hl[16 * 264];  // hid split
  __shared__ float xl[16 * 64];
  int t = threadIdx.x, w = t >> 6, lane = t & 63;
  int lq = lane & 15, quad = lane >> 4;
  int tok0 = blockIdx.x * 16;
  const unsigned short* labase = arena + OFF_LAY0 + lay * LAY_STRIDE;
  // stage o split
  for (int idx = t * 4; idx < 2048; idx += 1024) {
    int row = idx >> 7, col = idx & 127;
    float4 v = *(const float4*)(ob + (size_t)(tok0 + row) * 128 + col);
    unsigned short h0, e0, h1, e1, h2, e2, h3, e3;
    split_bf(v.x, h0, e0); split_bf(v.y, h1, e1);
    split_bf(v.z, h2, e2); split_bf(v.w, h3, e3);
    unsigned* ph = (unsigned*)(Ah + row * 136 + col);
    ph[0] = (unsigned)h0 | ((unsigned)h1 << 16);
    ph[1] = (unsigned)h2 | ((unsigned)h3 << 16);
    unsigned* pl = (unsigned*)(Al + row * 136 + col);
    pl[0] = (unsigned)e0 | ((unsigned)e1 << 16);
    pl[1] = (unsigned)e2 | ((unsigned)e3 << 16);
  }
  __syncthreads();
  // proj: 128 -> 64, + residual -> xl
  {
    const unsigned short* Bh = labase + OFF_WO;
    const unsigned short* Bl = Bh + 8192;
    int n = w * 16 + lq;
    float bb = bo[lay * 64 + n];
    floatx4 C = {bb, bb, bb, bb};
    C = mfma_tile<128, 136>(Ah, Al, Bh + w * 16 * 128, Bl + w * 16 * 128,
                            lq, quad, C);
#pragma unroll
    for (int r = 0; r < 4; ++r) {
      int m = quad * 4 + r;
      float xv = x[(size_t)(tok0 + m) * 64 + n] + C[r];
      xl[m * 64 + n] = xv;
    }
  }
  __syncthreads();
  // LN2
  {
    float ss = ln_s[lay * 64 + lane], sb = ln_b[lay * 64 + lane];
#pragma unroll
    for (int tk = 0; tk < 4; ++tk) {
      int tok = w * 4 + tk;
      float v = xl[tok * 64 + lane];
      float mean = wave_reduce_sum(v) * 0.015625f;
      float d = v - mean;
      float var = wave_reduce_sum(d * d) * 0.015625f;
      float hv = d * rsqrtf(var + 1e-6f) * ss + sb;
      unsigned short hi, lo;
      split_bf(hv, hi, lo);
      Sh[tok * 72 + lane] = hi;
      Sl[tok * 72 + lane] = lo;
    }
  }
  __syncthreads();
  // FFN G1: 64 -> 256, gelu
  {
    const unsigned short* Bh = labase + OFF_W1;
    const unsigned short* Bl = Bh + 16384;
#pragma unroll
    for (int j = 0; j < 4; ++j) {
      int tl = w * 4 + j, n = tl * 16 + lq;
      float bb = b1[lay * 256 + n];
      floatx4 C = {bb, bb, bb, bb};
      C = mfma_tile<64, 72>(Sh, Sl, Bh + tl * 16 * 64, Bl + tl * 16 * 64,
                            lq, quad, C);
#pragma unroll
      for (int r = 0; r < 4; ++r) {
        float g = gelu_tanh(C[r]);
        unsigned short hi, lo;
        split_bf(g, hi, lo);
        Hh[(quad * 4 + r) * 264 + n] = hi;
        Hl[(quad * 4 + r) * 264 + n] = lo;
      }
    }
  }
  __syncthreads();
  // FFN G2: 256 -> 64, + residual -> x
  {
    const unsigned short* Bh = labase + OFF_W2;
    const unsigned short* Bl = Bh + 16384;
    int n = w * 16 + lq;
    float bb = b2[lay * 64 + n];
    floatx4 C = {bb, bb, bb, bb};
    C = mfma_tile<256, 264>(Hh, Hl, Bh + w * 16 * 256, Bl + w * 16 * 256,
                            lq, quad, C);
#pragma unroll
    for (int r = 0; r < 4; ++r) {
      int m = quad * 4 + r;
      x[(size_t)(tok0 + m) * 64 + n] = xl[m * 64 + n] + C[r];
    }
  }
}

// ---------------------------------------------------------------------------
// K6: head MLP via MFMA. 16 tokens/block.
// ---------------------------------------------------------------------------
__global__ __launch_bounds__(256) void k_head(
    const float* __restrict__ x, const unsigned short* __restrict__ arena,
    const float* __restrict__ bh1, const float* __restrict__ bh2,
    const float* __restrict__ Wh3, const float* __restrict__ bh3,
    float* __restrict__ out) {
  __shared__ __align__(16) unsigned short Sh[16 * 72], Sl[16 * 72];
  __shared__ __align__(16) unsigned short Hh[16 * 264], Hl[16 * 264];
  __shared__ float h2s[16 * 64];
  int t = threadIdx.x, w = t >> 6, lane = t & 63;
  int lq = lane & 15, quad = lane >> 4;
  int tok0 = blockIdx.x * 16;
  {
    int idx = t * 4;
    int row = idx >> 6, col = idx & 63;
    float4 v = *(const float4*)(x + (size_t)(tok0 + row) * 64 + col);
    unsigned short h0, e0, h1, e1, h2, e2, h3, e3;
    split_bf(v.x, h0, e0); split_bf(v.y, h1, e1);
    split_bf(v.z, h2, e2); split_bf(v.w, h3, e3);
    unsigned* ph = (unsigned*)(Sh + row * 72 + col);
    ph[0] = (unsigned)h0 | ((unsigned)h1 << 16);
    ph[1] = (unsigned)h2 | ((unsigned)h3 << 16);
    unsigned* pl = (unsigned*)(Sl + row * 72 + col);
    pl[0] = (unsigned)e0 | ((unsigned)e1 << 16);
    pl[1] = (unsigned)e2 | ((unsigned)e3 << 16);
  }
  __syncthreads();
  // G1: 64 -> 256, gelu
  {
    const unsigned short* Bh = arena + OFF_WH1;
    const unsigned short* Bl = Bh + 16384;
#pragma unroll
    for (int j = 0; j < 4; ++j) {
      int tl = w * 4 + j, n = tl * 16 + lq;
      float bb = bh1[n];
      floatx4 C = {bb, bb, bb, bb};
      C = mfma_tile<64, 72>(Sh, Sl, Bh + tl * 16 * 64, Bl + tl * 16 * 64,
                            lq, quad, C);
#pragma unroll
      for (int r = 0; r < 4; ++r) {
        float g = gelu_tanh(C[r]);
        unsigned short hi, lo;
        split_bf(g, hi, lo);
        Hh[(quad * 4 + r) * 264 + n] = hi;
        Hl[(quad * 4 + r) * 264 + n] = lo;
      }
    }
  }
  __syncthreads();
  // G2: 256 -> 64, gelu -> h2s
  {
    const unsigned short* Bh = arena + OFF_WH2;
    const unsigned short* Bl = Bh + 16384;
    int n = w * 16 + lq;
    float bb = bh2[n];
    floatx4 C = {bb, bb, bb, bb};
    C = mfma_tile<256, 264>(Hh, Hl, Bh + w * 16 * 256, Bl + w * 16 * 256,
                            lq, quad, C);
#pragma unroll
    for (int r = 0; r < 4; ++r)
      h2s[(quad * 4 + r) * 64 + n] = gelu_tanh(C[r]);
  }
  __syncthreads();
  // G3: dot with Wh3
  float wv3 = Wh3[lane];
#pragma unroll
  for (int tk = 0; tk < 4; ++tk) {
    int tok = w * 4 + tk;
    float v = h2s[tok * 64 + lane] * wv3;
    float sum = wave_reduce_sum(v);
    if (lane == 0) out[tok0 + tok] = sum + bh3[0];
  }
}

// ---------------------------------------------------------------------------
extern "C" void kernel_launch(void* const* d_in, const int* in_sizes, int n_in,
                              void* d_out, int out_size, void* d_ws, size_t ws_size,
                              hipStream_t stream) {
  const float* z      = (const float*)d_in[0];
  const float* cond   = (const float*)d_in[1];
  const float* s      = (const float*)d_in[2];
  const float* embed  = (const float*)d_in[3];
  const float* Win1   = (const float*)d_in[4];
  const float* bin1   = (const float*)d_in[5];
  const float* Win2   = (const float*)d_in[6];
  const float* bin2   = (const float*)d_in[7];
  const float* ln1_s  = (const float*)d_in[8];
  const float* ln1_b  = (const float*)d_in[9];
  const float* ln2_s  = (const float*)d_in[10];
  const float* ln2_b  = (const float*)d_in[11];
  const float* Wq     = (const float*)d_in[12];
  const float* bq     = (const float*)d_in[13];
  const float* Wk     = (const float*)d_in[14];
  const float* bk     = (const float*)d_in[15];
  const float* Wv     = (const float*)d_in[16];
  const float* bv     = (const float*)d_in[17];
  const float* Wo     = (const float*)d_in[18];
  const float* bo     = (const float*)d_in[19];
  const float* rbf_c  = (const float*)d_in[20];
  const float* rbf_lw = (const float*)d_in[21];
  const float* rbf_w  = (const float*)d_in[22];
  const float* rbf_b  = (const float*)d_in[23];
  const float* W1     = (const float*)d_in[24];
  const float* b1     = (const float*)d_in[25];
  const float* W2     = (const float*)d_in[26];
  const float* b2     = (const float*)d_in[27];
  const float* Wh1    = (const float*)d_in[28];
  const float* bh1    = (const float*)d_in[29];
  const float* Wh2    = (const float*)d_in[30];
  const float* bh2    = (const float*)d_in[31];
  const float* Wh3    = (const float*)d_in[32];
  const float* bh3    = (const float*)d_in[33];

  char* base = (char*)d_ws;
  float*          x     = (float*)(base);                          // 2 MB
  unsigned short* qb    = (unsigned short*)(base + (2u << 20));    // 2 MB
  unsigned short* kb    = (unsigned short*)(base + (4u << 20));    // 2 MB
  unsigned short* vb    = (unsigned short*)(base + (6u << 20));    // 2 MB
  float*          ob    = (float*)(base + (8u << 20));             // 4 MB
  unsigned short* biasT = (unsigned short*)(base + (12u << 20));   // 2 x 16 MB
  unsigned short* arena = (unsigned short*)(base + (48u << 20));   // ~832 KB

  PrepArgs pa;
  auto set = [&](int i, const float* sp, int K, int N, int dst) {
    pa.src[i] = sp; pa.Kd[i] = K; pa.Nd[i] = N; pa.dst[i] = dst;
    pa.elems[i] = K * N;
  };
  set(0, Win1, 128, 256, OFF_WIN1);
  set(1, Win2, 256, 64, OFF_WIN2);
  for (int lay = 0; lay < 2; ++lay) {
    int lb = OFF_LAY0 + lay * LAY_STRIDE;
    set(2 + lay * 6, Wq + lay * 8192, 64, 128, lb + OFF_WQ);
    set(3 + lay * 6, Wk + lay * 8192, 64, 128, lb + OFF_WK);
    set(4 + lay * 6, Wv + lay * 8192, 64, 128, lb + OFF_WV);
    set(5 + lay * 6, Wo + lay * 8192, 128, 64, lb + OFF_WO);
    set(6 + lay * 6, W1 + lay * 16384, 64, 256, lb + OFF_W1);
    set(7 + lay * 6, W2 + lay * 16384, 256, 64, lb + OFF_W2);
  }
  set(14, Wh1, 64, 256, OFF_WH1);
  set(15, Wh2, 256, 64, OFF_WH2);

  k_prep<<<dim3(128, 16), 256, 0, stream>>>(pa, arena);
  k_bias<<<dim3(4096, 2), 256, 0, stream>>>(s, rbf_c, rbf_lw, rbf_w, rbf_b, biasT);
  k_input_mlp<<<512, 256, 0, stream>>>(embed, z, cond, arena, bin1, bin2, x);
  for (int lay = 0; lay < 2; ++lay) {
    k_ln_qkv<<<dim3(512, 3), 256, 0, stream>>>(x, ln1_s, ln1_b, arena,
                                               bq, bk, bv, qb, kb, vb, lay);
    k_attn<<<1024, 256, 0, stream>>>(qb, kb, vb,
                                     biasT + (size_t)lay * 8 * 1024 * 1024, ob);
    k_proj_ffn<<<512, 256, 0, stream>>>(ob, arena, bo, x, ln2_s, ln2_b,
                                        b1, b2, lay);
  }
  k_head<<<512, 256, 0, stream>>>(x, arena, bh1, bh2, Wh3, bh3, (float*)d_out);
}

// Round 6
// 281.323 us; speedup vs baseline: 3.4575x; 1.0182x over previous
//
#include <hip/hip_runtime.h>
#include <hip/hip_bf16.h>

// Problem constants (reference: B=8, L=1024, C=4, D=64, H=8, NB=2, K=16)
#define BB   8
#define LL   1024
#define DD   64
#define D2   128
#define D4   256
#define HH   8
#define DH   16

typedef __attribute__((ext_vector_type(8))) short short8;   // 8 bf16 (4 VGPRs)
typedef __attribute__((ext_vector_type(4))) float floatx4;  // MFMA C/D

// bf16 split-weight arena offsets (elements)
#define OFF_WIN1   0        // [256][128] hi, lo at +32768
#define OFF_WIN2   65536    // [64][256]  hi, lo at +16384
#define OFF_LAY0   98304
#define LAY_STRIDE 131072
#define OFF_WQ     0        // [128][64] hi, lo +8192
#define OFF_WK     16384
#define OFF_WV     32768
#define OFF_WO     49152    // [64][128] hi, lo +8192
#define OFF_W1     65536    // [256][64] hi, lo +16384
#define OFF_W2     98304    // [64][256] hi, lo +16384
#define OFF_WH1    360448   // [256][64] hi, lo +16384
#define OFF_WH2    393216   // [64][256] hi, lo +16384

__device__ __forceinline__ float gelu_tanh(float u) {
  float t = tanhf(0.7978845608028654f * (u + 0.044715f * u * u * u));
  return 0.5f * u * (1.0f + t);
}

__device__ __forceinline__ float wave_reduce_sum(float v) {
#pragma unroll
  for (int m = 32; m >= 1; m >>= 1) v += __shfl_xor(v, m, 64);
  return v;
}

__device__ __forceinline__ unsigned short f2bf(float x) {  // RNE
  unsigned u = __float_as_uint(x);
  u += 0x7fffu + ((u >> 16) & 1u);
  return (unsigned short)(u >> 16);
}

__device__ __forceinline__ float bf2f(unsigned short x) {
  return __uint_as_float(((unsigned)x) << 16);
}

__device__ __forceinline__ void split_bf(float v, unsigned short& hi,
                                         unsigned short& lo) {
  hi = f2bf(v);
  lo = f2bf(v - bf2f(hi));
}

// 16x16 output tile over K with 3-term bf16 split (ah*bh + al*bh + ah*bl).
template <int K, int KP>
__device__ __forceinline__ floatx4 mfma_tile(
    const unsigned short* Ah, const unsigned short* Al,
    const unsigned short* __restrict__ Bh, const unsigned short* __restrict__ Bl,
    int lq, int quad, floatx4 C) {
#pragma unroll
  for (int kk = 0; kk < K; kk += 32) {
    short8 ah = *(const short8*)(Ah + lq * KP + kk + quad * 8);
    short8 al = *(const short8*)(Al + lq * KP + kk + quad * 8);
    short8 bh = *(const short8*)(Bh + lq * K + kk + quad * 8);
    short8 bl = *(const short8*)(Bl + lq * K + kk + quad * 8);
    C = __builtin_amdgcn_mfma_f32_16x16x32_bf16(ah, bh, C, 0, 0, 0);
    C = __builtin_amdgcn_mfma_f32_16x16x32_bf16(al, bh, C, 0, 0, 0);
    C = __builtin_amdgcn_mfma_f32_16x16x32_bf16(ah, bl, C, 0, 0, 0);
  }
  return C;
}

// ---------------------------------------------------------------------------
// K0: weight prep — transpose fp32 W[k][n] -> bf16 hi/lo planes T[n][k].
// ---------------------------------------------------------------------------
struct PrepArgs {
  const float* src[16];
  int Kd[16], Nd[16], dst[16], elems[16];
};

__global__ __launch_bounds__(256) void k_prep(PrepArgs a,
                                              unsigned short* __restrict__ arena) {
  int mid = blockIdx.y;
  int e = blockIdx.x * 256 + threadIdx.x;
  int KN = a.elems[mid];
  if (e >= KN) return;
  int K = a.Kd[mid], N = a.Nd[mid];
  int n = e / K, k = e - n * K;
  float wv = a.src[mid][k * N + n];
  unsigned short hi, lo;
  split_bf(wv, hi, lo);
  arena[a.dst[mid] + e] = hi;
  arena[a.dst[mid] + KN + e] = lo;
}

// ---------------------------------------------------------------------------
// K1: input MLP via MFMA. 16 tokens/block.
// ---------------------------------------------------------------------------
__global__ __launch_bounds__(256) void k_input_mlp(
    const float* __restrict__ embed, const float* __restrict__ z,
    const float* __restrict__ cond, const unsigned short* __restrict__ arena,
    const float* __restrict__ bin1, const float* __restrict__ bin2,
    float* __restrict__ x) {
  __shared__ __align__(16) unsigned short Ah[16 * 136], Al[16 * 136];
  __shared__ __align__(16) unsigned short Hh[16 * 264], Hl[16 * 264];
  int t = threadIdx.x, w = t >> 6, lane = t & 63;
  int lq = lane & 15, quad = lane >> 4;
  int tok0 = blockIdx.x * 16;
  for (int idx = t; idx < 2048; idx += 256) {
    int tok = idx >> 7, dim = idx & 127;
    int bl = tok0 + tok, l = bl & (LL - 1);
    float v;
    if (dim < 123) v = embed[l * 123 + dim];
    else if (dim == 123) v = z[bl];
    else v = cond[dim - 124];
    unsigned short hi, lo;
    split_bf(v, hi, lo);
    Ah[tok * 136 + dim] = hi;
    Al[tok * 136 + dim] = lo;
  }
  __syncthreads();
  // G1: 128 -> 256, gelu
  const unsigned short* B1h = arena + OFF_WIN1;
  const unsigned short* B1l = B1h + 32768;
#pragma unroll
  for (int j = 0; j < 4; ++j) {
    int tl = w * 4 + j, n = tl * 16 + lq;
    float bb = bin1[n];
    floatx4 C = {bb, bb, bb, bb};
    C = mfma_tile<128, 136>(Ah, Al, B1h + tl * 16 * 128, B1l + tl * 16 * 128,
                            lq, quad, C);
#pragma unroll
    for (int r = 0; r < 4; ++r) {
      float g = gelu_tanh(C[r]);
      unsigned short hi, lo;
      split_bf(g, hi, lo);
      Hh[(quad * 4 + r) * 264 + n] = hi;
      Hl[(quad * 4 + r) * 264 + n] = lo;
    }
  }
  __syncthreads();
  // G2: 256 -> 64
  const unsigned short* B2h = arena + OFF_WIN2;
  const unsigned short* B2l = B2h + 16384;
  {
    int n = w * 16 + lq;
    float bb = bin2[n];
    floatx4 C = {bb, bb, bb, bb};
    C = mfma_tile<256, 264>(Hh, Hl, B2h + w * 16 * 256, B2l + w * 16 * 256,
                            lq, quad, C);
#pragma unroll
    for (int r = 0; r < 4; ++r)
      x[(size_t)(tok0 + quad * 4 + r) * 64 + n] = C[r];
  }
}

// ---------------------------------------------------------------------------
// K3: merged [RBF bias (both layers) | LN + Q/K/V] flat-grid kernel.
// bid < bias_blocks: bias role. Else: qkv role, mat = rem>>9, blk = rem&511.
// ---------------------------------------------------------------------------
__global__ __launch_bounds__(256) void k_qkv(
    const float* __restrict__ x, const float* __restrict__ ln_s,
    const float* __restrict__ ln_b, const unsigned short* __restrict__ arena,
    const float* __restrict__ bq, const float* __restrict__ bk,
    const float* __restrict__ bv, unsigned short* __restrict__ qo,
    unsigned short* __restrict__ ko, unsigned short* __restrict__ vo, int lay,
    int bias_blocks, const float* __restrict__ s,
    const float* __restrict__ rbf_c, const float* __restrict__ rbf_logw,
    const float* __restrict__ rbf_w, const float* __restrict__ rbf_b,
    unsigned short* __restrict__ biasT) {
  __shared__ __align__(16) unsigned short Ah[16 * 72], Al[16 * 72];
  int t = threadIdx.x;
  int bid = blockIdx.x;
  if (bid < bias_blocks) {
    // ---- bias role ----
    int blay = bid >> 12;
    int id = (bid & 4095) * 256 + t;
    int k = id >> 10, q = id & 1023;
    float dd = s[q] - s[k];
    float acc[8];
#pragma unroll
    for (int h = 0; h < 8; ++h) acc[h] = rbf_b[blay * 8 + h];
#pragma unroll 1
    for (int f = 0; f < 16; ++f) {
      float c = rbf_c[blay * 16 + f];
      float inv2w2 = 0.5f * __expf(-2.0f * rbf_logw[blay * 16 + f]);
      float e = dd - c;
      float ph = __expf(-e * e * inv2w2);
#pragma unroll
      for (int h = 0; h < 8; ++h)
        acc[h] = fmaf(ph, rbf_w[blay * 128 + f * 8 + h], acc[h]);
    }
    unsigned short* bT = biasT + (size_t)blay * 8 * 1024 * 1024;
#pragma unroll
    for (int h = 0; h < 8; ++h)
      bT[(size_t)(h * 1024 + k) * 1024 + q] = f2bf(acc[h]);
    return;
  }
  // ---- qkv role ----
  int rem = bid - bias_blocks;
  int mat = rem >> 9, blk = rem & 511;
  int w = t >> 6, lane = t & 63;
  int tok0 = blk * 16;
  float ss = ln_s[lay * 64 + lane], sb = ln_b[lay * 64 + lane];
#pragma unroll
  for (int tk = 0; tk < 4; ++tk) {
    int tok = w * 4 + tk;
    float v = x[(size_t)(tok0 + tok) * 64 + lane];
    float mean = wave_reduce_sum(v) * 0.015625f;
    float d = v - mean;
    float var = wave_reduce_sum(d * d) * 0.015625f;
    float hv = d * rsqrtf(var + 1e-6f) * ss + sb;
    unsigned short hi, lo;
    split_bf(hv, hi, lo);
    Ah[tok * 72 + lane] = hi;
    Al[tok * 72 + lane] = lo;
  }
  __syncthreads();
  int lq = lane & 15, quad = lane >> 4;
  const unsigned short* Bh = arena + OFF_LAY0 + lay * LAY_STRIDE + mat * 16384;
  const unsigned short* Bl = Bh + 8192;
  const float* bias = (mat == 0 ? bq : mat == 1 ? bk : bv) + lay * 128;
  unsigned short* outp = (mat == 0 ? qo : mat == 1 ? ko : vo);
  int b = tok0 >> 10, l0 = tok0 & 1023;
#pragma unroll
  for (int j = 0; j < 2; ++j) {
    int tl = w + j * 4;  // == head index
    int n = tl * 16 + lq;
    float bb = bias[n];
    floatx4 C = {bb, bb, bb, bb};
    C = mfma_tile<64, 72>(Ah, Al, Bh + tl * 16 * 64, Bl + tl * 16 * 64,
                          lq, quad, C);
    size_t basea = ((size_t)(b * 8 + tl) * 1024 + l0 + quad * 4) * 16 + lq;
#pragma unroll
    for (int r = 0; r < 4; ++r)
      outp[basea + (size_t)r * 16] = f2bf(C[r]);
  }
}

// ---------------------------------------------------------------------------
// K4: MFMA flash attention with LDS bias staging + register prefetch.
// Block = (b, h, 64 q rows); 4 waves x 16 q each.
// ---------------------------------------------------------------------------
__global__ __launch_bounds__(256) void k_attn(
    const unsigned short* __restrict__ qg, const unsigned short* __restrict__ kg,
    const unsigned short* __restrict__ vg, const unsigned short* __restrict__ biasT,
    float* __restrict__ og) {
  __shared__ __align__(16) unsigned short Kl[64 * 32];     // 4 KB
  __shared__ __align__(16) unsigned short VT[16 * 72];     // 2.25 KB
  __shared__ __align__(16) unsigned short Pl[4][16 * 72];  // 9 KB
  __shared__ __align__(16) unsigned short Bch[64 * 68];    // 8.5 KB bias chunk
  int t = threadIdx.x, w = t >> 6, lane = t & 63;
  int lq = lane & 15, quad = lane >> 4;
  int bid = blockIdx.x;
  int b = bid >> 7, h = (bid >> 4) & 7, qblk = bid & 15;
  int q0w = qblk * 64 + w * 16;
  size_t bh = (size_t)(b * 8 + h) * 1024;

  ((uint4*)Kl)[t] = uint4{0, 0, 0, 0};  // zero d16..31 pad

  short8 Qb = {};
  if (quad < 2)
    Qb = *(const short8*)(qg + (bh + q0w + lq) * 16 + quad * 8);

  float m = -1e30f, l = 0.0f;
  floatx4 O = {0.0f, 0.0f, 0.0f, 0.0f};

  // staging assignments
  int key = t >> 2, dp = (t & 3) * 4;
  const unsigned short* kgp = kg + (bh + key) * 16 + dp;
  const unsigned short* vgp = vg + (bh + key) * 16 + dp;
  int brow = t >> 3, bcol = (t & 7) * 8;  // bias: 2 uint4/thread (rows brow, brow+32)
  const unsigned short* bgp =
      biasT + ((size_t)h * 1024) * 1024 + qblk * 64 + bcol;

  // prefetch chunk 0
  uint2 kpre = *(const uint2*)(kgp);
  uint2 vpre = *(const uint2*)(vgp);
  uint4 bp0 = *(const uint4*)(bgp + (size_t)brow * 1024);
  uint4 bp1 = *(const uint4*)(bgp + (size_t)(brow + 32) * 1024);

#pragma unroll 1
  for (int kc = 0; kc < 1024; kc += 64) {
    __syncthreads();
    // write prefetched chunk into LDS
    *(uint2*)(Kl + key * 32 + dp) = kpre;
    VT[(dp + 0) * 72 + key] = (unsigned short)(vpre.x & 0xffff);
    VT[(dp + 1) * 72 + key] = (unsigned short)(vpre.x >> 16);
    VT[(dp + 2) * 72 + key] = (unsigned short)(vpre.y & 0xffff);
    VT[(dp + 3) * 72 + key] = (unsigned short)(vpre.y >> 16);
    {
      unsigned* p0 = (unsigned*)(Bch + brow * 68 + bcol);
      p0[0] = bp0.x; p0[1] = bp0.y;
      unsigned* p1 = (unsigned*)(Bch + brow * 68 + bcol + 4);
      p1[0] = bp0.z; p1[1] = bp0.w;
      unsigned* p2 = (unsigned*)(Bch + (brow + 32) * 68 + bcol);
      p2[0] = bp1.x; p2[1] = bp1.y;
      unsigned* p3 = (unsigned*)(Bch + (brow + 32) * 68 + bcol + 4);
      p3[0] = bp1.z; p3[1] = bp1.w;
    }
    __syncthreads();
    // issue prefetch for next chunk (hidden behind compute)
    if (kc + 64 < 1024) {
      kpre = *(const uint2*)(kgp + (size_t)(kc + 64) * 16);
      vpre = *(const uint2*)(vgp + (size_t)(kc + 64) * 16);
      bp0 = *(const uint4*)(bgp + (size_t)(kc + 64 + brow) * 1024);
      bp1 = *(const uint4*)(bgp + (size_t)(kc + 64 + brow + 32) * 1024);
    }
    // QK^T (transposed) + bias from LDS
    float s[16];
#pragma unroll
    for (int tile = 0; tile < 4; ++tile) {
      short8 A = *(const short8*)(Kl + (tile * 16 + lq) * 32 + quad * 8);
      floatx4 c = {0.0f, 0.0f, 0.0f, 0.0f};
      c = __builtin_amdgcn_mfma_f32_16x16x32_bf16(A, Qb, c, 0, 0, 0);
#pragma unroll
      for (int r = 0; r < 4; ++r)
        s[tile * 4 + r] =
            fmaf(c[r], 0.25f,
                 bf2f(Bch[(tile * 16 + quad * 4 + r) * 68 + w * 16 + lq]));
    }
    // online softmax (state keyed by column q = lane&15)
    float cm = s[0];
#pragma unroll
    for (int i = 1; i < 16; ++i) cm = fmaxf(cm, s[i]);
    cm = fmaxf(cm, __shfl_xor(cm, 16, 64));
    cm = fmaxf(cm, __shfl_xor(cm, 32, 64));
    float mnew = fmaxf(m, cm);
    float alpha = __expf(m - mnew);
    float p[16], psum = 0.0f;
#pragma unroll
    for (int i = 0; i < 16; ++i) {
      p[i] = __expf(s[i] - mnew);
      psum += p[i];
    }
    psum += __shfl_xor(psum, 16, 64);
    psum += __shfl_xor(psum, 32, 64);
    l = l * alpha + psum;
    m = mnew;
    // P -> bf16 -> per-wave LDS (A-layout bounce)
    unsigned short* pw = &Pl[w][lq * 72];
#pragma unroll
    for (int tile = 0; tile < 4; ++tile) {
      uint2 pk;
      pk.x = (unsigned)f2bf(p[tile * 4 + 0]) | ((unsigned)f2bf(p[tile * 4 + 1]) << 16);
      pk.y = (unsigned)f2bf(p[tile * 4 + 2]) | ((unsigned)f2bf(p[tile * 4 + 3]) << 16);
      *(uint2*)(pw + tile * 16 + quad * 4) = pk;
    }
    asm volatile("s_waitcnt lgkmcnt(0)" ::: "memory");
    // rescale O (rows keyed q = quad*4+r)
#pragma unroll
    for (int r = 0; r < 4; ++r) {
      int idx = (quad * 4 + r) * 4;
      float ar = __uint_as_float(
          __builtin_amdgcn_ds_bpermute(idx, __float_as_uint(alpha)));
      O[r] *= ar;
    }
    // PV: 2 MFMAs (K=32 keys each)
#pragma unroll
    for (int i = 0; i < 2; ++i) {
      short8 Pa = *(const short8*)(pw + i * 32 + quad * 8);
      short8 Vb = *(const short8*)(&VT[lq * 72 + i * 32 + quad * 8]);
      O = __builtin_amdgcn_mfma_f32_16x16x32_bf16(Pa, Vb, O, 0, 0, 0);
    }
  }
  float linv = 1.0f / l;
#pragma unroll
  for (int r = 0; r < 4; ++r) {
    int idx = (quad * 4 + r) * 4;
    float lr = __uint_as_float(
        __builtin_amdgcn_ds_bpermute(idx, __float_as_uint(linv)));
    og[((size_t)(b * 1024 + q0w + quad * 4 + r)) * 128 + h * 16 + lq] = O[r] * lr;
  }
}

// ---------------------------------------------------------------------------
// K5: fused proj + LN2 + FFN via MFMA. 16 tokens/block.
// ---------------------------------------------------------------------------
__global__ __launch_bounds__(256) void k_proj_ffn(
    const float* __restrict__ ob, const unsigned short* __restrict__ arena,
    const float* __restrict__ bo, float* __restrict__ x,
    const float* __restrict__ ln_s, const float* __restrict__ ln_b,
    const float* __restrict__ b1, const float* __restrict__ b2, int lay) {
  __shared__ __align__(16) unsigned short Ah[16 * 136], Al[16 * 136];  // o split
  __shared__ __align__(16) unsigned short Sh[16 * 72], Sl[16 * 72];    // LN2 split
  __shared__ __align__(16) unsigned short Hh[16 * 264], Hl[16 * 264];  // hid split
  __shared__ float xl[16 * 64];
  int t = threadIdx.x, w = t >> 6, lane = t & 63;
  int lq = lane & 15, quad = lane >> 4;
  int tok0 = blockIdx.x * 16;
  const unsigned short* labase = arena + OFF_LAY0 + lay * LAY_STRIDE;
  // stage o split
  for (int idx = t * 4; idx < 2048; idx += 1024) {
    int row = idx >> 7, col = idx & 127;
    float4 v = *(const float4*)(ob + (size_t)(tok0 + row) * 128 + col);
    unsigned short h0, e0, h1, e1, h2, e2, h3, e3;
    split_bf(v.x, h0, e0); split_bf(v.y, h1, e1);
    split_bf(v.z, h2, e2); split_bf(v.w, h3, e3);
    unsigned* ph = (unsigned*)(Ah + row * 136 + col);
    ph[0] = (unsigned)h0 | ((unsigned)h1 << 16);
    ph[1] = (unsigned)h2 | ((unsigned)h3 << 16);
    unsigned* pl = (unsigned*)(Al + row * 136 + col);
    pl[0] = (unsigned)e0 | ((unsigned)e1 << 16);
    pl[1] = (unsigned)e2 | ((unsigned)e3 << 16);
  }
  __syncthreads();
  // proj: 128 -> 64, + residual -> xl
  {
    const unsigned short* Bh = labase + OFF_WO;
    const unsigned short* Bl = Bh + 8192;
    int n = w * 16 + lq;
    float bb = bo[lay * 64 + n];
    floatx4 C = {bb, bb, bb, bb};
    C = mfma_tile<128, 136>(Ah, Al, Bh + w * 16 * 128, Bl + w * 16 * 128,
                            lq, quad, C);
#pragma unroll
    for (int r = 0; r < 4; ++r) {
      int m = quad * 4 + r;
      float xv = x[(size_t)(tok0 + m) * 64 + n] + C[r];
      xl[m * 64 + n] = xv;
    }
  }
  __syncthreads();
  // LN2
  {
    float ss = ln_s[lay * 64 + lane], sb = ln_b[lay * 64 + lane];
#pragma unroll
    for (int tk = 0; tk < 4; ++tk) {
      int tok = w * 4 + tk;
      float v = xl[tok * 64 + lane];
      float mean = wave_reduce_sum(v) * 0.015625f;
      float d = v - mean;
      float var = wave_reduce_sum(d * d) * 0.015625f;
      float hv = d * rsqrtf(var + 1e-6f) * ss + sb;
      unsigned short hi, lo;
      split_bf(hv, hi, lo);
      Sh[tok * 72 + lane] = hi;
      Sl[tok * 72 + lane] = lo;
    }
  }
  __syncthreads();
  // FFN G1: 64 -> 256, gelu
  {
    const unsigned short* Bh = labase + OFF_W1;
    const unsigned short* Bl = Bh + 16384;
#pragma unroll
    for (int j = 0; j < 4; ++j) {
      int tl = w * 4 + j, n = tl * 16 + lq;
      float bb = b1[lay * 256 + n];
      floatx4 C = {bb, bb, bb, bb};
      C = mfma_tile<64, 72>(Sh, Sl, Bh + tl * 16 * 64, Bl + tl * 16 * 64,
                            lq, quad, C);
#pragma unroll
      for (int r = 0; r < 4; ++r) {
        float g = gelu_tanh(C[r]);
        unsigned short hi, lo;
        split_bf(g, hi, lo);
        Hh[(quad * 4 + r) * 264 + n] = hi;
        Hl[(quad * 4 + r) * 264 + n] = lo;
      }
    }
  }
  __syncthreads();
  // FFN G2: 256 -> 64, + residual -> x
  {
    const unsigned short* Bh = labase + OFF_W2;
    const unsigned short* Bl = Bh + 16384;
    int n = w * 16 + lq;
    float bb = b2[lay * 64 + n];
    floatx4 C = {bb, bb, bb, bb};
    C = mfma_tile<256, 264>(Hh, Hl, Bh + w * 16 * 256, Bl + w * 16 * 256,
                            lq, quad, C);
#pragma unroll
    for (int r = 0; r < 4; ++r) {
      int m = quad * 4 + r;
      x[(size_t)(tok0 + m) * 64 + n] = xl[m * 64 + n] + C[r];
    }
  }
}

// ---------------------------------------------------------------------------
// K6: head MLP via MFMA. 16 tokens/block.
// ---------------------------------------------------------------------------
__global__ __launch_bounds__(256) void k_head(
    const float* __restrict__ x, const unsigned short* __restrict__ arena,
    const float* __restrict__ bh1, const float* __restrict__ bh2,
    const float* __restrict__ Wh3, const float* __restrict__ bh3,
    float* __restrict__ out) {
  __shared__ __align__(16) unsigned short Sh[16 * 72], Sl[16 * 72];
  __shared__ __align__(16) unsigned short Hh[16 * 264], Hl[16 * 264];
  __shared__ float h2s[16 * 64];
  int t = threadIdx.x, w = t >> 6, lane = t & 63;
  int lq = lane & 15, quad = lane >> 4;
  int tok0 = blockIdx.x * 16;
  {
    int idx = t * 4;
    int row = idx >> 6, col = idx & 63;
    float4 v = *(const float4*)(x + (size_t)(tok0 + row) * 64 + col);
    unsigned short h0, e0, h1, e1, h2, e2, h3, e3;
    split_bf(v.x, h0, e0); split_bf(v.y, h1, e1);
    split_bf(v.z, h2, e2); split_bf(v.w, h3, e3);
    unsigned* ph = (unsigned*)(Sh + row * 72 + col);
    ph[0] = (unsigned)h0 | ((unsigned)h1 << 16);
    ph[1] = (unsigned)h2 | ((unsigned)h3 << 16);
    unsigned* pl = (unsigned*)(Sl + row * 72 + col);
    pl[0] = (unsigned)e0 | ((unsigned)e1 << 16);
    pl[1] = (unsigned)e2 | ((unsigned)e3 << 16);
  }
  __syncthreads();
  // G1: 64 -> 256, gelu
  {
    const unsigned short* Bh = arena + OFF_WH1;
    const unsigned short* Bl = Bh + 16384;
#pragma unroll
    for (int j = 0; j < 4; ++j) {
      int tl = w * 4 + j, n = tl * 16 + lq;
      float bb = bh1[n];
      floatx4 C = {bb, bb, bb, bb};
      C = mfma_tile<64, 72>(Sh, Sl, Bh + tl * 16 * 64, Bl + tl * 16 * 64,
                            lq, quad, C);
#pragma unroll
      for (int r = 0; r < 4; ++r) {
        float g = gelu_tanh(C[r]);
        unsigned short hi, lo;
        split_bf(g, hi, lo);
        Hh[(quad * 4 + r) * 264 + n] = hi;
        Hl[(quad * 4 + r) * 264 + n] = lo;
      }
    }
  }
  __syncthreads();
  // G2: 256 -> 64, gelu -> h2s
  {
    const unsigned short* Bh = arena + OFF_WH2;
    const unsigned short* Bl = Bh + 16384;
    int n = w * 16 + lq;
    float bb = bh2[n];
    floatx4 C = {bb, bb, bb, bb};
    C = mfma_tile<256, 264>(Hh, Hl, Bh + w * 16 * 256, Bl + w * 16 * 256,
                            lq, quad, C);
#pragma unroll
    for (int r = 0; r < 4; ++r)
      h2s[(quad * 4 + r) * 64 + n] = gelu_tanh(C[r]);
  }
  __syncthreads();
  // G3: dot with Wh3
  float wv3 = Wh3[lane];
#pragma unroll
  for (int tk = 0; tk < 4; ++tk) {
    int tok = w * 4 + tk;
    float v = h2s[tok * 64 + lane] * wv3;
    float sum = wave_reduce_sum(v);
    if (lane == 0) out[tok0 + tok] = sum + bh3[0];
  }
}

// ---------------------------------------------------------------------------
extern "C" void kernel_launch(void* const* d_in, const int* in_sizes, int n_in,
                              void* d_out, int out_size, void* d_ws, size_t ws_size,
                              hipStream_t stream) {
  const float* z      = (const float*)d_in[0];
  const float* cond   = (const float*)d_in[1];
  const float* s      = (const float*)d_in[2];
  const float* embed  = (const float*)d_in[3];
  const float* Win1   = (const float*)d_in[4];
  const float* bin1   = (const float*)d_in[5];
  const float* Win2   = (const float*)d_in[6];
  const float* bin2   = (const float*)d_in[7];
  const float* ln1_s  = (const float*)d_in[8];
  const float* ln1_b  = (const float*)d_in[9];
  const float* ln2_s  = (const float*)d_in[10];
  const float* ln2_b  = (const float*)d_in[11];
  const float* Wq     = (const float*)d_in[12];
  const float* bq     = (const float*)d_in[13];
  const float* Wk     = (const float*)d_in[14];
  const float* bk     = (const float*)d_in[15];
  const float* Wv     = (const float*)d_in[16];
  const float* bv     = (const float*)d_in[17];
  const float* Wo     = (const float*)d_in[18];
  const float* bo     = (const float*)d_in[19];
  const float* rbf_c  = (const float*)d_in[20];
  const float* rbf_lw = (const float*)d_in[21];
  const float* rbf_w  = (const float*)d_in[22];
  const float* rbf_b  = (const float*)d_in[23];
  const float* W1     = (const float*)d_in[24];
  const float* b1     = (const float*)d_in[25];
  const float* W2     = (const float*)d_in[26];
  const float* b2     = (const float*)d_in[27];
  const float* Wh1    = (const float*)d_in[28];
  const float* bh1    = (const float*)d_in[29];
  const float* Wh2    = (const float*)d_in[30];
  const float* bh2    = (const float*)d_in[31];
  const float* Wh3    = (const float*)d_in[32];
  const float* bh3    = (const float*)d_in[33];

  char* base = (char*)d_ws;
  float*          x     = (float*)(base);                          // 2 MB
  unsigned short* qb    = (unsigned short*)(base + (2u << 20));    // 2 MB
  unsigned short* kb    = (unsigned short*)(base + (4u << 20));    // 2 MB
  unsigned short* vb    = (unsigned short*)(base + (6u << 20));    // 2 MB
  float*          ob    = (float*)(base + (8u << 20));             // 4 MB
  unsigned short* biasT = (unsigned short*)(base + (12u << 20));   // 2 x 16 MB
  unsigned short* arena = (unsigned short*)(base + (48u << 20));   // ~832 KB

  PrepArgs pa;
  auto set = [&](int i, const float* sp, int K, int N, int dst) {
    pa.src[i] = sp; pa.Kd[i] = K; pa.Nd[i] = N; pa.dst[i] = dst;
    pa.elems[i] = K * N;
  };
  set(0, Win1, 128, 256, OFF_WIN1);
  set(1, Win2, 256, 64, OFF_WIN2);
  for (int lay = 0; lay < 2; ++lay) {
    int lb = OFF_LAY0 + lay * LAY_STRIDE;
    set(2 + lay * 6, Wq + lay * 8192, 64, 128, lb + OFF_WQ);
    set(3 + lay * 6, Wk + lay * 8192, 64, 128, lb + OFF_WK);
    set(4 + lay * 6, Wv + lay * 8192, 64, 128, lb + OFF_WV);
    set(5 + lay * 6, Wo + lay * 8192, 128, 64, lb + OFF_WO);
    set(6 + lay * 6, W1 + lay * 16384, 64, 256, lb + OFF_W1);
    set(7 + lay * 6, W2 + lay * 16384, 256, 64, lb + OFF_W2);
  }
  set(14, Wh1, 64, 256, OFF_WH1);
  set(15, Wh2, 256, 64, OFF_WH2);

  k_prep<<<dim3(128, 16), 256, 0, stream>>>(pa, arena);
  k_input_mlp<<<512, 256, 0, stream>>>(embed, z, cond, arena, bin1, bin2, x);
  for (int lay = 0; lay < 2; ++lay) {
    int bias_blocks = (lay == 0) ? 8192 : 0;
    k_qkv<<<bias_blocks + 1536, 256, 0, stream>>>(
        x, ln1_s, ln1_b, arena, bq, bk, bv, qb, kb, vb, lay,
        bias_blocks, s, rbf_c, rbf_lw, rbf_w, rbf_b, biasT);
    k_attn<<<1024, 256, 0, stream>>>(qb, kb, vb,
                                     biasT + (size_t)lay * 8 * 1024 * 1024, ob);
    k_proj_ffn<<<512, 256, 0, stream>>>(ob, arena, bo, x, ln2_s, ln2_b,
                                        b1, b2, lay);
  }
  k_head<<<512, 256, 0, stream>>>(x, arena, bh1, bh2, Wh3, bh3, (float*)d_out);
}

// Round 8
// 275.407 us; speedup vs baseline: 3.5317x; 1.0215x over previous
//
#include <hip/hip_runtime.h>
#include <hip/hip_bf16.h>

// Problem constants (reference: B=8, L=1024, C=4, D=64, H=8, NB=2, K=16)
#define BB   8
#define LL   1024
#define DD   64
#define D2   128
#define D4   256
#define HH   8
#define DH   16

typedef __attribute__((ext_vector_type(8))) short short8;   // 8 bf16 (4 VGPRs)
typedef __attribute__((ext_vector_type(4))) float floatx4;  // MFMA C/D

// bf16 split-weight arena offsets (elements)
#define OFF_WIN1   0        // [256][128] hi, lo at +32768
#define OFF_WIN2   65536    // [64][256]  hi, lo at +16384
#define OFF_LAY0   98304
#define LAY_STRIDE 131072
#define OFF_WQ     0        // [128][64] hi, lo +8192
#define OFF_WK     16384
#define OFF_WV     32768
#define OFF_WO     49152    // [64][128] hi, lo +8192
#define OFF_W1     65536    // [256][64] hi, lo +16384
#define OFF_W2     98304    // [64][256] hi, lo +16384
#define OFF_WH1    360448   // [256][64] hi, lo +16384
#define OFF_WH2    393216   // [64][256] hi, lo +16384

__device__ __forceinline__ float gelu_tanh(float u) {
  float t = tanhf(0.7978845608028654f * (u + 0.044715f * u * u * u));
  return 0.5f * u * (1.0f + t);
}

__device__ __forceinline__ float wave_reduce_sum(float v) {
#pragma unroll
  for (int m = 32; m >= 1; m >>= 1) v += __shfl_xor(v, m, 64);
  return v;
}

__device__ __forceinline__ unsigned short f2bf(float x) {  // RNE
  unsigned u = __float_as_uint(x);
  u += 0x7fffu + ((u >> 16) & 1u);
  return (unsigned short)(u >> 16);
}

__device__ __forceinline__ float bf2f(unsigned short x) {
  return __uint_as_float(((unsigned)x) << 16);
}

__device__ __forceinline__ void split_bf(float v, unsigned short& hi,
                                         unsigned short& lo) {
  hi = f2bf(v);
  lo = f2bf(v - bf2f(hi));
}

// 16x16 output tile over K with 3-term bf16 split (ah*bh + al*bh + ah*bl).
template <int K, int KP>
__device__ __forceinline__ floatx4 mfma_tile(
    const unsigned short* Ah, const unsigned short* Al,
    const unsigned short* __restrict__ Bh, const unsigned short* __restrict__ Bl,
    int lq, int quad, floatx4 C) {
#pragma unroll
  for (int kk = 0; kk < K; kk += 32) {
    short8 ah = *(const short8*)(Ah + lq * KP + kk + quad * 8);
    short8 al = *(const short8*)(Al + lq * KP + kk + quad * 8);
    short8 bh = *(const short8*)(Bh + lq * K + kk + quad * 8);
    short8 bl = *(const short8*)(Bl + lq * K + kk + quad * 8);
    C = __builtin_amdgcn_mfma_f32_16x16x32_bf16(ah, bh, C, 0, 0, 0);
    C = __builtin_amdgcn_mfma_f32_16x16x32_bf16(al, bh, C, 0, 0, 0);
    C = __builtin_amdgcn_mfma_f32_16x16x32_bf16(ah, bl, C, 0, 0, 0);
  }
  return C;
}

// ---------------------------------------------------------------------------
// K0: weight prep — transpose fp32 W[k][n] -> bf16 hi/lo planes T[n][k].
// ---------------------------------------------------------------------------
struct PrepArgs {
  const float* src[16];
  int Kd[16], Nd[16], dst[16], elems[16];
};

__global__ __launch_bounds__(256) void k_prep(PrepArgs a,
                                              unsigned short* __restrict__ arena) {
  int mid = blockIdx.y;
  int e = blockIdx.x * 256 + threadIdx.x;
  int KN = a.elems[mid];
  if (e >= KN) return;
  int K = a.Kd[mid], N = a.Nd[mid];
  int n = e / K, k = e - n * K;
  float wv = a.src[mid][k * N + n];
  unsigned short hi, lo;
  split_bf(wv, hi, lo);
  arena[a.dst[mid] + e] = hi;
  arena[a.dst[mid] + KN + e] = lo;
}

// ---------------------------------------------------------------------------
// K2: RBF bias, both layers (blockIdx.y = lay), bf16, biasT[lay][h][q][k].
// ---------------------------------------------------------------------------
__global__ __launch_bounds__(256) void k_bias(
    const float* __restrict__ s, const float* __restrict__ rbf_c,
    const float* __restrict__ rbf_logw, const float* __restrict__ rbf_w,
    const float* __restrict__ rbf_b, unsigned short* __restrict__ biasT) {
  int lay = blockIdx.y;
  int id = blockIdx.x * 256 + threadIdx.x;
  int q = id >> 10, k = id & 1023;
  float dd = s[q] - s[k];  // dist[q,k] = s[q]-s[k]
  float acc[8];
#pragma unroll
  for (int h = 0; h < 8; ++h) acc[h] = rbf_b[lay * 8 + h];
#pragma unroll 1
  for (int f = 0; f < 16; ++f) {
    float c = rbf_c[lay * 16 + f];
    float inv2w2 = 0.5f * __expf(-2.0f * rbf_logw[lay * 16 + f]);
    float e = dd - c;
    float ph = __expf(-e * e * inv2w2);
#pragma unroll
    for (int h = 0; h < 8; ++h)
      acc[h] = fmaf(ph, rbf_w[lay * 128 + f * 8 + h], acc[h]);
  }
  unsigned short* bT = biasT + (size_t)lay * 8 * 1024 * 1024;
#pragma unroll
  for (int h = 0; h < 8; ++h)
    bT[(size_t)(h * 1024 + q) * 1024 + k] = f2bf(acc[h]);
}

// Shared QKV tail: LN(xl) -> split -> 3 MFMA mats -> q/k global, v transposed.
__device__ __forceinline__ void qkv_tail(
    const float* xl, unsigned short* Sh, unsigned short* Sl,
    const unsigned short* __restrict__ arena, int lay,
    const float* __restrict__ ln_s, const float* __restrict__ ln_b,
    const float* __restrict__ bq, const float* __restrict__ bk,
    const float* __restrict__ bv, unsigned short* __restrict__ qo,
    unsigned short* __restrict__ ko, unsigned short* __restrict__ voT,
    int tok0, int t) {
  int w = t >> 6, lane = t & 63;
  int lq = lane & 15, quad = lane >> 4;
  float ss = ln_s[lay * 64 + lane], sb = ln_b[lay * 64 + lane];
#pragma unroll
  for (int tk = 0; tk < 4; ++tk) {
    int tok = w * 4 + tk;
    float v = xl[tok * 64 + lane];
    float mean = wave_reduce_sum(v) * 0.015625f;
    float d = v - mean;
    float var = wave_reduce_sum(d * d) * 0.015625f;
    float hv = d * rsqrtf(var + 1e-6f) * ss + sb;
    unsigned short hi, lo;
    split_bf(hv, hi, lo);
    Sh[tok * 72 + lane] = hi;
    Sl[tok * 72 + lane] = lo;
  }
  __syncthreads();
  int b = tok0 >> 10, l0 = tok0 & 1023;
#pragma unroll 1
  for (int mat = 0; mat < 3; ++mat) {
    const unsigned short* Bh =
        arena + OFF_LAY0 + lay * LAY_STRIDE + mat * 16384;
    const unsigned short* Bl = Bh + 8192;
    const float* bias = (mat == 0 ? bq : mat == 1 ? bk : bv) + lay * 128;
#pragma unroll
    for (int j = 0; j < 2; ++j) {
      int tl = w + j * 4;  // head index
      int n = tl * 16 + lq;
      float bb = bias[n];
      floatx4 C = {bb, bb, bb, bb};
      C = mfma_tile<64, 72>(Sh, Sl, Bh + tl * 16 * 64, Bl + tl * 16 * 64,
                            lq, quad, C);
      if (mat < 2) {
        unsigned short* outp = (mat == 0 ? qo : ko);
        size_t basea = ((size_t)(b * 8 + tl) * 1024 + l0 + quad * 4) * 16 + lq;
#pragma unroll
        for (int r = 0; r < 4; ++r)
          outp[basea + (size_t)r * 16] = f2bf(C[r]);
      } else {
        size_t basev = ((size_t)(b * 8 + tl) * 16 + lq) * 1024 + l0 + quad * 4;
#pragma unroll
        for (int r = 0; r < 4; ++r)
          voT[basev + r] = f2bf(C[r]);
      }
    }
  }
}

// ---------------------------------------------------------------------------
// K1: input MLP + LN1 + QKV (layer 0). 16 tokens/block.
// ---------------------------------------------------------------------------
__global__ __launch_bounds__(256) void k_in_qkv(
    const float* __restrict__ embed, const float* __restrict__ z,
    const float* __restrict__ cond, const unsigned short* __restrict__ arena,
    const float* __restrict__ bin1, const float* __restrict__ bin2,
    float* __restrict__ x, const float* __restrict__ ln1_s,
    const float* __restrict__ ln1_b, const float* __restrict__ bq,
    const float* __restrict__ bk, const float* __restrict__ bv,
    unsigned short* __restrict__ qo, unsigned short* __restrict__ ko,
    unsigned short* __restrict__ voT) {
  __shared__ __align__(16) unsigned short Ah[16 * 136], Al[16 * 136];
  __shared__ __align__(16) unsigned short Hh[16 * 264], Hl[16 * 264];
  __shared__ __align__(16) unsigned short Sh[16 * 72], Sl[16 * 72];
  __shared__ float xl[16 * 64];
  int t = threadIdx.x, w = t >> 6, lane = t & 63;
  int lq = lane & 15, quad = lane >> 4;
  int tok0 = blockIdx.x * 16;
  for (int idx = t; idx < 2048; idx += 256) {
    int tok = idx >> 7, dim = idx & 127;
    int bl = tok0 + tok, l = bl & (LL - 1);
    float v;
    if (dim < 123) v = embed[l * 123 + dim];
    else if (dim == 123) v = z[bl];
    else v = cond[dim - 124];
    unsigned short hi, lo;
    split_bf(v, hi, lo);
    Ah[tok * 136 + dim] = hi;
    Al[tok * 136 + dim] = lo;
  }
  __syncthreads();
  // G1: 128 -> 256, gelu
  const unsigned short* B1h = arena + OFF_WIN1;
  const unsigned short* B1l = B1h + 32768;
#pragma unroll
  for (int j = 0; j < 4; ++j) {
    int tl = w * 4 + j, n = tl * 16 + lq;
    float bb = bin1[n];
    floatx4 C = {bb, bb, bb, bb};
    C = mfma_tile<128, 136>(Ah, Al, B1h + tl * 16 * 128, B1l + tl * 16 * 128,
                            lq, quad, C);
#pragma unroll
    for (int r = 0; r < 4; ++r) {
      float g = gelu_tanh(C[r]);
      unsigned short hi, lo;
      split_bf(g, hi, lo);
      Hh[(quad * 4 + r) * 264 + n] = hi;
      Hl[(quad * 4 + r) * 264 + n] = lo;
    }
  }
  __syncthreads();
  // G2: 256 -> 64 -> x (global + xl)
  const unsigned short* B2h = arena + OFF_WIN2;
  const unsigned short* B2l = B2h + 16384;
  {
    int n = w * 16 + lq;
    float bb = bin2[n];
    floatx4 C = {bb, bb, bb, bb};
    C = mfma_tile<256, 264>(Hh, Hl, B2h + w * 16 * 256, B2l + w * 16 * 256,
                            lq, quad, C);
#pragma unroll
    for (int r = 0; r < 4; ++r) {
      int m = quad * 4 + r;
      x[(size_t)(tok0 + m) * 64 + n] = C[r];
      xl[m * 64 + n] = C[r];
    }
  }
  __syncthreads();
  qkv_tail(xl, Sh, Sl, arena, 0, ln1_s, ln1_b, bq, bk, bv,
           qo, ko, voT, tok0, t);
}

// ---------------------------------------------------------------------------
// K4: MFMA flash attention, fully vectorized LDS. Block=(b,h,64 q rows).
// bias [h][q][k]; V pre-transposed in global [bh][d][l].
// ---------------------------------------------------------------------------
__global__ __launch_bounds__(256) void k_attn(
    const unsigned short* __restrict__ qg, const unsigned short* __restrict__ kg,
    const unsigned short* __restrict__ vgT, const unsigned short* __restrict__ biasT,
    float* __restrict__ og) {
  __shared__ __align__(16) unsigned short Kl[64 * 32];     // 4 KB
  __shared__ __align__(16) unsigned short VT[16 * 72];     // 2.25 KB
  __shared__ __align__(16) unsigned short Pl[4][16 * 72];  // 9 KB
  __shared__ __align__(16) unsigned short Bch[64 * 72];    // 9 KB [q][k]
  int t = threadIdx.x, w = t >> 6, lane = t & 63;
  int lq = lane & 15, quad = lane >> 4;
  int bid = blockIdx.x;
  int b = bid >> 7, h = (bid >> 4) & 7, qblk = bid & 15;
  int q0w = qblk * 64 + w * 16;
  size_t bh = (size_t)(b * 8 + h) * 1024;
  size_t bh16 = (size_t)(b * 8 + h) * 16;

  ((uint4*)Kl)[t] = uint4{0, 0, 0, 0};  // zero d16..31 pad

  short8 Qb = {};
  if (quad < 2)
    Qb = *(const short8*)(qg + (bh + q0w + lq) * 16 + quad * 8);

  float m = -1e30f, l = 0.0f;
  floatx4 O = {0.0f, 0.0f, 0.0f, 0.0f};

  // staging assignments (all vectorized)
  int key = t >> 2, dp = (t & 3) * 4;        // K: 1 uint2 / thread
  int drow = t >> 4, vcol = (t & 15) * 4;    // V^T: 1 uint2 / thread
  int qrow = t >> 2, bcol = (t & 3) * 16;    // bias: 2 uint4 / thread (16 ush)
  const unsigned short* kgp = kg + (bh + key) * 16 + dp;
  const unsigned short* vgp = vgT + (bh16 + drow) * 1024 + vcol;
  const unsigned short* bgp =
      biasT + ((size_t)(h * 1024 + qblk * 64 + qrow)) * 1024 + bcol;

  uint2 kpre = *(const uint2*)(kgp);
  uint2 vpre = *(const uint2*)(vgp);
  uint4 bpre0 = *(const uint4*)(bgp);
  uint4 bpre1 = *(const uint4*)(bgp + 8);

#pragma unroll 1
  for (int kc = 0; kc < 1024; kc += 64) {
    __syncthreads();
    *(uint2*)(Kl + key * 32 + dp) = kpre;
    *(uint2*)(VT + drow * 72 + vcol) = vpre;
    *(uint4*)(Bch + qrow * 72 + bcol) = bpre0;
    *(uint4*)(Bch + qrow * 72 + bcol + 8) = bpre1;
    __syncthreads();
    if (kc + 64 < 1024) {
      kpre = *(const uint2*)(kgp + (size_t)(kc + 64) * 16);
      vpre = *(const uint2*)(vgp + (kc + 64));
      bpre0 = *(const uint4*)(bgp + (kc + 64));
      bpre1 = *(const uint4*)(bgp + (kc + 64) + 8);
    }
    // QK^T (transposed) + bias (b64 per tile)
    float s[16];
#pragma unroll
    for (int tile = 0; tile < 4; ++tile) {
      short8 A = *(const short8*)(Kl + (tile * 16 + lq) * 32 + quad * 8);
      floatx4 c = {0.0f, 0.0f, 0.0f, 0.0f};
      c = __builtin_amdgcn_mfma_f32_16x16x32_bf16(A, Qb, c, 0, 0, 0);
      ushort4 bb = *(const ushort4*)(Bch + (w * 16 + lq) * 72 +
                                     tile * 16 + quad * 4);
      s[tile * 4 + 0] = fmaf(c[0], 0.25f, bf2f(bb.x));
      s[tile * 4 + 1] = fmaf(c[1], 0.25f, bf2f(bb.y));
      s[tile * 4 + 2] = fmaf(c[2], 0.25f, bf2f(bb.z));
      s[tile * 4 + 3] = fmaf(c[3], 0.25f, bf2f(bb.w));
    }
    // online softmax (state keyed by column q = lane&15)
    float cm = s[0];
#pragma unroll
    for (int i = 1; i < 16; ++i) cm = fmaxf(cm, s[i]);
    cm = fmaxf(cm, __shfl_xor(cm, 16, 64));
    cm = fmaxf(cm, __shfl_xor(cm, 32, 64));
    float mnew = fmaxf(m, cm);
    float alpha = __expf(m - mnew);
    float p[16], psum = 0.0f;
#pragma unroll
    for (int i = 0; i < 16; ++i) {
      p[i] = __expf(s[i] - mnew);
      psum += p[i];
    }
    psum += __shfl_xor(psum, 16, 64);
    psum += __shfl_xor(psum, 32, 64);
    l = l * alpha + psum;
    m = mnew;
    // P -> bf16 -> per-wave LDS (A-layout bounce)
    unsigned short* pw = &Pl[w][lq * 72];
#pragma unroll
    for (int tile = 0; tile < 4; ++tile) {
      uint2 pk;
      pk.x = (unsigned)f2bf(p[tile * 4 + 0]) | ((unsigned)f2bf(p[tile * 4 + 1]) << 16);
      pk.y = (unsigned)f2bf(p[tile * 4 + 2]) | ((unsigned)f2bf(p[tile * 4 + 3]) << 16);
      *(uint2*)(pw + tile * 16 + quad * 4) = pk;
    }
    asm volatile("s_waitcnt lgkmcnt(0)" ::: "memory");
    // rescale O (rows keyed q = quad*4+r)
#pragma unroll
    for (int r = 0; r < 4; ++r) {
      int idx = (quad * 4 + r) * 4;
      float ar = __uint_as_float(
          __builtin_amdgcn_ds_bpermute(idx, __float_as_uint(alpha)));
      O[r] *= ar;
    }
    // PV: 2 MFMAs (K=32 keys each)
#pragma unroll
    for (int i = 0; i < 2; ++i) {
      short8 Pa = *(const short8*)(pw + i * 32 + quad * 8);
      short8 Vb = *(const short8*)(&VT[lq * 72 + i * 32 + quad * 8]);
      O = __builtin_amdgcn_mfma_f32_16x16x32_bf16(Pa, Vb, O, 0, 0, 0);
    }
  }
  float linv = 1.0f / l;
#pragma unroll
  for (int r = 0; r < 4; ++r) {
    int idx = (quad * 4 + r) * 4;
    float lr = __uint_as_float(
        __builtin_amdgcn_ds_bpermute(idx, __float_as_uint(linv)));
    og[((size_t)(b * 1024 + q0w + quad * 4 + r)) * 128 + h * 16 + lq] = O[r] * lr;
  }
}

// Shared proj+LN2+FFN body. Returns with xl holding the post-FFN x rows.
__device__ __forceinline__ void pf_body(
    const float* __restrict__ ob, const unsigned short* __restrict__ arena,
    const float* __restrict__ bo, float* __restrict__ x,
    const float* __restrict__ ln_s, const float* __restrict__ ln_b,
    const float* __restrict__ b1, const float* __restrict__ b2, int lay,
    unsigned short* Ah, unsigned short* Al, unsigned short* Sh,
    unsigned short* Sl, unsigned short* Hh, unsigned short* Hl, float* xl,
    int tok0, int t, bool write_x) {
  int w = t >> 6, lane = t & 63;
  int lq = lane & 15, quad = lane >> 4;
  const unsigned short* labase = arena + OFF_LAY0 + lay * LAY_STRIDE;
  // stage attn-o split
  for (int idx = t * 4; idx < 2048; idx += 1024) {
    int row = idx >> 7, col = idx & 127;
    float4 v = *(const float4*)(ob + (size_t)(tok0 + row) * 128 + col);
    unsigned short h0, e0, h1, e1, h2, e2, h3, e3;
    split_bf(v.x, h0, e0); split_bf(v.y, h1, e1);
    split_bf(v.z, h2, e2); split_bf(v.w, h3, e3);
    unsigned* ph = (unsigned*)(Ah + row * 136 + col);
    ph[0] = (unsigned)h0 | ((unsigned)h1 << 16);
    ph[1] = (unsigned)h2 | ((unsigned)h3 << 16);
    unsigned* pl = (unsigned*)(Al + row * 136 + col);
    pl[0] = (unsigned)e0 | ((unsigned)e1 << 16);
    pl[1] = (unsigned)e2 | ((unsigned)e3 << 16);
  }
  __syncthreads();
  // proj: 128 -> 64, + residual -> xl
  {
    const unsigned short* Bh = labase + OFF_WO;
    const unsigned short* Bl = Bh + 8192;
    int n = w * 16 + lq;
    float bb = bo[lay * 64 + n];
    floatx4 C = {bb, bb, bb, bb};
    C = mfma_tile<128, 136>(Ah, Al, Bh + w * 16 * 128, Bl + w * 16 * 128,
                            lq, quad, C);
#pragma unroll
    for (int r = 0; r < 4; ++r) {
      int m = quad * 4 + r;
      xl[m * 64 + n] = x[(size_t)(tok0 + m) * 64 + n] + C[r];
    }
  }
  __syncthreads();
  // LN2 -> Sh/Sl
  {
    float ss = ln_s[lay * 64 + lane], sb = ln_b[lay * 64 + lane];
#pragma unroll
    for (int tk = 0; tk < 4; ++tk) {
      int tok = w * 4 + tk;
      float v = xl[tok * 64 + lane];
      float mean = wave_reduce_sum(v) * 0.015625f;
      float d = v - mean;
      float var = wave_reduce_sum(d * d) * 0.015625f;
      float hv = d * rsqrtf(var + 1e-6f) * ss + sb;
      unsigned short hi, lo;
      split_bf(hv, hi, lo);
      Sh[tok * 72 + lane] = hi;
      Sl[tok * 72 + lane] = lo;
    }
  }
  __syncthreads();
  // FFN G1: 64 -> 256, gelu
  {
    const unsigned short* Bh = labase + OFF_W1;
    const unsigned short* Bl = Bh + 16384;
#pragma unroll
    for (int j = 0; j < 4; ++j) {
      int tl = w * 4 + j, n = tl * 16 + lq;
      float bb = b1[lay * 256 + n];
      floatx4 C = {bb, bb, bb, bb};
      C = mfma_tile<64, 72>(Sh, Sl, Bh + tl * 16 * 64, Bl + tl * 16 * 64,
                            lq, quad, C);
#pragma unroll
      for (int r = 0; r < 4; ++r) {
        float g = gelu_tanh(C[r]);
        unsigned short hi, lo;
        split_bf(g, hi, lo);
        Hh[(quad * 4 + r) * 264 + n] = hi;
        Hl[(quad * 4 + r) * 264 + n] = lo;
      }
    }
  }
  __syncthreads();
  // FFN G2: 256 -> 64, + residual -> xl (and optionally x)
  {
    const unsigned short* Bh = labase + OFF_W2;
    const unsigned short* Bl = Bh + 16384;
    int n = w * 16 + lq;
    float bb = b2[lay * 64 + n];
    floatx4 C = {bb, bb, bb, bb};
    C = mfma_tile<256, 264>(Hh, Hl, Bh + w * 16 * 256, Bl + w * 16 * 256,
                            lq, quad, C);
#pragma unroll
    for (int r = 0; r < 4; ++r) {
      int m = quad * 4 + r;
      float xv = xl[m * 64 + n] + C[r];
      xl[m * 64 + n] = xv;
      if (write_x) x[(size_t)(tok0 + m) * 64 + n] = xv;
    }
  }
  __syncthreads();
}

// ---------------------------------------------------------------------------
// K5a: proj+LN2+FFN (layer lay) then LN1+QKV (layer lay+1).
// ---------------------------------------------------------------------------
__global__ __launch_bounds__(256) void k_pf_qkv(
    const float* __restrict__ ob, const unsigned short* __restrict__ arena,
    const float* __restrict__ bo, float* __restrict__ x,
    const float* __restrict__ ln2_s, const float* __restrict__ ln2_b,
    const float* __restrict__ b1, const float* __restrict__ b2, int lay,
    const float* __restrict__ ln1_s, const float* __restrict__ ln1_b,
    const float* __restrict__ bq, const float* __restrict__ bk,
    const float* __restrict__ bv, unsigned short* __restrict__ qo,
    unsigned short* __restrict__ ko, unsigned short* __restrict__ voT) {
  __shared__ __align__(16) unsigned short Ah[16 * 136], Al[16 * 136];
  __shared__ __align__(16) unsigned short Sh[16 * 72], Sl[16 * 72];
  __shared__ __align__(16) unsigned short Hh[16 * 264], Hl[16 * 264];
  __shared__ float xl[16 * 64];
  int t = threadIdx.x;
  int tok0 = blockIdx.x * 16;
  pf_body(ob, arena, bo, x, ln2_s, ln2_b, b1, b2, lay,
          Ah, Al, Sh, Sl, Hh, Hl, xl, tok0, t, true);
  qkv_tail(xl, Sh, Sl, arena, lay + 1, ln1_s, ln1_b, bq, bk, bv,
           qo, ko, voT, tok0, t);
}

// ---------------------------------------------------------------------------
// K5b: proj+LN2+FFN (last layer) then head MLP.
// ---------------------------------------------------------------------------
__global__ __launch_bounds__(256) void k_pf_head(
    const float* __restrict__ ob, const unsigned short* __restrict__ arena,
    const float* __restrict__ bo, float* __restrict__ x,
    const float* __restrict__ ln2_s, const float* __restrict__ ln2_b,
    const float* __restrict__ b1, const float* __restrict__ b2, int lay,
    const float* __restrict__ bh1, const float* __restrict__ bh2,
    const float* __restrict__ Wh3, const float* __restrict__ bh3,
    float* __restrict__ out) {
  __shared__ __align__(16) unsigned short Ah[16 * 136], Al[16 * 136];
  __shared__ __align__(16) unsigned short Sh[16 * 72], Sl[16 * 72];
  __shared__ __align__(16) unsigned short Hh[16 * 264], Hl[16 * 264];
  __shared__ float xl[16 * 64];
  int t = threadIdx.x, w = t >> 6, lane = t & 63;
  int lq = lane & 15, quad = lane >> 4;
  int tok0 = blockIdx.x * 16;
  pf_body(ob, arena, bo, x, ln2_s, ln2_b, b1, b2, lay,
          Ah, Al, Sh, Sl, Hh, Hl, xl, tok0, t, false);
  // split raw x -> Sh/Sl
#pragma unroll
  for (int tk = 0; tk < 4; ++tk) {
    int tok = w * 4 + tk;
    unsigned short hi, lo;
    split_bf(xl[tok * 64 + lane], hi, lo);
    Sh[tok * 72 + lane] = hi;
    Sl[tok * 72 + lane] = lo;
  }
  __syncthreads();
  // head G1: 64 -> 256, gelu
  {
    const unsigned short* Bh = arena + OFF_WH1;
    const unsigned short* Bl = Bh + 16384;
#pragma unroll
    for (int j = 0; j < 4; ++j) {
      int tl = w * 4 + j, n = tl * 16 + lq;
      float bb = bh1[n];
      floatx4 C = {bb, bb, bb, bb};
      C = mfma_tile<64, 72>(Sh, Sl, Bh + tl * 16 * 64, Bl + tl * 16 * 64,
                            lq, quad, C);
#pragma unroll
      for (int r = 0; r < 4; ++r) {
        float g = gelu_tanh(C[r]);
        unsigned short hi, lo;
        split_bf(g, hi, lo);
        Hh[(quad * 4 + r) * 264 + n] = hi;
        Hl[(quad * 4 + r) * 264 + n] = lo;
      }
    }
  }
  __syncthreads();
  // head G2: 256 -> 64, gelu -> xl (reused as h2s)
  {
    const unsigned short* Bh = arena + OFF_WH2;
    const unsigned short* Bl = Bh + 16384;
    int n = w * 16 + lq;
    float bb = bh2[n];
    floatx4 C = {bb, bb, bb, bb};
    C = mfma_tile<256, 264>(Hh, Hl, Bh + w * 16 * 256, Bl + w * 16 * 256,
                            lq, quad, C);
    __syncthreads();
#pragma unroll
    for (int r = 0; r < 4; ++r)
      xl[(quad * 4 + r) * 64 + n] = gelu_tanh(C[r]);
  }
  __syncthreads();
  // head G3: dot with Wh3
  float wv3 = Wh3[lane];
#pragma unroll
  for (int tk = 0; tk < 4; ++tk) {
    int tok = w * 4 + tk;
    float v = xl[tok * 64 + lane] * wv3;
    float sum = wave_reduce_sum(v);
    if (lane == 0) out[tok0 + tok] = sum + bh3[0];
  }
}

// ---------------------------------------------------------------------------
extern "C" void kernel_launch(void* const* d_in, const int* in_sizes, int n_in,
                              void* d_out, int out_size, void* d_ws, size_t ws_size,
                              hipStream_t stream) {
  const float* z      = (const float*)d_in[0];
  const float* cond   = (const float*)d_in[1];
  const float* s      = (const float*)d_in[2];
  const float* embed  = (const float*)d_in[3];
  const float* Win1   = (const float*)d_in[4];
  const float* bin1   = (const float*)d_in[5];
  const float* Win2   = (const float*)d_in[6];
  const float* bin2   = (const float*)d_in[7];
  const float* ln1_s  = (const float*)d_in[8];
  const float* ln1_b  = (const float*)d_in[9];
  const float* ln2_s  = (const float*)d_in[10];
  const float* ln2_b  = (const float*)d_in[11];
  const float* Wq     = (const float*)d_in[12];
  const float* bq     = (const float*)d_in[13];
  const float* Wk     = (const float*)d_in[14];
  const float* bk     = (const float*)d_in[15];
  const float* Wv     = (const float*)d_in[16];
  const float* bv     = (const float*)d_in[17];
  const float* Wo     = (const float*)d_in[18];
  const float* bo     = (const float*)d_in[19];
  const float* rbf_c  = (const float*)d_in[20];
  const float* rbf_lw = (const float*)d_in[21];
  const float* rbf_w  = (const float*)d_in[22];
  const float* rbf_b  = (const float*)d_in[23];
  const float* W1     = (const float*)d_in[24];
  const float* b1     = (const float*)d_in[25];
  const float* W2     = (const float*)d_in[26];
  const float* b2     = (const float*)d_in[27];
  const float* Wh1    = (const float*)d_in[28];
  const float* bh1    = (const float*)d_in[29];
  const float* Wh2    = (const float*)d_in[30];
  const float* bh2    = (const float*)d_in[31];
  const float* Wh3    = (const float*)d_in[32];
  const float* bh3    = (const float*)d_in[33];

  char* base = (char*)d_ws;
  float*          x     = (float*)(base);                          // 2 MB
  unsigned short* qb    = (unsigned short*)(base + (2u << 20));    // 2 MB
  unsigned short* kb    = (unsigned short*)(base + (4u << 20));    // 2 MB
  unsigned short* vbT   = (unsigned short*)(base + (6u << 20));    // 2 MB
  float*          ob    = (float*)(base + (8u << 20));             // 4 MB
  unsigned short* biasT = (unsigned short*)(base + (12u << 20));   // 2 x 16 MB
  unsigned short* arena = (unsigned short*)(base + (48u << 20));   // ~832 KB

  PrepArgs pa;
  auto set = [&](int i, const float* sp, int K, int N, int dst) {
    pa.src[i] = sp; pa.Kd[i] = K; pa.Nd[i] = N; pa.dst[i] = dst;
    pa.elems[i] = K * N;
  };
  set(0, Win1, 128, 256, OFF_WIN1);
  set(1, Win2, 256, 64, OFF_WIN2);
  for (int lay = 0; lay < 2; ++lay) {
    int lb = OFF_LAY0 + lay * LAY_STRIDE;
    set(2 + lay * 6, Wq + lay * 8192, 64, 128, lb + OFF_WQ);
    set(3 + lay * 6, Wk + lay * 8192, 64, 128, lb + OFF_WK);
    set(4 + lay * 6, Wv + lay * 8192, 64, 128, lb + OFF_WV);
    set(5 + lay * 6, Wo + lay * 8192, 128, 64, lb + OFF_WO);
    set(6 + lay * 6, W1 + lay * 16384, 64, 256, lb + OFF_W1);
    set(7 + lay * 6, W2 + lay * 16384, 256, 64, lb + OFF_W2);
  }
  set(14, Wh1, 64, 256, OFF_WH1);
  set(15, Wh2, 256, 64, OFF_WH2);

  k_prep<<<dim3(128, 16), 256, 0, stream>>>(pa, arena);
  k_bias<<<dim3(4096, 2), 256, 0, stream>>>(s, rbf_c, rbf_lw, rbf_w, rbf_b, biasT);
  k_in_qkv<<<512, 256, 0, stream>>>(embed, z, cond, arena, bin1, bin2, x,
                                    ln1_s, ln1_b, bq, bk, bv, qb, kb, vbT);
  k_attn<<<1024, 256, 0, stream>>>(qb, kb, vbT, biasT, ob);
  k_pf_qkv<<<512, 256, 0, stream>>>(ob, arena, bo, x, ln2_s, ln2_b, b1, b2, 0,
                                    ln1_s, ln1_b, bq, bk, bv, qb, kb, vbT);
  k_attn<<<1024, 256, 0, stream>>>(qb, kb, vbT,
                                   biasT + (size_t)8 * 1024 * 1024, ob);
  k_pf_head<<<512, 256, 0, stream>>>(ob, arena, bo, x, ln2_s, ln2_b, b1, b2, 1,
                                     bh1, bh2, Wh3, bh3, (float*)d_out);
}